// Round 17
// baseline (346.566 us; speedup 1.0000x reference)
//
#include <hip/hip_runtime.h>

#define NN 50000
#define NBGRAPH 512
#define DIN 768
#define DHID 256
#define DOUT 128

typedef unsigned short ushort_t;
typedef __attribute__((ext_vector_type(4))) float f32x4;
typedef _Float16 f16_t;
typedef __attribute__((ext_vector_type(8))) _Float16 f16x8;

__device__ __forceinline__ float lrelu(float v) { return v > 0.f ? v : 0.2f * v; }

__device__ __forceinline__ float h2f_u(ushort_t u) { return (float)__builtin_bit_cast(f16_t, u); }
__device__ __forceinline__ ushort_t f2h_u(float f) { return __builtin_bit_cast(ushort_t, (f16_t)f); }

__device__ __forceinline__ float sel_h(int h, float q0, float q1, float q2, float q3) {
  float lo = (h & 1) ? q1 : q0;
  float hi = (h & 1) ? q3 : q2;
  return (h & 2) ? hi : lo;
}

__device__ __forceinline__ f16x8 cvt8(float4 u, float4 v) {
  unsigned int a = __builtin_bit_cast(unsigned int, __builtin_amdgcn_cvt_pkrtz(u.x, u.y));
  unsigned int b = __builtin_bit_cast(unsigned int, __builtin_amdgcn_cvt_pkrtz(u.z, u.w));
  unsigned int c = __builtin_bit_cast(unsigned int, __builtin_amdgcn_cvt_pkrtz(v.x, v.y));
  unsigned int d = __builtin_bit_cast(unsigned int, __builtin_amdgcn_cvt_pkrtz(v.z, v.w));
  uint4 q = {a, b, c, d};
  return __builtin_bit_cast(f16x8, q);
}
__device__ __forceinline__ f16x8 cvt8_relu(float4 u, float4 v) {
  u.x = fmaxf(u.x, 0.f); u.y = fmaxf(u.y, 0.f); u.z = fmaxf(u.z, 0.f); u.w = fmaxf(u.w, 0.f);
  v.x = fmaxf(v.x, 0.f); v.y = fmaxf(v.y, 0.f); v.z = fmaxf(v.z, 0.f); v.w = fmaxf(v.w, 0.f);
  return cvt8(u, v);
}

// ---------------- CSR build ----------------
__global__ void k_zero2(int* __restrict__ a, int* __restrict__ b, int n) {
  int i = blockIdx.x * blockDim.x + threadIdx.x;
  if (i < n) { a[i] = 0; b[i] = 0; }
}

__global__ void k_hist(const int* __restrict__ ei, int* __restrict__ deg, int E, int Etot) {
  int e = blockIdx.x * blockDim.x + threadIdx.x;
  if (e >= Etot) return;
  int dst = (e < E) ? ei[e] : (e - E);
  atomicAdd(&deg[dst], 1);
}

__global__ __launch_bounds__(1024) void k_scan1(const int* __restrict__ deg, int* __restrict__ off,
                                                int* __restrict__ bsum, int n) {
  __shared__ int wsum[16];
  int tid = threadIdx.x, lane = tid & 63, w = tid >> 6;
  int i = blockIdx.x * 1024 + tid;
  int v = (i < n) ? deg[i] : 0;
  int x = v;
#pragma unroll
  for (int d = 1; d < 64; d <<= 1) { int t = __shfl_up(x, d); if (lane >= d) x += t; }
  if (lane == 63) wsum[w] = x;
  __syncthreads();
  if (tid < 16) {
    int y = wsum[tid];
#pragma unroll
    for (int d = 1; d < 16; d <<= 1) { int t = __shfl_up(y, d); if (tid >= d) y += t; }
    wsum[tid] = y;
  }
  __syncthreads();
  int base = (w > 0) ? wsum[w - 1] : 0;
  if (i < n) off[i] = base + x - v;
  if (tid == 1023) bsum[blockIdx.x] = wsum[15];
}

__global__ void k_scan2(int* __restrict__ bsum, int* __restrict__ off, int nb, int n) {
  int lane = threadIdx.x;
  int v = (lane < nb) ? bsum[lane] : 0;
  int x = v;
#pragma unroll
  for (int d = 1; d < 64; d <<= 1) { int t = __shfl_up(x, d); if (lane >= d) x += t; }
  if (lane < nb) bsum[lane] = x - v;
  if (lane == 63) off[n] = x;
}

__global__ void k_scan3(int* __restrict__ off, const int* __restrict__ bsum, int n) {
  int i = blockIdx.x * blockDim.x + threadIdx.x;
  if (i < n) off[i] += bsum[i >> 10];
}

__global__ void k_scatter(const int* __restrict__ ei, const int* __restrict__ off,
                          int* __restrict__ cur, int* __restrict__ csr, int E, int Etot) {
  int e = blockIdx.x * blockDim.x + threadIdx.x;
  if (e >= Etot) return;
  int dst, src;
  if (e < E) { dst = ei[e]; src = ei[E + e]; }
  else       { dst = src = e - E; }
  int p = atomicAdd(&cur[dst], 1);
  csr[off[dst] + p] = src;
}

// ---------------- roots / segments ----------------
__global__ void k_segstart(const int* __restrict__ batch, int* __restrict__ segstart, int n, int b_cnt) {
  int b = blockIdx.x * blockDim.x + threadIdx.x;
  if (b > b_cnt) return;
  int lo = 0, hi = n;
  while (lo < hi) { int mid = (lo + hi) >> 1; if (batch[mid] < b) lo = mid + 1; else hi = mid; }
  segstart[b] = lo;
}

// ---------------- weight transpose+cast (fp16): Wt[n][k] = f16(W[k][n]) ----------------
__global__ void k_prepW(const float* __restrict__ W, ushort_t* __restrict__ Wt, int K, int N) {
  int id = blockIdx.x * blockDim.x + threadIdx.x;
  if (id >= K * N) return;
  int n = id / K, k = id - n * K;
  Wt[(size_t)n * K + k] = f2h_u(W[(size_t)k * N + n]);
}

// ---------------- GEMM1: BM=64, BN=128, BK=64, single-LDS, 2-DEEP reg prefetch ----------------
#define LDT2 72
__global__ __launch_bounds__(256) void k_gemm1m(const float* __restrict__ A,
                                                const ushort_t* __restrict__ Bt,
                                                ushort_t* __restrict__ C) {
  const int K = DIN, NC = DHID;
  __shared__ __align__(16) ushort_t As[64 * LDT2];
  __shared__ __align__(16) ushort_t Bs[128 * LDT2];
  const int tid = threadIdx.x;
  const int bm = blockIdx.x * 64;
  const int bn = blockIdx.y * 128;
  const int row = tid >> 2, q = tid & 3;
  const int arow = bm + row;
  const int r_c = arow < NN ? arow : NN - 1;
  const int wid = tid >> 6, lane = tid & 63;
  const int wr = (wid >> 1) * 32, wc = (wid & 1) * 64;
  const int fr = lane & 15, fg = lane >> 4;
  const float* aptr = &A[(size_t)r_c * K + q * 16];
  const int bc0 = tid >> 3, bk0 = tid & 7;
  const int bc1 = (tid + 256) >> 3, bk1 = (tid + 256) & 7;
  const int bc2 = (tid + 512) >> 3, bk2 = (tid + 512) & 7;
  const int bc3 = (tid + 768) >> 3, bk3 = (tid + 768) & 7;
  const ushort_t* bp0 = &Bt[(size_t)(bn + bc0) * K + bk0 * 8];
  const ushort_t* bp1 = &Bt[(size_t)(bn + bc1) * K + bk1 * 8];
  const ushort_t* bp2 = &Bt[(size_t)(bn + bc2) * K + bk2 * 8];
  const ushort_t* bp3 = &Bt[(size_t)(bn + bc3) * K + bk3 * 8];
  f32x4 acc[2][4] = {};

  float4 Pa0, Pa1, Pa2, Pa3; uint4 Pb0, Pb1, Pb2, Pb3;
  float4 Qa0, Qa1, Qa2, Qa3; uint4 Qb0, Qb1, Qb2, Qb3;

  auto loadP = [&](int kk) {
    const float4* s = (const float4*)(aptr + kk);
    Pa0 = s[0]; Pa1 = s[1]; Pa2 = s[2]; Pa3 = s[3];
    Pb0 = *(const uint4*)(bp0 + kk); Pb1 = *(const uint4*)(bp1 + kk);
    Pb2 = *(const uint4*)(bp2 + kk); Pb3 = *(const uint4*)(bp3 + kk);
  };
  auto loadQ = [&](int kk) {
    const float4* s = (const float4*)(aptr + kk);
    Qa0 = s[0]; Qa1 = s[1]; Qa2 = s[2]; Qa3 = s[3];
    Qb0 = *(const uint4*)(bp0 + kk); Qb1 = *(const uint4*)(bp1 + kk);
    Qb2 = *(const uint4*)(bp2 + kk); Qb3 = *(const uint4*)(bp3 + kk);
  };
  auto stage = [&](float4 a0, float4 a1, float4 a2, float4 a3,
                   uint4 b0, uint4 b1, uint4 b2, uint4 b3) {
    const int p = row * LDT2 + q * 16;
    *(f16x8*)&As[p + 0] = cvt8(a0, a1);
    *(f16x8*)&As[p + 8] = cvt8(a2, a3);
    *(uint4*)&Bs[bc0 * LDT2 + bk0 * 8] = b0;
    *(uint4*)&Bs[bc1 * LDT2 + bk1 * 8] = b1;
    *(uint4*)&Bs[bc2 * LDT2 + bk2 * 8] = b2;
    *(uint4*)&Bs[bc3 * LDT2 + bk3 * 8] = b3;
  };
  auto compute = [&]() {
#pragma unroll
    for (int kk = 0; kk < 64; kk += 32) {
      f16x8 af0 = *(const f16x8*)&As[(wr + fr) * LDT2 + kk + fg * 8];
      f16x8 af1 = *(const f16x8*)&As[(wr + 16 + fr) * LDT2 + kk + fg * 8];
      f16x8 bf0 = *(const f16x8*)&Bs[(wc + fr) * LDT2 + kk + fg * 8];
      f16x8 bf1 = *(const f16x8*)&Bs[(wc + 16 + fr) * LDT2 + kk + fg * 8];
      f16x8 bf2 = *(const f16x8*)&Bs[(wc + 32 + fr) * LDT2 + kk + fg * 8];
      f16x8 bf3 = *(const f16x8*)&Bs[(wc + 48 + fr) * LDT2 + kk + fg * 8];
      acc[0][0] = __builtin_amdgcn_mfma_f32_16x16x32_f16(af0, bf0, acc[0][0], 0, 0, 0);
      acc[0][1] = __builtin_amdgcn_mfma_f32_16x16x32_f16(af0, bf1, acc[0][1], 0, 0, 0);
      acc[0][2] = __builtin_amdgcn_mfma_f32_16x16x32_f16(af0, bf2, acc[0][2], 0, 0, 0);
      acc[0][3] = __builtin_amdgcn_mfma_f32_16x16x32_f16(af0, bf3, acc[0][3], 0, 0, 0);
      acc[1][0] = __builtin_amdgcn_mfma_f32_16x16x32_f16(af1, bf0, acc[1][0], 0, 0, 0);
      acc[1][1] = __builtin_amdgcn_mfma_f32_16x16x32_f16(af1, bf1, acc[1][1], 0, 0, 0);
      acc[1][2] = __builtin_amdgcn_mfma_f32_16x16x32_f16(af1, bf2, acc[1][2], 0, 0, 0);
      acc[1][3] = __builtin_amdgcn_mfma_f32_16x16x32_f16(af1, bf3, acc[1][3], 0, 0, 0);
    }
  };

  loadP(0);
  loadQ(64);
  for (int k0 = 0; k0 < K; k0 += 128) {
    stage(Pa0, Pa1, Pa2, Pa3, Pb0, Pb1, Pb2, Pb3);
    __syncthreads();
    if (k0 + 128 < K) loadP(k0 + 128);
    compute();
    __syncthreads();
    stage(Qa0, Qa1, Qa2, Qa3, Qb0, Qb1, Qb2, Qb3);
    __syncthreads();
    if (k0 + 192 < K) loadQ(k0 + 192);
    compute();
    __syncthreads();
  }
#pragma unroll
  for (int m = 0; m < 2; ++m)
#pragma unroll
    for (int n = 0; n < 4; ++n)
#pragma unroll
      for (int j = 0; j < 4; ++j) {
        int r = bm + wr + m * 16 + fg * 4 + j;
        if (r < NN) C[(size_t)r * NC + bn + wc + n * 16 + fr] = f2h_u(acc[m][n][j]);
      }
}

// ---------------- gemmR: R2[b][c] = relu(x[segstart[b]]) . W2[256:, c]  (512 graphs) ----------------
__global__ __launch_bounds__(256) void k_gemmR(const float* __restrict__ X,
                                               const int* __restrict__ segstart,
                                               const ushort_t* __restrict__ Wt2,
                                               float* __restrict__ R2) {
  __shared__ float part[2][128];
  const int b = blockIdx.x;
  const int t = threadIdx.x;
  const int c = t & 127, seg = t >> 7;
  int root = segstart[b];
  if (root >= NN) root = NN - 1;
  const float* xr = &X[(size_t)root * DIN + seg * 384];
  const ushort_t* wp = &Wt2[(size_t)c * (DHID + DIN) + DHID + seg * 384];
  float s = 0.f;
#pragma unroll 4
  for (int k = 0; k < 384; k += 4) {
    float4 xv = *(const float4*)&xr[k];
    ushort4 wv = *(const ushort4*)&wp[k];
    s += fmaxf(xv.x, 0.f) * h2f_u(wv.x);
    s += fmaxf(xv.y, 0.f) * h2f_u(wv.y);
    s += fmaxf(xv.z, 0.f) * h2f_u(wv.z);
    s += fmaxf(xv.w, 0.f) * h2f_u(wv.w);
  }
  part[seg][c] = s;
  __syncthreads();
  if (t < 128) R2[(size_t)b * DOUT + t] = part[0][t] + part[1][t];
}

// ---------------- GEMM2: K=256 (relu(OUT1) @ W2[:256]), 2-deep prefetch; adds R2[batch[r]] ----------------
__global__ __launch_bounds__(256) void k_gemm2m(const float* __restrict__ OUT1,
                                                const int* __restrict__ batch,
                                                const ushort_t* __restrict__ Bt,
                                                const float* __restrict__ R2,
                                                ushort_t* __restrict__ C) {
  const int K = DHID;           // 256
  const int KS = DHID + DIN;    // B row stride = 1024
  __shared__ __align__(16) ushort_t As[64 * LDT2];
  __shared__ __align__(16) ushort_t Bs[128 * LDT2];
  const int tid = threadIdx.x;
  const int bm = blockIdx.x * 64;
  const int row = tid >> 2, q = tid & 3;
  const int arow = bm + row;
  const int r_c = arow < NN ? arow : NN - 1;
  const int wid = tid >> 6, lane = tid & 63;
  const int wr = (wid >> 1) * 32, wc = (wid & 1) * 64;
  const int fr = lane & 15, fg = lane >> 4;
  const float* aptr = &OUT1[(size_t)r_c * DHID + q * 16];
  const int bc0 = tid >> 3, bk0 = tid & 7;
  const int bc1 = (tid + 256) >> 3, bk1 = (tid + 256) & 7;
  const int bc2 = (tid + 512) >> 3, bk2 = (tid + 512) & 7;
  const int bc3 = (tid + 768) >> 3, bk3 = (tid + 768) & 7;
  const ushort_t* bp0 = &Bt[(size_t)bc0 * KS + bk0 * 8];
  const ushort_t* bp1 = &Bt[(size_t)bc1 * KS + bk1 * 8];
  const ushort_t* bp2 = &Bt[(size_t)bc2 * KS + bk2 * 8];
  const ushort_t* bp3 = &Bt[(size_t)bc3 * KS + bk3 * 8];
  f32x4 acc[2][4] = {};

  float4 Pa0, Pa1, Pa2, Pa3; uint4 Pb0, Pb1, Pb2, Pb3;
  float4 Qa0, Qa1, Qa2, Qa3; uint4 Qb0, Qb1, Qb2, Qb3;

  auto loadP = [&](int kk) {
    const float4* s = (const float4*)(aptr + kk);
    Pa0 = s[0]; Pa1 = s[1]; Pa2 = s[2]; Pa3 = s[3];
    Pb0 = *(const uint4*)(bp0 + kk); Pb1 = *(const uint4*)(bp1 + kk);
    Pb2 = *(const uint4*)(bp2 + kk); Pb3 = *(const uint4*)(bp3 + kk);
  };
  auto loadQ = [&](int kk) {
    const float4* s = (const float4*)(aptr + kk);
    Qa0 = s[0]; Qa1 = s[1]; Qa2 = s[2]; Qa3 = s[3];
    Qb0 = *(const uint4*)(bp0 + kk); Qb1 = *(const uint4*)(bp1 + kk);
    Qb2 = *(const uint4*)(bp2 + kk); Qb3 = *(const uint4*)(bp3 + kk);
  };
  auto stage = [&](float4 a0, float4 a1, float4 a2, float4 a3,
                   uint4 b0, uint4 b1, uint4 b2, uint4 b3) {
    const int p = row * LDT2 + q * 16;
    *(f16x8*)&As[p + 0] = cvt8_relu(a0, a1);
    *(f16x8*)&As[p + 8] = cvt8_relu(a2, a3);
    *(uint4*)&Bs[bc0 * LDT2 + bk0 * 8] = b0;
    *(uint4*)&Bs[bc1 * LDT2 + bk1 * 8] = b1;
    *(uint4*)&Bs[bc2 * LDT2 + bk2 * 8] = b2;
    *(uint4*)&Bs[bc3 * LDT2 + bk3 * 8] = b3;
  };
  auto compute = [&]() {
#pragma unroll
    for (int kk = 0; kk < 64; kk += 32) {
      f16x8 af0 = *(const f16x8*)&As[(wr + fr) * LDT2 + kk + fg * 8];
      f16x8 af1 = *(const f16x8*)&As[(wr + 16 + fr) * LDT2 + kk + fg * 8];
      f16x8 bf0 = *(const f16x8*)&Bs[(wc + fr) * LDT2 + kk + fg * 8];
      f16x8 bf1 = *(const f16x8*)&Bs[(wc + 16 + fr) * LDT2 + kk + fg * 8];
      f16x8 bf2 = *(const f16x8*)&Bs[(wc + 32 + fr) * LDT2 + kk + fg * 8];
      f16x8 bf3 = *(const f16x8*)&Bs[(wc + 48 + fr) * LDT2 + kk + fg * 8];
      acc[0][0] = __builtin_amdgcn_mfma_f32_16x16x32_f16(af0, bf0, acc[0][0], 0, 0, 0);
      acc[0][1] = __builtin_amdgcn_mfma_f32_16x16x32_f16(af0, bf1, acc[0][1], 0, 0, 0);
      acc[0][2] = __builtin_amdgcn_mfma_f32_16x16x32_f16(af0, bf2, acc[0][2], 0, 0, 0);
      acc[0][3] = __builtin_amdgcn_mfma_f32_16x16x32_f16(af0, bf3, acc[0][3], 0, 0, 0);
      acc[1][0] = __builtin_amdgcn_mfma_f32_16x16x32_f16(af1, bf0, acc[1][0], 0, 0, 0);
      acc[1][1] = __builtin_amdgcn_mfma_f32_16x16x32_f16(af1, bf1, acc[1][1], 0, 0, 0);
      acc[1][2] = __builtin_amdgcn_mfma_f32_16x16x32_f16(af1, bf2, acc[1][2], 0, 0, 0);
      acc[1][3] = __builtin_amdgcn_mfma_f32_16x16x32_f16(af1, bf3, acc[1][3], 0, 0, 0);
    }
  };

  loadP(0);
  loadQ(64);
  for (int k0 = 0; k0 < K; k0 += 128) {
    stage(Pa0, Pa1, Pa2, Pa3, Pb0, Pb1, Pb2, Pb3);
    __syncthreads();
    if (k0 + 128 < K) loadP(k0 + 128);
    compute();
    __syncthreads();
    stage(Qa0, Qa1, Qa2, Qa3, Qb0, Qb1, Qb2, Qb3);
    __syncthreads();
    if (k0 + 192 < K) loadQ(k0 + 192);
    compute();
    __syncthreads();
  }
#pragma unroll
  for (int m = 0; m < 2; ++m)
#pragma unroll
    for (int j = 0; j < 4; ++j) {
      int r = bm + wr + m * 16 + fg * 4 + j;
      if (r < NN) {
        int gb = batch[r];
        const float* r2 = &R2[(size_t)gb * DOUT];
#pragma unroll
        for (int n = 0; n < 4; ++n) {
          int col = wc + n * 16 + fr;
          C[(size_t)r * DOUT + col] = f2h_u(acc[m][n][j] + r2[col]);
        }
      }
    }
}

// ---------------- attention scores (fp16 H) ----------------
__global__ __launch_bounds__(256) void k_scores1(const ushort_t* __restrict__ Hh,
                                                 const float* __restrict__ att_s,
                                                 const float* __restrict__ att_d,
                                                 float4* __restrict__ as_out,
                                                 float4* __restrict__ ad_out) {
  int lane = threadIdx.x & 63;
  int n = blockIdx.x * 4 + (threadIdx.x >> 6);
  if (n >= NN) return;
  ushort4 hv = *(const ushort4*)&Hh[(size_t)n * DHID + lane * 4];
  float h0 = h2f_u(hv.x), h1 = h2f_u(hv.y), h2 = h2f_u(hv.z), h3 = h2f_u(hv.w);
  float4 sa = *(const float4*)&att_s[lane * 4];
  float4 da = *(const float4*)&att_d[lane * 4];
  float ps = h0 * sa.x + h1 * sa.y + h2 * sa.z + h3 * sa.w;
  float pd = h0 * da.x + h1 * da.y + h2 * da.z + h3 * da.w;
#pragma unroll
  for (int m = 1; m < 16; m <<= 1) { ps += __shfl_xor(ps, m); pd += __shfl_xor(pd, m); }
  float4 rs, rd;
  rs.x = __shfl(ps, 0);  rd.x = __shfl(pd, 0);
  rs.y = __shfl(ps, 16); rd.y = __shfl(pd, 16);
  rs.z = __shfl(ps, 32); rd.z = __shfl(pd, 32);
  rs.w = __shfl(ps, 48); rd.w = __shfl(pd, 48);
  if (lane == 0) { as_out[n] = rs; ad_out[n] = rd; }
}

__global__ __launch_bounds__(256) void k_scores2(const ushort_t* __restrict__ Hh,
                                                 const float* __restrict__ att_s,
                                                 const float* __restrict__ att_d,
                                                 float4* __restrict__ as_out,
                                                 float4* __restrict__ ad_out) {
  int lane = threadIdx.x & 63;
  int n = blockIdx.x * 4 + (threadIdx.x >> 6);
  if (n >= NN) return;
  ushort2 hv = *(const ushort2*)&Hh[(size_t)n * DOUT + lane * 2];
  float h0 = h2f_u(hv.x), h1 = h2f_u(hv.y);
  float2 sa = *(const float2*)&att_s[lane * 2];
  float2 da = *(const float2*)&att_d[lane * 2];
  float ps = h0 * sa.x + h1 * sa.y;
  float pd = h0 * da.x + h1 * da.y;
#pragma unroll
  for (int m = 1; m < 16; m <<= 1) { ps += __shfl_xor(ps, m); pd += __shfl_xor(pd, m); }
  float4 rs, rd;
  rs.x = __shfl(ps, 0);  rd.x = __shfl(pd, 0);
  rs.y = __shfl(ps, 16); rd.y = __shfl(pd, 16);
  rs.z = __shfl(ps, 32); rd.z = __shfl(pd, 32);
  rs.w = __shfl(ps, 48); rd.w = __shfl(pd, 48);
  if (lane == 0) { as_out[n] = rs; ad_out[n] = rd; }
}

// ---------------- GAT aggregation, layer 1: one node per 16-lane group ----------------
__global__ __launch_bounds__(256) void k_agg1(const int* __restrict__ off, const int* __restrict__ csr,
                                              const float4* __restrict__ as_v, const float4* __restrict__ ad_v,
                                              const ushort_t* __restrict__ Hh, const float* __restrict__ bias,
                                              float* __restrict__ OUT) {
  __shared__ int s_tab[16][65];
  __shared__ __align__(16) float al_tab[16][260];
  const int tid = threadIdx.x;
  const int nd = tid >> 4;
  const int g = tid & 15;
  const int hd = g >> 2;
  const int n = blockIdx.x * 16 + nd;
  if (n >= NN) return;
  const int beg = off[n];
  const int nt = off[n + 1] - beg;
  const float4 adv = ad_v[n];

  float acc[16] = {};
  float rdh;

  if (nt <= 64) {
    float mx0 = -INFINITY, mx1 = -INFINITY, mx2 = -INFINITY, mx3 = -INFINITY;
    for (int le = g; le < nt; le += 16) {
      int s = csr[beg + le];
      float4 a = as_v[s];
      s_tab[nd][le] = s;
      *(float4*)&al_tab[nd][le << 2] = a;
      mx0 = fmaxf(mx0, a.x); mx1 = fmaxf(mx1, a.y);
      mx2 = fmaxf(mx2, a.z); mx3 = fmaxf(mx3, a.w);
    }
#pragma unroll
    for (int m = 1; m < 16; m <<= 1) {
      mx0 = fmaxf(mx0, __shfl_xor(mx0, m)); mx1 = fmaxf(mx1, __shfl_xor(mx1, m));
      mx2 = fmaxf(mx2, __shfl_xor(mx2, m)); mx3 = fmaxf(mx3, __shfl_xor(mx3, m));
    }
    float em0 = lrelu(mx0 + adv.x), em1 = lrelu(mx1 + adv.y);
    float em2 = lrelu(mx2 + adv.z), em3 = lrelu(mx3 + adv.w);
    float s0 = 0.f, s1 = 0.f, s2 = 0.f, s3 = 0.f;
    for (int le = g; le < nt; le += 16) {
      float4 a = *(const float4*)&al_tab[nd][le << 2];
      float p0 = __expf(lrelu(a.x + adv.x) - em0);
      float p1 = __expf(lrelu(a.y + adv.y) - em1);
      float p2 = __expf(lrelu(a.z + adv.z) - em2);
      float p3 = __expf(lrelu(a.w + adv.w) - em3);
      *(float4*)&al_tab[nd][le << 2] = make_float4(p0, p1, p2, p3);
      s0 += p0; s1 += p1; s2 += p2; s3 += p3;
    }
#pragma unroll
    for (int m = 1; m < 16; m <<= 1) {
      s0 += __shfl_xor(s0, m); s1 += __shfl_xor(s1, m);
      s2 += __shfl_xor(s2, m); s3 += __shfl_xor(s3, m);
    }
    rdh = sel_h(hd, 1.f / (s0 + 1e-16f), 1.f / (s1 + 1e-16f),
                    1.f / (s2 + 1e-16f), 1.f / (s3 + 1e-16f));

    int sP = s_tab[nd][0];
    float pP = al_tab[nd][hd];
    f16x8 v0 = *(const f16x8*)&Hh[(size_t)sP * DHID + g * 16];
    f16x8 v1 = *(const f16x8*)&Hh[(size_t)sP * DHID + g * 16 + 8];
    for (int e = 0; e < nt; ++e) {
      int en = (e + 1 < nt) ? e + 1 : e;
      int sN = s_tab[nd][en];
      float pN = al_tab[nd][(en << 2) | hd];
      f16x8 n0 = *(const f16x8*)&Hh[(size_t)sN * DHID + g * 16];
      f16x8 n1 = *(const f16x8*)&Hh[(size_t)sN * DHID + g * 16 + 8];
      float al = pP * rdh;
#pragma unroll
      for (int q = 0; q < 8; ++q) acc[q] += al * (float)v0[q];
#pragma unroll
      for (int q = 0; q < 8; ++q) acc[8 + q] += al * (float)v1[q];
      pP = pN; v0 = n0; v1 = n1;
    }
  } else {
    float mx0 = -INFINITY, mx1 = -INFINITY, mx2 = -INFINITY, mx3 = -INFINITY;
    for (int le = g; le < nt; le += 16) {
      float4 a = as_v[csr[beg + le]];
      mx0 = fmaxf(mx0, a.x); mx1 = fmaxf(mx1, a.y);
      mx2 = fmaxf(mx2, a.z); mx3 = fmaxf(mx3, a.w);
    }
#pragma unroll
    for (int m = 1; m < 16; m <<= 1) {
      mx0 = fmaxf(mx0, __shfl_xor(mx0, m)); mx1 = fmaxf(mx1, __shfl_xor(mx1, m));
      mx2 = fmaxf(mx2, __shfl_xor(mx2, m)); mx3 = fmaxf(mx3, __shfl_xor(mx3, m));
    }
    float em0 = lrelu(mx0 + adv.x), em1 = lrelu(mx1 + adv.y);
    float em2 = lrelu(mx2 + adv.z), em3 = lrelu(mx3 + adv.w);
    float s0 = 0.f, s1 = 0.f, s2 = 0.f, s3 = 0.f;
    for (int le = g; le < nt; le += 16) {
      float4 a = as_v[csr[beg + le]];
      s0 += __expf(lrelu(a.x + adv.x) - em0);
      s1 += __expf(lrelu(a.y + adv.y) - em1);
      s2 += __expf(lrelu(a.z + adv.z) - em2);
      s3 += __expf(lrelu(a.w + adv.w) - em3);
    }
#pragma unroll
    for (int m = 1; m < 16; m <<= 1) {
      s0 += __shfl_xor(s0, m); s1 += __shfl_xor(s1, m);
      s2 += __shfl_xor(s2, m); s3 += __shfl_xor(s3, m);
    }
    rdh = sel_h(hd, 1.f / (s0 + 1e-16f), 1.f / (s1 + 1e-16f),
                    1.f / (s2 + 1e-16f), 1.f / (s3 + 1e-16f));
    float adh = sel_h(hd, adv.x, adv.y, adv.z, adv.w);
    float emh = sel_h(hd, em0, em1, em2, em3);
    for (int e = 0; e < nt; ++e) {
      int s = csr[beg + e];
      float4 a = as_v[s];
      float ah = sel_h(hd, a.x, a.y, a.z, a.w);
      float al = __expf(lrelu(ah + adh) - emh) * rdh;
      f16x8 v0 = *(const f16x8*)&Hh[(size_t)s * DHID + g * 16];
      f16x8 v1 = *(const f16x8*)&Hh[(size_t)s * DHID + g * 16 + 8];
#pragma unroll
      for (int q = 0; q < 8; ++q) acc[q] += al * (float)v0[q];
#pragma unroll
      for (int q = 0; q < 8; ++q) acc[8 + q] += al * (float)v1[q];
    }
  }

  const float* bv = &bias[g * 16];
  float* ob = &OUT[(size_t)n * DHID + g * 16];
#pragma unroll
  for (int k = 0; k < 4; ++k) {
    float4 b4 = *(const float4*)&bv[k * 4];
    *(float4*)&ob[k * 4] = make_float4(acc[k * 4] + b4.x, acc[k * 4 + 1] + b4.y,
                                       acc[k * 4 + 2] + b4.z, acc[k * 4 + 3] + b4.w);
  }
}

// ---------------- GAT aggregation, layer 2: one node per 16-lane group ----------------
__global__ __launch_bounds__(256) void k_agg2(const int* __restrict__ off, const int* __restrict__ csr,
                                              const float4* __restrict__ as_v, const float4* __restrict__ ad_v,
                                              const ushort_t* __restrict__ Hh, const float* __restrict__ bias,
                                              float* __restrict__ OUT) {
  __shared__ int s_tab[16][65];
  __shared__ __align__(16) float al_tab[16][260];
  const int tid = threadIdx.x;
  const int nd = tid >> 4;
  const int g = tid & 15;
  const int hd = g >> 2;
  const int n = blockIdx.x * 16 + nd;
  if (n >= NN) return;
  const int beg = off[n];
  const int nt = off[n + 1] - beg;
  const float4 adv = ad_v[n];

  float acc[8] = {};
  float rdh;

  if (nt <= 64) {
    float mx0 = -INFINITY, mx1 = -INFINITY, mx2 = -INFINITY, mx3 = -INFINITY;
    for (int le = g; le < nt; le += 16) {
      int s = csr[beg + le];
      float4 a = as_v[s];
      s_tab[nd][le] = s;
      *(float4*)&al_tab[nd][le << 2] = a;
      mx0 = fmaxf(mx0, a.x); mx1 = fmaxf(mx1, a.y);
      mx2 = fmaxf(mx2, a.z); mx3 = fmaxf(mx3, a.w);
    }
#pragma unroll
    for (int m = 1; m < 16; m <<= 1) {
      mx0 = fmaxf(mx0, __shfl_xor(mx0, m)); mx1 = fmaxf(mx1, __shfl_xor(mx1, m));
      mx2 = fmaxf(mx2, __shfl_xor(mx2, m)); mx3 = fmaxf(mx3, __shfl_xor(mx3, m));
    }
    float em0 = lrelu(mx0 + adv.x), em1 = lrelu(mx1 + adv.y);
    float em2 = lrelu(mx2 + adv.z), em3 = lrelu(mx3 + adv.w);
    float s0 = 0.f, s1 = 0.f, s2 = 0.f, s3 = 0.f;
    for (int le = g; le < nt; le += 16) {
      float4 a = *(const float4*)&al_tab[nd][le << 2];
      float p0 = __expf(lrelu(a.x + adv.x) - em0);
      float p1 = __expf(lrelu(a.y + adv.y) - em1);
      float p2 = __expf(lrelu(a.z + adv.z) - em2);
      float p3 = __expf(lrelu(a.w + adv.w) - em3);
      *(float4*)&al_tab[nd][le << 2] = make_float4(p0, p1, p2, p3);
      s0 += p0; s1 += p1; s2 += p2; s3 += p3;
    }
#pragma unroll
    for (int m = 1; m < 16; m <<= 1) {
      s0 += __shfl_xor(s0, m); s1 += __shfl_xor(s1, m);
      s2 += __shfl_xor(s2, m); s3 += __shfl_xor(s3, m);
    }
    rdh = sel_h(hd, 1.f / (s0 + 1e-16f), 1.f / (s1 + 1e-16f),
                    1.f / (s2 + 1e-16f), 1.f / (s3 + 1e-16f));

    int sP = s_tab[nd][0];
    float pP = al_tab[nd][hd];
    f16x8 v0 = *(const f16x8*)&Hh[(size_t)sP * DOUT + g * 8];
    for (int e = 0; e < nt; ++e) {
      int en = (e + 1 < nt) ? e + 1 : e;
      int sN = s_tab[nd][en];
      float pN = al_tab[nd][(en << 2) | hd];
      f16x8 n0 = *(const f16x8*)&Hh[(size_t)sN * DOUT + g * 8];
      float al = pP * rdh;
#pragma unroll
      for (int q = 0; q < 8; ++q) acc[q] += al * (float)v0[q];
      pP = pN; v0 = n0;
    }
  } else {
    float mx0 = -INFINITY, mx1 = -INFINITY, mx2 = -INFINITY, mx3 = -INFINITY;
    for (int le = g; le < nt; le += 16) {
      float4 a = as_v[csr[beg + le]];
      mx0 = fmaxf(mx0, a.x); mx1 = fmaxf(mx1, a.y);
      mx2 = fmaxf(mx2, a.z); mx3 = fmaxf(mx3, a.w);
    }
#pragma unroll
    for (int m = 1; m < 16; m <<= 1) {
      mx0 = fmaxf(mx0, __shfl_xor(mx0, m)); mx1 = fmaxf(mx1, __shfl_xor(mx1, m));
      mx2 = fmaxf(mx2, __shfl_xor(mx2, m)); mx3 = fmaxf(mx3, __shfl_xor(mx3, m));
    }
    float em0 = lrelu(mx0 + adv.x), em1 = lrelu(mx1 + adv.y);
    float em2 = lrelu(mx2 + adv.z), em3 = lrelu(mx3 + adv.w);
    float s0 = 0.f, s1 = 0.f, s2 = 0.f, s3 = 0.f;
    for (int le = g; le < nt; le += 16) {
      float4 a = as_v[csr[beg + le]];
      s0 += __expf(lrelu(a.x + adv.x) - em0);
      s1 += __expf(lrelu(a.y + adv.y) - em1);
      s2 += __expf(lrelu(a.z + adv.z) - em2);
      s3 += __expf(lrelu(a.w + adv.w) - em3);
    }
#pragma unroll
    for (int m = 1; m < 16; m <<= 1) {
      s0 += __shfl_xor(s0, m); s1 += __shfl_xor(s1, m);
      s2 += __shfl_xor(s2, m); s3 += __shfl_xor(s3, m);
    }
    rdh = sel_h(hd, 1.f / (s0 + 1e-16f), 1.f / (s1 + 1e-16f),
                    1.f / (s2 + 1e-16f), 1.f / (s3 + 1e-16f));
    float adh = sel_h(hd, adv.x, adv.y, adv.z, adv.w);
    float emh = sel_h(hd, em0, em1, em2, em3);
    for (int e = 0; e < nt; ++e) {
      int s = csr[beg + e];
      float4 a = as_v[s];
      float ah = sel_h(hd, a.x, a.y, a.z, a.w);
      float al = __expf(lrelu(ah + adh) - emh) * rdh;
      f16x8 v0 = *(const f16x8*)&Hh[(size_t)s * DOUT + g * 8];
#pragma unroll
      for (int q = 0; q < 8; ++q) acc[q] += al * (float)v0[q];
    }
  }

  const float* bv = &bias[g * 8];
  float* ob = &OUT[(size_t)n * DOUT + g * 8];
#pragma unroll
  for (int k = 0; k < 2; ++k) {
    float4 b4 = *(const float4*)&bv[k * 4];
    *(float4*)&ob[k * 4] = make_float4(acc[k * 4] + b4.x, acc[k * 4 + 1] + b4.y,
                                       acc[k * 4 + 2] + b4.z, acc[k * 4 + 3] + b4.w);
  }
}

// ---------------- pooling ----------------
__global__ __launch_bounds__(256) void k_pool(const int* __restrict__ segstart,
                                              const float* __restrict__ OUT2,
                                              const float* __restrict__ OUT1,
                                              float* __restrict__ out) {
  int b = blockIdx.x;
  int t = threadIdx.x;
  int s = segstart[b], e = segstart[b + 1];
  float* ob = out + (size_t)b * 384;
  if (s >= e) {
    for (int i = t; i < 384; i += 256) ob[i] = 0.f;
    return;
  }
  if (t < 128) {
    float s0 = 0.f, s1 = 0.f;
    int n = s;
    for (; n + 1 < e; n += 2) {
      float v0 = OUT2[(size_t)n * DOUT + t];
      float v1 = OUT2[(size_t)(n + 1) * DOUT + t];
      s0 += fmaxf(v0, 0.f); s1 += fmaxf(v1, 0.f);
    }
    if (n < e) s0 += fmaxf(OUT2[(size_t)n * DOUT + t], 0.f);
    ob[t] = (s0 + s1) / (float)(e - s);
  } else {
    int k = t - 128;
    ob[128 + k] = OUT1[(size_t)s * DHID + k];
    ob[256 + k] = OUT1[(size_t)s * DHID + 128 + k];
  }
}

// ---------------- launch ----------------
extern "C" void kernel_launch(void* const* d_in, const int* in_sizes, int n_in,
                              void* d_out, int out_size, void* d_ws, size_t ws_size,
                              hipStream_t stream) {
  const float* x    = (const float*)d_in[0];
  const int*   ei   = (const int*)d_in[1];
  const int*   batch = (const int*)d_in[2];
  const float* W1   = (const float*)d_in[3];
  const float* as1w = (const float*)d_in[4];
  const float* ad1w = (const float*)d_in[5];
  const float* b1   = (const float*)d_in[6];
  const float* W2   = (const float*)d_in[7];
  const float* as2w = (const float*)d_in[8];
  const float* ad2w = (const float*)d_in[9];
  const float* b2   = (const float*)d_in[10];
  float* out = (float*)d_out;
  char* ws = (char*)d_ws;

  const int E = in_sizes[1] / 2;
  const int Etot = E + NN;

  // workspace layout (bytes). NOTE: Wt2h lives INSIDE the H1h region (0..25.6MB) —
  // it MUST be written only after k_agg1 (H1h dead), and H2h (0..12.8MB) stays below it.
  ushort_t* H1h = (ushort_t*)(ws + 0);        // NN*256*2 = 25.6 MB (dead after agg1)
  ushort_t* H2h = (ushort_t*)(ws + 0);        // NN*128*2 = 12.8 MB (aliases H1h)
  ushort_t* Wt2h = (ushort_t*)(ws + 13000000);// 262144 B (written AFTER agg1)
  float*  R2   = (float*)(ws + 14000000);     // 512*128*4 (written after agg1)
  float*  OUT2 = (float*)(ws + 25600000);
  float*  OUT1 = (float*)(ws + 51200000);
  float4* as1  = (float4*)(ws + 102400000);
  float4* ad1  = (float4*)(ws + 103200000);
  float4* as2  = (float4*)(ws + 104000000);
  float4* ad2  = (float4*)(ws + 104800000);
  int* deg     = (int*)(ws + 105600000);
  int* cur     = (int*)(ws + 105800000);
  int* off     = (int*)(ws + 106000000);
  int* csr     = (int*)(ws + 106200016);
  int* segstart = (int*)(ws + 109600016);
  int* bsum    = (int*)(ws + 109802080);
  ushort_t* Wt1h = (ushort_t*)(ws + 105600000); // over deg+cur (dead after scatter)

  const int TB = 256;
  const int NB_SCAN = (NN + 1023) / 1024;

  k_zero2<<<(NN + TB - 1) / TB, TB, 0, stream>>>(deg, cur, NN);
  k_hist<<<(Etot + TB - 1) / TB, TB, 0, stream>>>(ei, deg, E, Etot);
  k_scan1<<<NB_SCAN, 1024, 0, stream>>>(deg, off, bsum, NN);
  k_scan2<<<1, 64, 0, stream>>>(bsum, off, NB_SCAN, NN);
  k_scan3<<<NB_SCAN, 1024, 0, stream>>>(off, bsum, NN);
  k_scatter<<<(Etot + TB - 1) / TB, TB, 0, stream>>>(ei, off, cur, csr, E, Etot);
  k_segstart<<<(NBGRAPH + 1 + TB - 1) / TB, TB, 0, stream>>>(batch, segstart, NN, NBGRAPH);

  // layer 1
  k_prepW<<<(DIN * DHID + TB - 1) / TB, TB, 0, stream>>>(W1, Wt1h, DIN, DHID);
  dim3 g1((NN + 63) / 64, DHID / 128);
  k_gemm1m<<<g1, TB, 0, stream>>>(x, Wt1h, H1h);
  k_scores1<<<(NN + 3) / 4, TB, 0, stream>>>(H1h, as1w, ad1w, as1, ad1);
  k_agg1<<<(NN + 15) / 16, TB, 0, stream>>>(off, csr, as1, ad1, H1h, b1, OUT1);

  // layer 2 (H1h dead now; Wt2h/R2/H2h may live in its region)
  k_prepW<<<((DHID + DIN) * DOUT + TB - 1) / TB, TB, 0, stream>>>(W2, Wt2h, DHID + DIN, DOUT);
  k_gemmR<<<NBGRAPH, TB, 0, stream>>>(x, segstart, Wt2h, R2);
  dim3 g2((NN + 63) / 64, 1);
  k_gemm2m<<<g2, TB, 0, stream>>>(OUT1, batch, Wt2h, R2, H2h);
  k_scores2<<<(NN + 3) / 4, TB, 0, stream>>>(H2h, as2w, ad2w, as2, ad2);
  k_agg2<<<(NN + 15) / 16, TB, 0, stream>>>(off, csr, as2, ad2, H2h, b2, OUT2);

  k_pool<<<NBGRAPH, TB, 0, stream>>>(segstart, OUT2, OUT1, out);
}

// Round 18
// 335.720 us; speedup vs baseline: 1.0323x; 1.0323x over previous
//
#include <hip/hip_runtime.h>

#define NN 50000
#define NBGRAPH 512
#define DIN 768
#define DHID 256
#define DOUT 128

typedef unsigned short ushort_t;
typedef __attribute__((ext_vector_type(4))) float f32x4;
typedef _Float16 f16_t;
typedef __attribute__((ext_vector_type(8))) _Float16 f16x8;

__device__ __forceinline__ float lrelu(float v) { return v > 0.f ? v : 0.2f * v; }

__device__ __forceinline__ float h2f_u(ushort_t u) { return (float)__builtin_bit_cast(f16_t, u); }
__device__ __forceinline__ ushort_t f2h_u(float f) { return __builtin_bit_cast(ushort_t, (f16_t)f); }

__device__ __forceinline__ float sel_h(int h, float q0, float q1, float q2, float q3) {
  float lo = (h & 1) ? q1 : q0;
  float hi = (h & 1) ? q3 : q2;
  return (h & 2) ? hi : lo;
}

__device__ __forceinline__ f16x8 cvt8(float4 u, float4 v) {
  unsigned int a = __builtin_bit_cast(unsigned int, __builtin_amdgcn_cvt_pkrtz(u.x, u.y));
  unsigned int b = __builtin_bit_cast(unsigned int, __builtin_amdgcn_cvt_pkrtz(u.z, u.w));
  unsigned int c = __builtin_bit_cast(unsigned int, __builtin_amdgcn_cvt_pkrtz(v.x, v.y));
  unsigned int d = __builtin_bit_cast(unsigned int, __builtin_amdgcn_cvt_pkrtz(v.z, v.w));
  uint4 q = {a, b, c, d};
  return __builtin_bit_cast(f16x8, q);
}
__device__ __forceinline__ f16x8 cvt8_relu(float4 u, float4 v) {
  u.x = fmaxf(u.x, 0.f); u.y = fmaxf(u.y, 0.f); u.z = fmaxf(u.z, 0.f); u.w = fmaxf(u.w, 0.f);
  v.x = fmaxf(v.x, 0.f); v.y = fmaxf(v.y, 0.f); v.z = fmaxf(v.z, 0.f); v.w = fmaxf(v.w, 0.f);
  return cvt8(u, v);
}

// ---------------- CSR build ----------------
__global__ void k_hist(const int* __restrict__ ei, int* __restrict__ deg, int E, int Etot) {
  int e = blockIdx.x * blockDim.x + threadIdx.x;
  if (e >= Etot) return;
  int dst = (e < E) ? ei[e] : (e - E);
  atomicAdd(&deg[dst], 1);
}

__global__ __launch_bounds__(1024) void k_scan1(const int* __restrict__ deg, int* __restrict__ off,
                                                int* __restrict__ bsum, int n) {
  __shared__ int wsum[16];
  int tid = threadIdx.x, lane = tid & 63, w = tid >> 6;
  int i = blockIdx.x * 1024 + tid;
  int v = (i < n) ? deg[i] : 0;
  int x = v;
#pragma unroll
  for (int d = 1; d < 64; d <<= 1) { int t = __shfl_up(x, d); if (lane >= d) x += t; }
  if (lane == 63) wsum[w] = x;
  __syncthreads();
  if (tid < 16) {
    int y = wsum[tid];
#pragma unroll
    for (int d = 1; d < 16; d <<= 1) { int t = __shfl_up(y, d); if (tid >= d) y += t; }
    wsum[tid] = y;
  }
  __syncthreads();
  int base = (w > 0) ? wsum[w - 1] : 0;
  if (i < n) off[i] = base + x - v;
  if (tid == 1023) bsum[blockIdx.x] = wsum[15];
}

__global__ void k_scan2(int* __restrict__ bsum, int* __restrict__ off, int nb, int n) {
  int lane = threadIdx.x;
  int v = (lane < nb) ? bsum[lane] : 0;
  int x = v;
#pragma unroll
  for (int d = 1; d < 64; d <<= 1) { int t = __shfl_up(x, d); if (lane >= d) x += t; }
  if (lane < nb) bsum[lane] = x - v;
  if (lane == 63) off[n] = x;
}

__global__ void k_scan3(int* __restrict__ off, const int* __restrict__ bsum, int n) {
  int i = blockIdx.x * blockDim.x + threadIdx.x;
  if (i < n) off[i] += bsum[i >> 10];
}

__global__ void k_scatter(const int* __restrict__ ei, const int* __restrict__ off,
                          int* __restrict__ cur, int* __restrict__ csr, int E, int Etot) {
  int e = blockIdx.x * blockDim.x + threadIdx.x;
  if (e >= Etot) return;
  int dst, src;
  if (e < E) { dst = ei[e]; src = ei[E + e]; }
  else       { dst = src = e - E; }
  int p = atomicAdd(&cur[dst], 1);
  csr[off[dst] + p] = src;
}

// ---------------- roots / segments ----------------
__global__ void k_segstart(const int* __restrict__ batch, int* __restrict__ segstart, int n, int b_cnt) {
  int b = blockIdx.x * blockDim.x + threadIdx.x;
  if (b > b_cnt) return;
  int lo = 0, hi = n;
  while (lo < hi) { int mid = (lo + hi) >> 1; if (batch[mid] < b) lo = mid + 1; else hi = mid; }
  segstart[b] = lo;
}

// ---------------- weight transpose+cast (fp16): Wt[n][k] = f16(W[k][n]) ----------------
__global__ void k_prepW(const float* __restrict__ W, ushort_t* __restrict__ Wt, int K, int N) {
  int id = blockIdx.x * blockDim.x + threadIdx.x;
  if (id >= K * N) return;
  int n = id / K, k = id - n * K;
  Wt[(size_t)n * K + k] = f2h_u(W[(size_t)k * N + n]);
}

// ---------------- GEMM1: BM=64, BN=128, BK=64, single-LDS, 2-deep reg prefetch ----------------
#define LDT2 72
__global__ __launch_bounds__(256) void k_gemm1m(const float* __restrict__ A,
                                                const ushort_t* __restrict__ Bt,
                                                ushort_t* __restrict__ C) {
  const int K = DIN, NC = DHID;
  __shared__ __align__(16) ushort_t As[64 * LDT2];
  __shared__ __align__(16) ushort_t Bs[128 * LDT2];
  const int tid = threadIdx.x;
  const int bm = blockIdx.x * 64;
  const int bn = blockIdx.y * 128;
  const int row = tid >> 2, q = tid & 3;
  const int arow = bm + row;
  const int r_c = arow < NN ? arow : NN - 1;
  const int wid = tid >> 6, lane = tid & 63;
  const int wr = (wid >> 1) * 32, wc = (wid & 1) * 64;
  const int fr = lane & 15, fg = lane >> 4;
  const float* aptr = &A[(size_t)r_c * K + q * 16];
  const int bc0 = tid >> 3, bk0 = tid & 7;
  const int bc1 = (tid + 256) >> 3, bk1 = (tid + 256) & 7;
  const int bc2 = (tid + 512) >> 3, bk2 = (tid + 512) & 7;
  const int bc3 = (tid + 768) >> 3, bk3 = (tid + 768) & 7;
  const ushort_t* bp0 = &Bt[(size_t)(bn + bc0) * K + bk0 * 8];
  const ushort_t* bp1 = &Bt[(size_t)(bn + bc1) * K + bk1 * 8];
  const ushort_t* bp2 = &Bt[(size_t)(bn + bc2) * K + bk2 * 8];
  const ushort_t* bp3 = &Bt[(size_t)(bn + bc3) * K + bk3 * 8];
  f32x4 acc[2][4] = {};

  float4 Pa0, Pa1, Pa2, Pa3; uint4 Pb0, Pb1, Pb2, Pb3;
  float4 Qa0, Qa1, Qa2, Qa3; uint4 Qb0, Qb1, Qb2, Qb3;

  auto loadP = [&](int kk) {
    const float4* s = (const float4*)(aptr + kk);
    Pa0 = s[0]; Pa1 = s[1]; Pa2 = s[2]; Pa3 = s[3];
    Pb0 = *(const uint4*)(bp0 + kk); Pb1 = *(const uint4*)(bp1 + kk);
    Pb2 = *(const uint4*)(bp2 + kk); Pb3 = *(const uint4*)(bp3 + kk);
  };
  auto loadQ = [&](int kk) {
    const float4* s = (const float4*)(aptr + kk);
    Qa0 = s[0]; Qa1 = s[1]; Qa2 = s[2]; Qa3 = s[3];
    Qb0 = *(const uint4*)(bp0 + kk); Qb1 = *(const uint4*)(bp1 + kk);
    Qb2 = *(const uint4*)(bp2 + kk); Qb3 = *(const uint4*)(bp3 + kk);
  };
  auto stage = [&](float4 a0, float4 a1, float4 a2, float4 a3,
                   uint4 b0, uint4 b1, uint4 b2, uint4 b3) {
    const int p = row * LDT2 + q * 16;
    *(f16x8*)&As[p + 0] = cvt8(a0, a1);
    *(f16x8*)&As[p + 8] = cvt8(a2, a3);
    *(uint4*)&Bs[bc0 * LDT2 + bk0 * 8] = b0;
    *(uint4*)&Bs[bc1 * LDT2 + bk1 * 8] = b1;
    *(uint4*)&Bs[bc2 * LDT2 + bk2 * 8] = b2;
    *(uint4*)&Bs[bc3 * LDT2 + bk3 * 8] = b3;
  };
  auto compute = [&]() {
#pragma unroll
    for (int kk = 0; kk < 64; kk += 32) {
      f16x8 af0 = *(const f16x8*)&As[(wr + fr) * LDT2 + kk + fg * 8];
      f16x8 af1 = *(const f16x8*)&As[(wr + 16 + fr) * LDT2 + kk + fg * 8];
      f16x8 bf0 = *(const f16x8*)&Bs[(wc + fr) * LDT2 + kk + fg * 8];
      f16x8 bf1 = *(const f16x8*)&Bs[(wc + 16 + fr) * LDT2 + kk + fg * 8];
      f16x8 bf2 = *(const f16x8*)&Bs[(wc + 32 + fr) * LDT2 + kk + fg * 8];
      f16x8 bf3 = *(const f16x8*)&Bs[(wc + 48 + fr) * LDT2 + kk + fg * 8];
      acc[0][0] = __builtin_amdgcn_mfma_f32_16x16x32_f16(af0, bf0, acc[0][0], 0, 0, 0);
      acc[0][1] = __builtin_amdgcn_mfma_f32_16x16x32_f16(af0, bf1, acc[0][1], 0, 0, 0);
      acc[0][2] = __builtin_amdgcn_mfma_f32_16x16x32_f16(af0, bf2, acc[0][2], 0, 0, 0);
      acc[0][3] = __builtin_amdgcn_mfma_f32_16x16x32_f16(af0, bf3, acc[0][3], 0, 0, 0);
      acc[1][0] = __builtin_amdgcn_mfma_f32_16x16x32_f16(af1, bf0, acc[1][0], 0, 0, 0);
      acc[1][1] = __builtin_amdgcn_mfma_f32_16x16x32_f16(af1, bf1, acc[1][1], 0, 0, 0);
      acc[1][2] = __builtin_amdgcn_mfma_f32_16x16x32_f16(af1, bf2, acc[1][2], 0, 0, 0);
      acc[1][3] = __builtin_amdgcn_mfma_f32_16x16x32_f16(af1, bf3, acc[1][3], 0, 0, 0);
    }
  };

  loadP(0);
  loadQ(64);
  for (int k0 = 0; k0 < K; k0 += 128) {
    stage(Pa0, Pa1, Pa2, Pa3, Pb0, Pb1, Pb2, Pb3);
    __syncthreads();
    if (k0 + 128 < K) loadP(k0 + 128);
    compute();
    __syncthreads();
    stage(Qa0, Qa1, Qa2, Qa3, Qb0, Qb1, Qb2, Qb3);
    __syncthreads();
    if (k0 + 192 < K) loadQ(k0 + 192);
    compute();
    __syncthreads();
  }
#pragma unroll
  for (int m = 0; m < 2; ++m)
#pragma unroll
    for (int n = 0; n < 4; ++n)
#pragma unroll
      for (int j = 0; j < 4; ++j) {
        int r = bm + wr + m * 16 + fg * 4 + j;
        if (r < NN) C[(size_t)r * NC + bn + wc + n * 16 + fr] = f2h_u(acc[m][n][j]);
      }
}

// ---------------- gemmR: R2[b][c] = relu(x[segstart[b]]) . W2[256:, c]  (512 graphs) ----------------
__global__ __launch_bounds__(256) void k_gemmR(const float* __restrict__ X,
                                               const int* __restrict__ segstart,
                                               const ushort_t* __restrict__ Wt2,
                                               float* __restrict__ R2) {
  __shared__ float part[2][128];
  const int b = blockIdx.x;
  const int t = threadIdx.x;
  const int c = t & 127, seg = t >> 7;
  int root = segstart[b];
  if (root >= NN) root = NN - 1;
  const float* xr = &X[(size_t)root * DIN + seg * 384];
  const ushort_t* wp = &Wt2[(size_t)c * (DHID + DIN) + DHID + seg * 384];
  float s = 0.f;
#pragma unroll 4
  for (int k = 0; k < 384; k += 4) {
    float4 xv = *(const float4*)&xr[k];
    ushort4 wv = *(const ushort4*)&wp[k];
    s += fmaxf(xv.x, 0.f) * h2f_u(wv.x);
    s += fmaxf(xv.y, 0.f) * h2f_u(wv.y);
    s += fmaxf(xv.z, 0.f) * h2f_u(wv.z);
    s += fmaxf(xv.w, 0.f) * h2f_u(wv.w);
  }
  part[seg][c] = s;
  __syncthreads();
  if (t < 128) R2[(size_t)b * DOUT + t] = part[0][t] + part[1][t];
}

// ---------------- GEMM2: K=256, 2-deep prefetch; epilogue adds R2 AND fuses scores2 ----------------
__global__ __launch_bounds__(256) void k_gemm2m(const float* __restrict__ OUT1,
                                                const int* __restrict__ batch,
                                                const ushort_t* __restrict__ Bt,
                                                const float* __restrict__ R2,
                                                const float* __restrict__ att_s,
                                                const float* __restrict__ att_d,
                                                ushort_t* __restrict__ C,
                                                float4* __restrict__ as_out,
                                                float4* __restrict__ ad_out) {
  const int K = DHID;           // 256
  const int KS = DHID + DIN;    // B row stride = 1024
  __shared__ __align__(16) ushort_t As[64 * LDT2];
  __shared__ __align__(16) ushort_t Bs[128 * LDT2];
  const int tid = threadIdx.x;
  const int bm = blockIdx.x * 64;
  const int row = tid >> 2, q = tid & 3;
  const int arow = bm + row;
  const int r_c = arow < NN ? arow : NN - 1;
  const int wid = tid >> 6, lane = tid & 63;
  const int wr = (wid >> 1) * 32, wc = (wid & 1) * 64;
  const int fr = lane & 15, fg = lane >> 4;
  const float* aptr = &OUT1[(size_t)r_c * DHID + q * 16];
  const int bc0 = tid >> 3, bk0 = tid & 7;
  const int bc1 = (tid + 256) >> 3, bk1 = (tid + 256) & 7;
  const int bc2 = (tid + 512) >> 3, bk2 = (tid + 512) & 7;
  const int bc3 = (tid + 768) >> 3, bk3 = (tid + 768) & 7;
  const ushort_t* bp0 = &Bt[(size_t)bc0 * KS + bk0 * 8];
  const ushort_t* bp1 = &Bt[(size_t)bc1 * KS + bk1 * 8];
  const ushort_t* bp2 = &Bt[(size_t)bc2 * KS + bk2 * 8];
  const ushort_t* bp3 = &Bt[(size_t)bc3 * KS + bk3 * 8];
  f32x4 acc[2][4] = {};

  float4 Pa0, Pa1, Pa2, Pa3; uint4 Pb0, Pb1, Pb2, Pb3;
  float4 Qa0, Qa1, Qa2, Qa3; uint4 Qb0, Qb1, Qb2, Qb3;

  auto loadP = [&](int kk) {
    const float4* s = (const float4*)(aptr + kk);
    Pa0 = s[0]; Pa1 = s[1]; Pa2 = s[2]; Pa3 = s[3];
    Pb0 = *(const uint4*)(bp0 + kk); Pb1 = *(const uint4*)(bp1 + kk);
    Pb2 = *(const uint4*)(bp2 + kk); Pb3 = *(const uint4*)(bp3 + kk);
  };
  auto loadQ = [&](int kk) {
    const float4* s = (const float4*)(aptr + kk);
    Qa0 = s[0]; Qa1 = s[1]; Qa2 = s[2]; Qa3 = s[3];
    Qb0 = *(const uint4*)(bp0 + kk); Qb1 = *(const uint4*)(bp1 + kk);
    Qb2 = *(const uint4*)(bp2 + kk); Qb3 = *(const uint4*)(bp3 + kk);
  };
  auto stage = [&](float4 a0, float4 a1, float4 a2, float4 a3,
                   uint4 b0, uint4 b1, uint4 b2, uint4 b3) {
    const int p = row * LDT2 + q * 16;
    *(f16x8*)&As[p + 0] = cvt8_relu(a0, a1);
    *(f16x8*)&As[p + 8] = cvt8_relu(a2, a3);
    *(uint4*)&Bs[bc0 * LDT2 + bk0 * 8] = b0;
    *(uint4*)&Bs[bc1 * LDT2 + bk1 * 8] = b1;
    *(uint4*)&Bs[bc2 * LDT2 + bk2 * 8] = b2;
    *(uint4*)&Bs[bc3 * LDT2 + bk3 * 8] = b3;
  };
  auto compute = [&]() {
#pragma unroll
    for (int kk = 0; kk < 64; kk += 32) {
      f16x8 af0 = *(const f16x8*)&As[(wr + fr) * LDT2 + kk + fg * 8];
      f16x8 af1 = *(const f16x8*)&As[(wr + 16 + fr) * LDT2 + kk + fg * 8];
      f16x8 bf0 = *(const f16x8*)&Bs[(wc + fr) * LDT2 + kk + fg * 8];
      f16x8 bf1 = *(const f16x8*)&Bs[(wc + 16 + fr) * LDT2 + kk + fg * 8];
      f16x8 bf2 = *(const f16x8*)&Bs[(wc + 32 + fr) * LDT2 + kk + fg * 8];
      f16x8 bf3 = *(const f16x8*)&Bs[(wc + 48 + fr) * LDT2 + kk + fg * 8];
      acc[0][0] = __builtin_amdgcn_mfma_f32_16x16x32_f16(af0, bf0, acc[0][0], 0, 0, 0);
      acc[0][1] = __builtin_amdgcn_mfma_f32_16x16x32_f16(af0, bf1, acc[0][1], 0, 0, 0);
      acc[0][2] = __builtin_amdgcn_mfma_f32_16x16x32_f16(af0, bf2, acc[0][2], 0, 0, 0);
      acc[0][3] = __builtin_amdgcn_mfma_f32_16x16x32_f16(af0, bf3, acc[0][3], 0, 0, 0);
      acc[1][0] = __builtin_amdgcn_mfma_f32_16x16x32_f16(af1, bf0, acc[1][0], 0, 0, 0);
      acc[1][1] = __builtin_amdgcn_mfma_f32_16x16x32_f16(af1, bf1, acc[1][1], 0, 0, 0);
      acc[1][2] = __builtin_amdgcn_mfma_f32_16x16x32_f16(af1, bf2, acc[1][2], 0, 0, 0);
      acc[1][3] = __builtin_amdgcn_mfma_f32_16x16x32_f16(af1, bf3, acc[1][3], 0, 0, 0);
    }
  };

  loadP(0);
  loadQ(64);
  for (int k0 = 0; k0 < K; k0 += 128) {
    stage(Pa0, Pa1, Pa2, Pa3, Pb0, Pb1, Pb2, Pb3);
    __syncthreads();
    if (k0 + 128 < K) loadP(k0 + 128);
    compute();
    __syncthreads();
    stage(Qa0, Qa1, Qa2, Qa3, Qb0, Qb1, Qb2, Qb3);
    __syncthreads();
    if (k0 + 192 < K) loadQ(k0 + 192);
    compute();
    __syncthreads();
  }

  // epilogue: v = acc + R2[batch[r]]; store f16 H2; fused per-head score dots.
  // Lane's cols: wc + n*16 + fr. Head of col = col>>5: n<2 -> head wc/32, n>=2 -> head wc/32+1.
  float as_c[4], ad_c[4];
#pragma unroll
  for (int n = 0; n < 4; ++n) {
    int col = wc + n * 16 + fr;
    as_c[n] = att_s[col];
    ad_c[n] = att_d[col];
  }
#pragma unroll
  for (int m = 0; m < 2; ++m)
#pragma unroll
    for (int j = 0; j < 4; ++j) {
      int r = bm + wr + m * 16 + fg * 4 + j;
      int rc = r < NN ? r : NN - 1;
      int gb = batch[rc];
      const float* r2 = &R2[(size_t)gb * DOUT];
      float v0 = acc[m][0][j] + r2[wc + fr];
      float v1 = acc[m][1][j] + r2[wc + 16 + fr];
      float v2 = acc[m][2][j] + r2[wc + 32 + fr];
      float v3 = acc[m][3][j] + r2[wc + 48 + fr];
      if (r < NN) {
        C[(size_t)r * DOUT + wc + fr] = f2h_u(v0);
        C[(size_t)r * DOUT + wc + 16 + fr] = f2h_u(v1);
        C[(size_t)r * DOUT + wc + 32 + fr] = f2h_u(v2);
        C[(size_t)r * DOUT + wc + 48 + fr] = f2h_u(v3);
      }
      float psl = v0 * as_c[0] + v1 * as_c[1];
      float psh = v2 * as_c[2] + v3 * as_c[3];
      float pdl = v0 * ad_c[0] + v1 * ad_c[1];
      float pdh = v2 * ad_c[2] + v3 * ad_c[3];
#pragma unroll
      for (int msk = 1; msk < 16; msk <<= 1) {
        psl += __shfl_xor(psl, msk);
        psh += __shfl_xor(psh, msk);
        pdl += __shfl_xor(pdl, msk);
        pdh += __shfl_xor(pdh, msk);
      }
      if (fr == m * 4 + j && r < NN) {
        float* sp = (float*)&as_out[r] + (wid & 1) * 2;
        float* dp = (float*)&ad_out[r] + (wid & 1) * 2;
        sp[0] = psl; sp[1] = psh;
        dp[0] = pdl; dp[1] = pdh;
      }
    }
}

// ---------------- attention scores, layer 1 (fp16 H) ----------------
__global__ __launch_bounds__(256) void k_scores1(const ushort_t* __restrict__ Hh,
                                                 const float* __restrict__ att_s,
                                                 const float* __restrict__ att_d,
                                                 float4* __restrict__ as_out,
                                                 float4* __restrict__ ad_out) {
  int lane = threadIdx.x & 63;
  int n = blockIdx.x * 4 + (threadIdx.x >> 6);
  if (n >= NN) return;
  ushort4 hv = *(const ushort4*)&Hh[(size_t)n * DHID + lane * 4];
  float h0 = h2f_u(hv.x), h1 = h2f_u(hv.y), h2 = h2f_u(hv.z), h3 = h2f_u(hv.w);
  float4 sa = *(const float4*)&att_s[lane * 4];
  float4 da = *(const float4*)&att_d[lane * 4];
  float ps = h0 * sa.x + h1 * sa.y + h2 * sa.z + h3 * sa.w;
  float pd = h0 * da.x + h1 * da.y + h2 * da.z + h3 * da.w;
#pragma unroll
  for (int m = 1; m < 16; m <<= 1) { ps += __shfl_xor(ps, m); pd += __shfl_xor(pd, m); }
  float4 rs, rd;
  rs.x = __shfl(ps, 0);  rd.x = __shfl(pd, 0);
  rs.y = __shfl(ps, 16); rd.y = __shfl(pd, 16);
  rs.z = __shfl(ps, 32); rd.z = __shfl(pd, 32);
  rs.w = __shfl(ps, 48); rd.w = __shfl(pd, 48);
  if (lane == 0) { as_out[n] = rs; ad_out[n] = rd; }
}

// ---------------- GAT aggregation, layer 1: one node per 16-lane group ----------------
__global__ __launch_bounds__(256) void k_agg1(const int* __restrict__ off, const int* __restrict__ csr,
                                              const float4* __restrict__ as_v, const float4* __restrict__ ad_v,
                                              const ushort_t* __restrict__ Hh, const float* __restrict__ bias,
                                              float* __restrict__ OUT) {
  __shared__ int s_tab[16][65];
  __shared__ __align__(16) float al_tab[16][260];
  const int tid = threadIdx.x;
  const int nd = tid >> 4;
  const int g = tid & 15;
  const int hd = g >> 2;
  const int n = blockIdx.x * 16 + nd;
  if (n >= NN) return;
  const int beg = off[n];
  const int nt = off[n + 1] - beg;
  const float4 adv = ad_v[n];

  float acc[16] = {};
  float rdh;

  if (nt <= 64) {
    float mx0 = -INFINITY, mx1 = -INFINITY, mx2 = -INFINITY, mx3 = -INFINITY;
    for (int le = g; le < nt; le += 16) {
      int s = csr[beg + le];
      float4 a = as_v[s];
      s_tab[nd][le] = s;
      *(float4*)&al_tab[nd][le << 2] = a;
      mx0 = fmaxf(mx0, a.x); mx1 = fmaxf(mx1, a.y);
      mx2 = fmaxf(mx2, a.z); mx3 = fmaxf(mx3, a.w);
    }
#pragma unroll
    for (int m = 1; m < 16; m <<= 1) {
      mx0 = fmaxf(mx0, __shfl_xor(mx0, m)); mx1 = fmaxf(mx1, __shfl_xor(mx1, m));
      mx2 = fmaxf(mx2, __shfl_xor(mx2, m)); mx3 = fmaxf(mx3, __shfl_xor(mx3, m));
    }
    float em0 = lrelu(mx0 + adv.x), em1 = lrelu(mx1 + adv.y);
    float em2 = lrelu(mx2 + adv.z), em3 = lrelu(mx3 + adv.w);
    float s0 = 0.f, s1 = 0.f, s2 = 0.f, s3 = 0.f;
    for (int le = g; le < nt; le += 16) {
      float4 a = *(const float4*)&al_tab[nd][le << 2];
      float p0 = __expf(lrelu(a.x + adv.x) - em0);
      float p1 = __expf(lrelu(a.y + adv.y) - em1);
      float p2 = __expf(lrelu(a.z + adv.z) - em2);
      float p3 = __expf(lrelu(a.w + adv.w) - em3);
      *(float4*)&al_tab[nd][le << 2] = make_float4(p0, p1, p2, p3);
      s0 += p0; s1 += p1; s2 += p2; s3 += p3;
    }
#pragma unroll
    for (int m = 1; m < 16; m <<= 1) {
      s0 += __shfl_xor(s0, m); s1 += __shfl_xor(s1, m);
      s2 += __shfl_xor(s2, m); s3 += __shfl_xor(s3, m);
    }
    rdh = sel_h(hd, 1.f / (s0 + 1e-16f), 1.f / (s1 + 1e-16f),
                    1.f / (s2 + 1e-16f), 1.f / (s3 + 1e-16f));

    int sP = s_tab[nd][0];
    float pP = al_tab[nd][hd];
    f16x8 v0 = *(const f16x8*)&Hh[(size_t)sP * DHID + g * 16];
    f16x8 v1 = *(const f16x8*)&Hh[(size_t)sP * DHID + g * 16 + 8];
    for (int e = 0; e < nt; ++e) {
      int en = (e + 1 < nt) ? e + 1 : e;
      int sN = s_tab[nd][en];
      float pN = al_tab[nd][(en << 2) | hd];
      f16x8 n0 = *(const f16x8*)&Hh[(size_t)sN * DHID + g * 16];
      f16x8 n1 = *(const f16x8*)&Hh[(size_t)sN * DHID + g * 16 + 8];
      float al = pP * rdh;
#pragma unroll
      for (int qq = 0; qq < 8; ++qq) acc[qq] += al * (float)v0[qq];
#pragma unroll
      for (int qq = 0; qq < 8; ++qq) acc[8 + qq] += al * (float)v1[qq];
      pP = pN; v0 = n0; v1 = n1;
    }
  } else {
    float mx0 = -INFINITY, mx1 = -INFINITY, mx2 = -INFINITY, mx3 = -INFINITY;
    for (int le = g; le < nt; le += 16) {
      float4 a = as_v[csr[beg + le]];
      mx0 = fmaxf(mx0, a.x); mx1 = fmaxf(mx1, a.y);
      mx2 = fmaxf(mx2, a.z); mx3 = fmaxf(mx3, a.w);
    }
#pragma unroll
    for (int m = 1; m < 16; m <<= 1) {
      mx0 = fmaxf(mx0, __shfl_xor(mx0, m)); mx1 = fmaxf(mx1, __shfl_xor(mx1, m));
      mx2 = fmaxf(mx2, __shfl_xor(mx2, m)); mx3 = fmaxf(mx3, __shfl_xor(mx3, m));
    }
    float em0 = lrelu(mx0 + adv.x), em1 = lrelu(mx1 + adv.y);
    float em2 = lrelu(mx2 + adv.z), em3 = lrelu(mx3 + adv.w);
    float s0 = 0.f, s1 = 0.f, s2 = 0.f, s3 = 0.f;
    for (int le = g; le < nt; le += 16) {
      float4 a = as_v[csr[beg + le]];
      s0 += __expf(lrelu(a.x + adv.x) - em0);
      s1 += __expf(lrelu(a.y + adv.y) - em1);
      s2 += __expf(lrelu(a.z + adv.z) - em2);
      s3 += __expf(lrelu(a.w + adv.w) - em3);
    }
#pragma unroll
    for (int m = 1; m < 16; m <<= 1) {
      s0 += __shfl_xor(s0, m); s1 += __shfl_xor(s1, m);
      s2 += __shfl_xor(s2, m); s3 += __shfl_xor(s3, m);
    }
    rdh = sel_h(hd, 1.f / (s0 + 1e-16f), 1.f / (s1 + 1e-16f),
                    1.f / (s2 + 1e-16f), 1.f / (s3 + 1e-16f));
    float adh = sel_h(hd, adv.x, adv.y, adv.z, adv.w);
    float emh = sel_h(hd, em0, em1, em2, em3);
    for (int e = 0; e < nt; ++e) {
      int s = csr[beg + e];
      float4 a = as_v[s];
      float ah = sel_h(hd, a.x, a.y, a.z, a.w);
      float al = __expf(lrelu(ah + adh) - emh) * rdh;
      f16x8 v0 = *(const f16x8*)&Hh[(size_t)s * DHID + g * 16];
      f16x8 v1 = *(const f16x8*)&Hh[(size_t)s * DHID + g * 16 + 8];
#pragma unroll
      for (int qq = 0; qq < 8; ++qq) acc[qq] += al * (float)v0[qq];
#pragma unroll
      for (int qq = 0; qq < 8; ++qq) acc[8 + qq] += al * (float)v1[qq];
    }
  }

  const float* bv = &bias[g * 16];
  float* ob = &OUT[(size_t)n * DHID + g * 16];
#pragma unroll
  for (int k = 0; k < 4; ++k) {
    float4 b4 = *(const float4*)&bv[k * 4];
    *(float4*)&ob[k * 4] = make_float4(acc[k * 4] + b4.x, acc[k * 4 + 1] + b4.y,
                                       acc[k * 4 + 2] + b4.z, acc[k * 4 + 3] + b4.w);
  }
}

// ---------------- GAT aggregation, layer 2: one node per 16-lane group ----------------
__global__ __launch_bounds__(256) void k_agg2(const int* __restrict__ off, const int* __restrict__ csr,
                                              const float4* __restrict__ as_v, const float4* __restrict__ ad_v,
                                              const ushort_t* __restrict__ Hh, const float* __restrict__ bias,
                                              float* __restrict__ OUT) {
  __shared__ int s_tab[16][65];
  __shared__ __align__(16) float al_tab[16][260];
  const int tid = threadIdx.x;
  const int nd = tid >> 4;
  const int g = tid & 15;
  const int hd = g >> 2;
  const int n = blockIdx.x * 16 + nd;
  if (n >= NN) return;
  const int beg = off[n];
  const int nt = off[n + 1] - beg;
  const float4 adv = ad_v[n];

  float acc[8] = {};
  float rdh;

  if (nt <= 64) {
    float mx0 = -INFINITY, mx1 = -INFINITY, mx2 = -INFINITY, mx3 = -INFINITY;
    for (int le = g; le < nt; le += 16) {
      int s = csr[beg + le];
      float4 a = as_v[s];
      s_tab[nd][le] = s;
      *(float4*)&al_tab[nd][le << 2] = a;
      mx0 = fmaxf(mx0, a.x); mx1 = fmaxf(mx1, a.y);
      mx2 = fmaxf(mx2, a.z); mx3 = fmaxf(mx3, a.w);
    }
#pragma unroll
    for (int m = 1; m < 16; m <<= 1) {
      mx0 = fmaxf(mx0, __shfl_xor(mx0, m)); mx1 = fmaxf(mx1, __shfl_xor(mx1, m));
      mx2 = fmaxf(mx2, __shfl_xor(mx2, m)); mx3 = fmaxf(mx3, __shfl_xor(mx3, m));
    }
    float em0 = lrelu(mx0 + adv.x), em1 = lrelu(mx1 + adv.y);
    float em2 = lrelu(mx2 + adv.z), em3 = lrelu(mx3 + adv.w);
    float s0 = 0.f, s1 = 0.f, s2 = 0.f, s3 = 0.f;
    for (int le = g; le < nt; le += 16) {
      float4 a = *(const float4*)&al_tab[nd][le << 2];
      float p0 = __expf(lrelu(a.x + adv.x) - em0);
      float p1 = __expf(lrelu(a.y + adv.y) - em1);
      float p2 = __expf(lrelu(a.z + adv.z) - em2);
      float p3 = __expf(lrelu(a.w + adv.w) - em3);
      *(float4*)&al_tab[nd][le << 2] = make_float4(p0, p1, p2, p3);
      s0 += p0; s1 += p1; s2 += p2; s3 += p3;
    }
#pragma unroll
    for (int m = 1; m < 16; m <<= 1) {
      s0 += __shfl_xor(s0, m); s1 += __shfl_xor(s1, m);
      s2 += __shfl_xor(s2, m); s3 += __shfl_xor(s3, m);
    }
    rdh = sel_h(hd, 1.f / (s0 + 1e-16f), 1.f / (s1 + 1e-16f),
                    1.f / (s2 + 1e-16f), 1.f / (s3 + 1e-16f));

    int sP = s_tab[nd][0];
    float pP = al_tab[nd][hd];
    f16x8 v0 = *(const f16x8*)&Hh[(size_t)sP * DOUT + g * 8];
    for (int e = 0; e < nt; ++e) {
      int en = (e + 1 < nt) ? e + 1 : e;
      int sN = s_tab[nd][en];
      float pN = al_tab[nd][(en << 2) | hd];
      f16x8 n0 = *(const f16x8*)&Hh[(size_t)sN * DOUT + g * 8];
      float al = pP * rdh;
#pragma unroll
      for (int qq = 0; qq < 8; ++qq) acc[qq] += al * (float)v0[qq];
      pP = pN; v0 = n0;
    }
  } else {
    float mx0 = -INFINITY, mx1 = -INFINITY, mx2 = -INFINITY, mx3 = -INFINITY;
    for (int le = g; le < nt; le += 16) {
      float4 a = as_v[csr[beg + le]];
      mx0 = fmaxf(mx0, a.x); mx1 = fmaxf(mx1, a.y);
      mx2 = fmaxf(mx2, a.z); mx3 = fmaxf(mx3, a.w);
    }
#pragma unroll
    for (int m = 1; m < 16; m <<= 1) {
      mx0 = fmaxf(mx0, __shfl_xor(mx0, m)); mx1 = fmaxf(mx1, __shfl_xor(mx1, m));
      mx2 = fmaxf(mx2, __shfl_xor(mx2, m)); mx3 = fmaxf(mx3, __shfl_xor(mx3, m));
    }
    float em0 = lrelu(mx0 + adv.x), em1 = lrelu(mx1 + adv.y);
    float em2 = lrelu(mx2 + adv.z), em3 = lrelu(mx3 + adv.w);
    float s0 = 0.f, s1 = 0.f, s2 = 0.f, s3 = 0.f;
    for (int le = g; le < nt; le += 16) {
      float4 a = as_v[csr[beg + le]];
      s0 += __expf(lrelu(a.x + adv.x) - em0);
      s1 += __expf(lrelu(a.y + adv.y) - em1);
      s2 += __expf(lrelu(a.z + adv.z) - em2);
      s3 += __expf(lrelu(a.w + adv.w) - em3);
    }
#pragma unroll
    for (int m = 1; m < 16; m <<= 1) {
      s0 += __shfl_xor(s0, m); s1 += __shfl_xor(s1, m);
      s2 += __shfl_xor(s2, m); s3 += __shfl_xor(s3, m);
    }
    rdh = sel_h(hd, 1.f / (s0 + 1e-16f), 1.f / (s1 + 1e-16f),
                    1.f / (s2 + 1e-16f), 1.f / (s3 + 1e-16f));
    float adh = sel_h(hd, adv.x, adv.y, adv.z, adv.w);
    float emh = sel_h(hd, em0, em1, em2, em3);
    for (int e = 0; e < nt; ++e) {
      int s = csr[beg + e];
      float4 a = as_v[s];
      float ah = sel_h(hd, a.x, a.y, a.z, a.w);
      float al = __expf(lrelu(ah + adh) - emh) * rdh;
      f16x8 v0 = *(const f16x8*)&Hh[(size_t)s * DOUT + g * 8];
#pragma unroll
      for (int qq = 0; qq < 8; ++qq) acc[qq] += al * (float)v0[qq];
    }
  }

  const float* bv = &bias[g * 8];
  float* ob = &OUT[(size_t)n * DOUT + g * 8];
#pragma unroll
  for (int k = 0; k < 2; ++k) {
    float4 b4 = *(const float4*)&bv[k * 4];
    *(float4*)&ob[k * 4] = make_float4(acc[k * 4] + b4.x, acc[k * 4 + 1] + b4.y,
                                       acc[k * 4 + 2] + b4.z, acc[k * 4 + 3] + b4.w);
  }
}

// ---------------- pooling (4-way ILP) ----------------
__global__ __launch_bounds__(256) void k_pool(const int* __restrict__ segstart,
                                              const float* __restrict__ OUT2,
                                              const float* __restrict__ OUT1,
                                              float* __restrict__ out) {
  int b = blockIdx.x;
  int t = threadIdx.x;
  int s = segstart[b], e = segstart[b + 1];
  float* ob = out + (size_t)b * 384;
  if (s >= e) {
    for (int i = t; i < 384; i += 256) ob[i] = 0.f;
    return;
  }
  if (t < 128) {
    float s0 = 0.f, s1 = 0.f, s2 = 0.f, s3 = 0.f;
    int n = s;
    for (; n + 3 < e; n += 4) {
      s0 += fmaxf(OUT2[(size_t)n * DOUT + t], 0.f);
      s1 += fmaxf(OUT2[(size_t)(n + 1) * DOUT + t], 0.f);
      s2 += fmaxf(OUT2[(size_t)(n + 2) * DOUT + t], 0.f);
      s3 += fmaxf(OUT2[(size_t)(n + 3) * DOUT + t], 0.f);
    }
    for (; n < e; ++n) s0 += fmaxf(OUT2[(size_t)n * DOUT + t], 0.f);
    ob[t] = ((s0 + s1) + (s2 + s3)) / (float)(e - s);
  } else {
    int k = t - 128;
    ob[128 + k] = OUT1[(size_t)s * DHID + k];
    ob[256 + k] = OUT1[(size_t)s * DHID + 128 + k];
  }
}

// ---------------- launch ----------------
extern "C" void kernel_launch(void* const* d_in, const int* in_sizes, int n_in,
                              void* d_out, int out_size, void* d_ws, size_t ws_size,
                              hipStream_t stream) {
  const float* x    = (const float*)d_in[0];
  const int*   ei   = (const int*)d_in[1];
  const int*   batch = (const int*)d_in[2];
  const float* W1   = (const float*)d_in[3];
  const float* as1w = (const float*)d_in[4];
  const float* ad1w = (const float*)d_in[5];
  const float* b1   = (const float*)d_in[6];
  const float* W2   = (const float*)d_in[7];
  const float* as2w = (const float*)d_in[8];
  const float* ad2w = (const float*)d_in[9];
  const float* b2   = (const float*)d_in[10];
  float* out = (float*)d_out;
  char* ws = (char*)d_ws;

  const int E = in_sizes[1] / 2;
  const int Etot = E + NN;

  // workspace layout (bytes). Wt2h/R2 live INSIDE the H1h region (0..25.6MB):
  // they are written only AFTER k_agg1 (H1h dead); H2h (0..12.8MB) stays below them.
  ushort_t* H1h = (ushort_t*)(ws + 0);        // NN*256*2 = 25.6 MB (dead after agg1)
  ushort_t* H2h = (ushort_t*)(ws + 0);        // NN*128*2 = 12.8 MB (aliases H1h)
  ushort_t* Wt2h = (ushort_t*)(ws + 13000000);// 262144 B (written AFTER agg1)
  float*  R2   = (float*)(ws + 14000000);     // 512*128*4 (written after agg1)
  float*  OUT2 = (float*)(ws + 25600000);
  float*  OUT1 = (float*)(ws + 51200000);
  float4* as1  = (float4*)(ws + 102400000);
  float4* ad1  = (float4*)(ws + 103200000);
  float4* as2  = (float4*)(ws + 104000000);
  float4* ad2  = (float4*)(ws + 104800000);
  int* deg     = (int*)(ws + 105600000);
  int* cur     = (int*)(ws + 105800000);
  int* off     = (int*)(ws + 106000000);
  int* csr     = (int*)(ws + 106200016);
  int* segstart = (int*)(ws + 109600016);
  int* bsum    = (int*)(ws + 109802080);
  ushort_t* Wt1h = (ushort_t*)(ws + 105600000); // over deg+cur (dead after scatter)

  const int TB = 256;
  const int NB_SCAN = (NN + 1023) / 1024;

  hipMemsetAsync(deg, 0, NN * sizeof(int), stream);
  hipMemsetAsync(cur, 0, NN * sizeof(int), stream);
  k_hist<<<(Etot + TB - 1) / TB, TB, 0, stream>>>(ei, deg, E, Etot);
  k_scan1<<<NB_SCAN, 1024, 0, stream>>>(deg, off, bsum, NN);
  k_scan2<<<1, 64, 0, stream>>>(bsum, off, NB_SCAN, NN);
  k_scan3<<<NB_SCAN, 1024, 0, stream>>>(off, bsum, NN);
  k_scatter<<<(Etot + TB - 1) / TB, TB, 0, stream>>>(ei, off, cur, csr, E, Etot);
  k_segstart<<<(NBGRAPH + 1 + TB - 1) / TB, TB, 0, stream>>>(batch, segstart, NN, NBGRAPH);

  // layer 1
  k_prepW<<<(DIN * DHID + TB - 1) / TB, TB, 0, stream>>>(W1, Wt1h, DIN, DHID);
  dim3 g1((NN + 63) / 64, DHID / 128);
  k_gemm1m<<<g1, TB, 0, stream>>>(x, Wt1h, H1h);
  k_scores1<<<(NN + 3) / 4, TB, 0, stream>>>(H1h, as1w, ad1w, as1, ad1);
  k_agg1<<<(NN + 15) / 16, TB, 0, stream>>>(off, csr, as1, ad1, H1h, b1, OUT1);

  // layer 2 (H1h dead now; Wt2h/R2/H2h live in its region). scores2 fused into gemm2m.
  k_prepW<<<((DHID + DIN) * DOUT + TB - 1) / TB, TB, 0, stream>>>(W2, Wt2h, DHID + DIN, DOUT);
  k_gemmR<<<NBGRAPH, TB, 0, stream>>>(x, segstart, Wt2h, R2);
  dim3 g2((NN + 63) / 64, 1);
  k_gemm2m<<<g2, TB, 0, stream>>>(OUT1, batch, Wt2h, R2, as2w, ad2w, H2h, as2, ad2);
  k_agg2<<<(NN + 15) / 16, TB, 0, stream>>>(off, csr, as2, ad2, H2h, b2, OUT2);

  k_pool<<<NBGRAPH, TB, 0, stream>>>(segstart, OUT2, OUT1, out);
}

// Round 19
// 334.591 us; speedup vs baseline: 1.0358x; 1.0034x over previous
//
#include <hip/hip_runtime.h>

#define NN 50000
#define NBGRAPH 512
#define DIN 768
#define DHID 256
#define DOUT 128

typedef unsigned short ushort_t;
typedef __attribute__((ext_vector_type(4))) float f32x4;
typedef _Float16 f16_t;
typedef __attribute__((ext_vector_type(8))) _Float16 f16x8;

__device__ __forceinline__ float lrelu(float v) { return v > 0.f ? v : 0.2f * v; }

__device__ __forceinline__ float h2f_u(ushort_t u) { return (float)__builtin_bit_cast(f16_t, u); }
__device__ __forceinline__ ushort_t f2h_u(float f) { return __builtin_bit_cast(ushort_t, (f16_t)f); }

__device__ __forceinline__ float sel_h(int h, float q0, float q1, float q2, float q3) {
  float lo = (h & 1) ? q1 : q0;
  float hi = (h & 1) ? q3 : q2;
  return (h & 2) ? hi : lo;
}

__device__ __forceinline__ f16x8 cvt8(float4 u, float4 v) {
  unsigned int a = __builtin_bit_cast(unsigned int, __builtin_amdgcn_cvt_pkrtz(u.x, u.y));
  unsigned int b = __builtin_bit_cast(unsigned int, __builtin_amdgcn_cvt_pkrtz(u.z, u.w));
  unsigned int c = __builtin_bit_cast(unsigned int, __builtin_amdgcn_cvt_pkrtz(v.x, v.y));
  unsigned int d = __builtin_bit_cast(unsigned int, __builtin_amdgcn_cvt_pkrtz(v.z, v.w));
  uint4 q = {a, b, c, d};
  return __builtin_bit_cast(f16x8, q);
}
__device__ __forceinline__ f16x8 cvt8_relu(float4 u, float4 v) {
  u.x = fmaxf(u.x, 0.f); u.y = fmaxf(u.y, 0.f); u.z = fmaxf(u.z, 0.f); u.w = fmaxf(u.w, 0.f);
  v.x = fmaxf(v.x, 0.f); v.y = fmaxf(v.y, 0.f); v.z = fmaxf(v.z, 0.f); v.w = fmaxf(v.w, 0.f);
  return cvt8(u, v);
}

// ---------------- CSR build ----------------
__global__ void k_hist(const int* __restrict__ ei, int* __restrict__ deg, int E, int Etot) {
  int e = blockIdx.x * blockDim.x + threadIdx.x;
  if (e >= Etot) return;
  int dst = (e < E) ? ei[e] : (e - E);
  atomicAdd(&deg[dst], 1);
}

__global__ __launch_bounds__(1024) void k_scan1(const int* __restrict__ deg, int* __restrict__ off,
                                                int* __restrict__ bsum, int n) {
  __shared__ int wsum[16];
  int tid = threadIdx.x, lane = tid & 63, w = tid >> 6;
  int i = blockIdx.x * 1024 + tid;
  int v = (i < n) ? deg[i] : 0;
  int x = v;
#pragma unroll
  for (int d = 1; d < 64; d <<= 1) { int t = __shfl_up(x, d); if (lane >= d) x += t; }
  if (lane == 63) wsum[w] = x;
  __syncthreads();
  if (tid < 16) {
    int y = wsum[tid];
#pragma unroll
    for (int d = 1; d < 16; d <<= 1) { int t = __shfl_up(y, d); if (tid >= d) y += t; }
    wsum[tid] = y;
  }
  __syncthreads();
  int base = (w > 0) ? wsum[w - 1] : 0;
  if (i < n) off[i] = base + x - v;
  if (tid == 1023) bsum[blockIdx.x] = wsum[15];
}

__global__ void k_scan2(int* __restrict__ bsum, int* __restrict__ off, int nb, int n) {
  int lane = threadIdx.x;
  int v = (lane < nb) ? bsum[lane] : 0;
  int x = v;
#pragma unroll
  for (int d = 1; d < 64; d <<= 1) { int t = __shfl_up(x, d); if (lane >= d) x += t; }
  if (lane < nb) bsum[lane] = x - v;
  if (lane == 63) off[n] = x;
}

__global__ void k_scan3(int* __restrict__ off, const int* __restrict__ bsum, int n) {
  int i = blockIdx.x * blockDim.x + threadIdx.x;
  if (i < n) off[i] += bsum[i >> 10];
}

__global__ void k_scatter(const int* __restrict__ ei, const int* __restrict__ off,
                          int* __restrict__ cur, int* __restrict__ csr, int E, int Etot) {
  int e = blockIdx.x * blockDim.x + threadIdx.x;
  if (e >= Etot) return;
  int dst, src;
  if (e < E) { dst = ei[e]; src = ei[E + e]; }
  else       { dst = src = e - E; }
  int p = atomicAdd(&cur[dst], 1);
  csr[off[dst] + p] = src;
}

// ---------------- roots / segments ----------------
__global__ void k_segstart(const int* __restrict__ batch, int* __restrict__ segstart, int n, int b_cnt) {
  int b = blockIdx.x * blockDim.x + threadIdx.x;
  if (b > b_cnt) return;
  int lo = 0, hi = n;
  while (lo < hi) { int mid = (lo + hi) >> 1; if (batch[mid] < b) lo = mid + 1; else hi = mid; }
  segstart[b] = lo;
}

// ---------------- weight transpose+cast (fp16): Wt[n][k] = f16(W[k][n]) ----------------
__global__ void k_prepW(const float* __restrict__ W, ushort_t* __restrict__ Wt, int K, int N) {
  int id = blockIdx.x * blockDim.x + threadIdx.x;
  if (id >= K * N) return;
  int n = id / K, k = id - n * K;
  Wt[(size_t)n * K + k] = f2h_u(W[(size_t)k * N + n]);
}

// ---------------- GEMM1: BM=64, BN=128, BK=64; epilogue fuses scores1 ----------------
#define LDT2 72
__global__ __launch_bounds__(256) void k_gemm1m(const float* __restrict__ A,
                                                const ushort_t* __restrict__ Bt,
                                                const float* __restrict__ att_s,
                                                const float* __restrict__ att_d,
                                                ushort_t* __restrict__ C,
                                                float4* __restrict__ as_out,
                                                float4* __restrict__ ad_out) {
  const int K = DIN, NC = DHID;
  __shared__ __align__(16) ushort_t As[64 * LDT2];
  __shared__ __align__(16) ushort_t Bs[128 * LDT2];
  const int tid = threadIdx.x;
  const int bm = blockIdx.x * 64;
  const int bn = blockIdx.y * 128;
  const int row = tid >> 2, q = tid & 3;
  const int arow = bm + row;
  const int r_c = arow < NN ? arow : NN - 1;
  const int wid = tid >> 6, lane = tid & 63;
  const int wr = (wid >> 1) * 32, wc = (wid & 1) * 64;
  const int fr = lane & 15, fg = lane >> 4;
  const float* aptr = &A[(size_t)r_c * K + q * 16];
  const int bc0 = tid >> 3, bk0 = tid & 7;
  const int bc1 = (tid + 256) >> 3, bk1 = (tid + 256) & 7;
  const int bc2 = (tid + 512) >> 3, bk2 = (tid + 512) & 7;
  const int bc3 = (tid + 768) >> 3, bk3 = (tid + 768) & 7;
  const ushort_t* bp0 = &Bt[(size_t)(bn + bc0) * K + bk0 * 8];
  const ushort_t* bp1 = &Bt[(size_t)(bn + bc1) * K + bk1 * 8];
  const ushort_t* bp2 = &Bt[(size_t)(bn + bc2) * K + bk2 * 8];
  const ushort_t* bp3 = &Bt[(size_t)(bn + bc3) * K + bk3 * 8];
  f32x4 acc[2][4] = {};

  float4 Pa0, Pa1, Pa2, Pa3; uint4 Pb0, Pb1, Pb2, Pb3;
  float4 Qa0, Qa1, Qa2, Qa3; uint4 Qb0, Qb1, Qb2, Qb3;

  auto loadP = [&](int kk) {
    const float4* s = (const float4*)(aptr + kk);
    Pa0 = s[0]; Pa1 = s[1]; Pa2 = s[2]; Pa3 = s[3];
    Pb0 = *(const uint4*)(bp0 + kk); Pb1 = *(const uint4*)(bp1 + kk);
    Pb2 = *(const uint4*)(bp2 + kk); Pb3 = *(const uint4*)(bp3 + kk);
  };
  auto loadQ = [&](int kk) {
    const float4* s = (const float4*)(aptr + kk);
    Qa0 = s[0]; Qa1 = s[1]; Qa2 = s[2]; Qa3 = s[3];
    Qb0 = *(const uint4*)(bp0 + kk); Qb1 = *(const uint4*)(bp1 + kk);
    Qb2 = *(const uint4*)(bp2 + kk); Qb3 = *(const uint4*)(bp3 + kk);
  };
  auto stage = [&](float4 a0, float4 a1, float4 a2, float4 a3,
                   uint4 b0, uint4 b1, uint4 b2, uint4 b3) {
    const int p = row * LDT2 + q * 16;
    *(f16x8*)&As[p + 0] = cvt8(a0, a1);
    *(f16x8*)&As[p + 8] = cvt8(a2, a3);
    *(uint4*)&Bs[bc0 * LDT2 + bk0 * 8] = b0;
    *(uint4*)&Bs[bc1 * LDT2 + bk1 * 8] = b1;
    *(uint4*)&Bs[bc2 * LDT2 + bk2 * 8] = b2;
    *(uint4*)&Bs[bc3 * LDT2 + bk3 * 8] = b3;
  };
  auto compute = [&]() {
#pragma unroll
    for (int kk = 0; kk < 64; kk += 32) {
      f16x8 af0 = *(const f16x8*)&As[(wr + fr) * LDT2 + kk + fg * 8];
      f16x8 af1 = *(const f16x8*)&As[(wr + 16 + fr) * LDT2 + kk + fg * 8];
      f16x8 bf0 = *(const f16x8*)&Bs[(wc + fr) * LDT2 + kk + fg * 8];
      f16x8 bf1 = *(const f16x8*)&Bs[(wc + 16 + fr) * LDT2 + kk + fg * 8];
      f16x8 bf2 = *(const f16x8*)&Bs[(wc + 32 + fr) * LDT2 + kk + fg * 8];
      f16x8 bf3 = *(const f16x8*)&Bs[(wc + 48 + fr) * LDT2 + kk + fg * 8];
      acc[0][0] = __builtin_amdgcn_mfma_f32_16x16x32_f16(af0, bf0, acc[0][0], 0, 0, 0);
      acc[0][1] = __builtin_amdgcn_mfma_f32_16x16x32_f16(af0, bf1, acc[0][1], 0, 0, 0);
      acc[0][2] = __builtin_amdgcn_mfma_f32_16x16x32_f16(af0, bf2, acc[0][2], 0, 0, 0);
      acc[0][3] = __builtin_amdgcn_mfma_f32_16x16x32_f16(af0, bf3, acc[0][3], 0, 0, 0);
      acc[1][0] = __builtin_amdgcn_mfma_f32_16x16x32_f16(af1, bf0, acc[1][0], 0, 0, 0);
      acc[1][1] = __builtin_amdgcn_mfma_f32_16x16x32_f16(af1, bf1, acc[1][1], 0, 0, 0);
      acc[1][2] = __builtin_amdgcn_mfma_f32_16x16x32_f16(af1, bf2, acc[1][2], 0, 0, 0);
      acc[1][3] = __builtin_amdgcn_mfma_f32_16x16x32_f16(af1, bf3, acc[1][3], 0, 0, 0);
    }
  };

  loadP(0);
  loadQ(64);
  for (int k0 = 0; k0 < K; k0 += 128) {
    stage(Pa0, Pa1, Pa2, Pa3, Pb0, Pb1, Pb2, Pb3);
    __syncthreads();
    if (k0 + 128 < K) loadP(k0 + 128);
    compute();
    __syncthreads();
    stage(Qa0, Qa1, Qa2, Qa3, Qb0, Qb1, Qb2, Qb3);
    __syncthreads();
    if (k0 + 192 < K) loadQ(k0 + 192);
    compute();
    __syncthreads();
  }

  // epilogue: store f16 H1 + fused scores1.
  // This wave's 4 n-columns (bn+wc+n*16+fr) all lie in head h = (bn+wc)>>6.
  const int h = (bn + wc) >> 6;
  float as_c[4], ad_c[4];
#pragma unroll
  for (int n = 0; n < 4; ++n) {
    int col = bn + wc + n * 16 + fr;
    as_c[n] = att_s[col];
    ad_c[n] = att_d[col];
  }
#pragma unroll
  for (int m = 0; m < 2; ++m)
#pragma unroll
    for (int j = 0; j < 4; ++j) {
      int r = bm + wr + m * 16 + fg * 4 + j;
      float v0 = acc[m][0][j], v1 = acc[m][1][j], v2 = acc[m][2][j], v3 = acc[m][3][j];
      if (r < NN) {
        C[(size_t)r * NC + bn + wc + fr] = f2h_u(v0);
        C[(size_t)r * NC + bn + wc + 16 + fr] = f2h_u(v1);
        C[(size_t)r * NC + bn + wc + 32 + fr] = f2h_u(v2);
        C[(size_t)r * NC + bn + wc + 48 + fr] = f2h_u(v3);
      }
      float ps = v0 * as_c[0] + v1 * as_c[1] + v2 * as_c[2] + v3 * as_c[3];
      float pd = v0 * ad_c[0] + v1 * ad_c[1] + v2 * ad_c[2] + v3 * ad_c[3];
#pragma unroll
      for (int msk = 1; msk < 16; msk <<= 1) {
        ps += __shfl_xor(ps, msk);
        pd += __shfl_xor(pd, msk);
      }
      if (fr == m * 4 + j && r < NN) {
        ((float*)&as_out[r])[h] = ps;
        ((float*)&ad_out[r])[h] = pd;
      }
    }
}

// ---------------- gemmR: R2[b][c] = relu(x[segstart[b]]) . W2[256:, c]  (512 graphs) ----------------
__global__ __launch_bounds__(256) void k_gemmR(const float* __restrict__ X,
                                               const int* __restrict__ segstart,
                                               const ushort_t* __restrict__ Wt2,
                                               float* __restrict__ R2) {
  __shared__ float part[2][128];
  const int b = blockIdx.x;
  const int t = threadIdx.x;
  const int c = t & 127, seg = t >> 7;
  int root = segstart[b];
  if (root >= NN) root = NN - 1;
  const float* xr = &X[(size_t)root * DIN + seg * 384];
  const ushort_t* wp = &Wt2[(size_t)c * (DHID + DIN) + DHID + seg * 384];
  float s = 0.f;
#pragma unroll 4
  for (int k = 0; k < 384; k += 4) {
    float4 xv = *(const float4*)&xr[k];
    ushort4 wv = *(const ushort4*)&wp[k];
    s += fmaxf(xv.x, 0.f) * h2f_u(wv.x);
    s += fmaxf(xv.y, 0.f) * h2f_u(wv.y);
    s += fmaxf(xv.z, 0.f) * h2f_u(wv.z);
    s += fmaxf(xv.w, 0.f) * h2f_u(wv.w);
  }
  part[seg][c] = s;
  __syncthreads();
  if (t < 128) R2[(size_t)b * DOUT + t] = part[0][t] + part[1][t];
}

// ---------------- GEMM2: K=256, 2-deep prefetch; epilogue adds R2 AND fuses scores2 ----------------
__global__ __launch_bounds__(256) void k_gemm2m(const float* __restrict__ OUT1,
                                                const int* __restrict__ batch,
                                                const ushort_t* __restrict__ Bt,
                                                const float* __restrict__ R2,
                                                const float* __restrict__ att_s,
                                                const float* __restrict__ att_d,
                                                ushort_t* __restrict__ C,
                                                float4* __restrict__ as_out,
                                                float4* __restrict__ ad_out) {
  const int K = DHID;           // 256
  const int KS = DHID + DIN;    // B row stride = 1024
  __shared__ __align__(16) ushort_t As[64 * LDT2];
  __shared__ __align__(16) ushort_t Bs[128 * LDT2];
  const int tid = threadIdx.x;
  const int bm = blockIdx.x * 64;
  const int row = tid >> 2, q = tid & 3;
  const int arow = bm + row;
  const int r_c = arow < NN ? arow : NN - 1;
  const int wid = tid >> 6, lane = tid & 63;
  const int wr = (wid >> 1) * 32, wc = (wid & 1) * 64;
  const int fr = lane & 15, fg = lane >> 4;
  const float* aptr = &OUT1[(size_t)r_c * DHID + q * 16];
  const int bc0 = tid >> 3, bk0 = tid & 7;
  const int bc1 = (tid + 256) >> 3, bk1 = (tid + 256) & 7;
  const int bc2 = (tid + 512) >> 3, bk2 = (tid + 512) & 7;
  const int bc3 = (tid + 768) >> 3, bk3 = (tid + 768) & 7;
  const ushort_t* bp0 = &Bt[(size_t)bc0 * KS + bk0 * 8];
  const ushort_t* bp1 = &Bt[(size_t)bc1 * KS + bk1 * 8];
  const ushort_t* bp2 = &Bt[(size_t)bc2 * KS + bk2 * 8];
  const ushort_t* bp3 = &Bt[(size_t)bc3 * KS + bk3 * 8];
  f32x4 acc[2][4] = {};

  float4 Pa0, Pa1, Pa2, Pa3; uint4 Pb0, Pb1, Pb2, Pb3;
  float4 Qa0, Qa1, Qa2, Qa3; uint4 Qb0, Qb1, Qb2, Qb3;

  auto loadP = [&](int kk) {
    const float4* s = (const float4*)(aptr + kk);
    Pa0 = s[0]; Pa1 = s[1]; Pa2 = s[2]; Pa3 = s[3];
    Pb0 = *(const uint4*)(bp0 + kk); Pb1 = *(const uint4*)(bp1 + kk);
    Pb2 = *(const uint4*)(bp2 + kk); Pb3 = *(const uint4*)(bp3 + kk);
  };
  auto loadQ = [&](int kk) {
    const float4* s = (const float4*)(aptr + kk);
    Qa0 = s[0]; Qa1 = s[1]; Qa2 = s[2]; Qa3 = s[3];
    Qb0 = *(const uint4*)(bp0 + kk); Qb1 = *(const uint4*)(bp1 + kk);
    Qb2 = *(const uint4*)(bp2 + kk); Qb3 = *(const uint4*)(bp3 + kk);
  };
  auto stage = [&](float4 a0, float4 a1, float4 a2, float4 a3,
                   uint4 b0, uint4 b1, uint4 b2, uint4 b3) {
    const int p = row * LDT2 + q * 16;
    *(f16x8*)&As[p + 0] = cvt8_relu(a0, a1);
    *(f16x8*)&As[p + 8] = cvt8_relu(a2, a3);
    *(uint4*)&Bs[bc0 * LDT2 + bk0 * 8] = b0;
    *(uint4*)&Bs[bc1 * LDT2 + bk1 * 8] = b1;
    *(uint4*)&Bs[bc2 * LDT2 + bk2 * 8] = b2;
    *(uint4*)&Bs[bc3 * LDT2 + bk3 * 8] = b3;
  };
  auto compute = [&]() {
#pragma unroll
    for (int kk = 0; kk < 64; kk += 32) {
      f16x8 af0 = *(const f16x8*)&As[(wr + fr) * LDT2 + kk + fg * 8];
      f16x8 af1 = *(const f16x8*)&As[(wr + 16 + fr) * LDT2 + kk + fg * 8];
      f16x8 bf0 = *(const f16x8*)&Bs[(wc + fr) * LDT2 + kk + fg * 8];
      f16x8 bf1 = *(const f16x8*)&Bs[(wc + 16 + fr) * LDT2 + kk + fg * 8];
      f16x8 bf2 = *(const f16x8*)&Bs[(wc + 32 + fr) * LDT2 + kk + fg * 8];
      f16x8 bf3 = *(const f16x8*)&Bs[(wc + 48 + fr) * LDT2 + kk + fg * 8];
      acc[0][0] = __builtin_amdgcn_mfma_f32_16x16x32_f16(af0, bf0, acc[0][0], 0, 0, 0);
      acc[0][1] = __builtin_amdgcn_mfma_f32_16x16x32_f16(af0, bf1, acc[0][1], 0, 0, 0);
      acc[0][2] = __builtin_amdgcn_mfma_f32_16x16x32_f16(af0, bf2, acc[0][2], 0, 0, 0);
      acc[0][3] = __builtin_amdgcn_mfma_f32_16x16x32_f16(af0, bf3, acc[0][3], 0, 0, 0);
      acc[1][0] = __builtin_amdgcn_mfma_f32_16x16x32_f16(af1, bf0, acc[1][0], 0, 0, 0);
      acc[1][1] = __builtin_amdgcn_mfma_f32_16x16x32_f16(af1, bf1, acc[1][1], 0, 0, 0);
      acc[1][2] = __builtin_amdgcn_mfma_f32_16x16x32_f16(af1, bf2, acc[1][2], 0, 0, 0);
      acc[1][3] = __builtin_amdgcn_mfma_f32_16x16x32_f16(af1, bf3, acc[1][3], 0, 0, 0);
    }
  };

  loadP(0);
  loadQ(64);
  for (int k0 = 0; k0 < K; k0 += 128) {
    stage(Pa0, Pa1, Pa2, Pa3, Pb0, Pb1, Pb2, Pb3);
    __syncthreads();
    if (k0 + 128 < K) loadP(k0 + 128);
    compute();
    __syncthreads();
    stage(Qa0, Qa1, Qa2, Qa3, Qb0, Qb1, Qb2, Qb3);
    __syncthreads();
    if (k0 + 192 < K) loadQ(k0 + 192);
    compute();
    __syncthreads();
  }

  // epilogue: v = acc + R2[batch[r]]; store f16 H2; fused per-head score dots.
  float as_c[4], ad_c[4];
#pragma unroll
  for (int n = 0; n < 4; ++n) {
    int col = wc + n * 16 + fr;
    as_c[n] = att_s[col];
    ad_c[n] = att_d[col];
  }
#pragma unroll
  for (int m = 0; m < 2; ++m)
#pragma unroll
    for (int j = 0; j < 4; ++j) {
      int r = bm + wr + m * 16 + fg * 4 + j;
      int rc = r < NN ? r : NN - 1;
      int gb = batch[rc];
      const float* r2 = &R2[(size_t)gb * DOUT];
      float v0 = acc[m][0][j] + r2[wc + fr];
      float v1 = acc[m][1][j] + r2[wc + 16 + fr];
      float v2 = acc[m][2][j] + r2[wc + 32 + fr];
      float v3 = acc[m][3][j] + r2[wc + 48 + fr];
      if (r < NN) {
        C[(size_t)r * DOUT + wc + fr] = f2h_u(v0);
        C[(size_t)r * DOUT + wc + 16 + fr] = f2h_u(v1);
        C[(size_t)r * DOUT + wc + 32 + fr] = f2h_u(v2);
        C[(size_t)r * DOUT + wc + 48 + fr] = f2h_u(v3);
      }
      float psl = v0 * as_c[0] + v1 * as_c[1];
      float psh = v2 * as_c[2] + v3 * as_c[3];
      float pdl = v0 * ad_c[0] + v1 * ad_c[1];
      float pdh = v2 * ad_c[2] + v3 * ad_c[3];
#pragma unroll
      for (int msk = 1; msk < 16; msk <<= 1) {
        psl += __shfl_xor(psl, msk);
        psh += __shfl_xor(psh, msk);
        pdl += __shfl_xor(pdl, msk);
        pdh += __shfl_xor(pdh, msk);
      }
      if (fr == m * 4 + j && r < NN) {
        float* sp = (float*)&as_out[r] + (wid & 1) * 2;
        float* dp = (float*)&ad_out[r] + (wid & 1) * 2;
        sp[0] = psl; sp[1] = psh;
        dp[0] = pdl; dp[1] = pdh;
      }
    }
}

// ---------------- GAT aggregation, layer 1: one node per 16-lane group ----------------
__global__ __launch_bounds__(256) void k_agg1(const int* __restrict__ off, const int* __restrict__ csr,
                                              const float4* __restrict__ as_v, const float4* __restrict__ ad_v,
                                              const ushort_t* __restrict__ Hh, const float* __restrict__ bias,
                                              float* __restrict__ OUT) {
  __shared__ int s_tab[16][65];
  __shared__ __align__(16) float al_tab[16][260];
  const int tid = threadIdx.x;
  const int nd = tid >> 4;
  const int g = tid & 15;
  const int hd = g >> 2;
  const int n = blockIdx.x * 16 + nd;
  if (n >= NN) return;
  const int beg = off[n];
  const int nt = off[n + 1] - beg;
  const float4 adv = ad_v[n];

  float acc[16] = {};
  float rdh;

  if (nt <= 64) {
    float mx0 = -INFINITY, mx1 = -INFINITY, mx2 = -INFINITY, mx3 = -INFINITY;
    for (int le = g; le < nt; le += 16) {
      int s = csr[beg + le];
      float4 a = as_v[s];
      s_tab[nd][le] = s;
      *(float4*)&al_tab[nd][le << 2] = a;
      mx0 = fmaxf(mx0, a.x); mx1 = fmaxf(mx1, a.y);
      mx2 = fmaxf(mx2, a.z); mx3 = fmaxf(mx3, a.w);
    }
#pragma unroll
    for (int m = 1; m < 16; m <<= 1) {
      mx0 = fmaxf(mx0, __shfl_xor(mx0, m)); mx1 = fmaxf(mx1, __shfl_xor(mx1, m));
      mx2 = fmaxf(mx2, __shfl_xor(mx2, m)); mx3 = fmaxf(mx3, __shfl_xor(mx3, m));
    }
    float em0 = lrelu(mx0 + adv.x), em1 = lrelu(mx1 + adv.y);
    float em2 = lrelu(mx2 + adv.z), em3 = lrelu(mx3 + adv.w);
    float s0 = 0.f, s1 = 0.f, s2 = 0.f, s3 = 0.f;
    for (int le = g; le < nt; le += 16) {
      float4 a = *(const float4*)&al_tab[nd][le << 2];
      float p0 = __expf(lrelu(a.x + adv.x) - em0);
      float p1 = __expf(lrelu(a.y + adv.y) - em1);
      float p2 = __expf(lrelu(a.z + adv.z) - em2);
      float p3 = __expf(lrelu(a.w + adv.w) - em3);
      *(float4*)&al_tab[nd][le << 2] = make_float4(p0, p1, p2, p3);
      s0 += p0; s1 += p1; s2 += p2; s3 += p3;
    }
#pragma unroll
    for (int m = 1; m < 16; m <<= 1) {
      s0 += __shfl_xor(s0, m); s1 += __shfl_xor(s1, m);
      s2 += __shfl_xor(s2, m); s3 += __shfl_xor(s3, m);
    }
    rdh = sel_h(hd, 1.f / (s0 + 1e-16f), 1.f / (s1 + 1e-16f),
                    1.f / (s2 + 1e-16f), 1.f / (s3 + 1e-16f));

    int sP = s_tab[nd][0];
    float pP = al_tab[nd][hd];
    f16x8 v0 = *(const f16x8*)&Hh[(size_t)sP * DHID + g * 16];
    f16x8 v1 = *(const f16x8*)&Hh[(size_t)sP * DHID + g * 16 + 8];
    for (int e = 0; e < nt; ++e) {
      int en = (e + 1 < nt) ? e + 1 : e;
      int sN = s_tab[nd][en];
      float pN = al_tab[nd][(en << 2) | hd];
      f16x8 n0 = *(const f16x8*)&Hh[(size_t)sN * DHID + g * 16];
      f16x8 n1 = *(const f16x8*)&Hh[(size_t)sN * DHID + g * 16 + 8];
      float al = pP * rdh;
#pragma unroll
      for (int qq = 0; qq < 8; ++qq) acc[qq] += al * (float)v0[qq];
#pragma unroll
      for (int qq = 0; qq < 8; ++qq) acc[8 + qq] += al * (float)v1[qq];
      pP = pN; v0 = n0; v1 = n1;
    }
  } else {
    float mx0 = -INFINITY, mx1 = -INFINITY, mx2 = -INFINITY, mx3 = -INFINITY;
    for (int le = g; le < nt; le += 16) {
      float4 a = as_v[csr[beg + le]];
      mx0 = fmaxf(mx0, a.x); mx1 = fmaxf(mx1, a.y);
      mx2 = fmaxf(mx2, a.z); mx3 = fmaxf(mx3, a.w);
    }
#pragma unroll
    for (int m = 1; m < 16; m <<= 1) {
      mx0 = fmaxf(mx0, __shfl_xor(mx0, m)); mx1 = fmaxf(mx1, __shfl_xor(mx1, m));
      mx2 = fmaxf(mx2, __shfl_xor(mx2, m)); mx3 = fmaxf(mx3, __shfl_xor(mx3, m));
    }
    float em0 = lrelu(mx0 + adv.x), em1 = lrelu(mx1 + adv.y);
    float em2 = lrelu(mx2 + adv.z), em3 = lrelu(mx3 + adv.w);
    float s0 = 0.f, s1 = 0.f, s2 = 0.f, s3 = 0.f;
    for (int le = g; le < nt; le += 16) {
      float4 a = as_v[csr[beg + le]];
      s0 += __expf(lrelu(a.x + adv.x) - em0);
      s1 += __expf(lrelu(a.y + adv.y) - em1);
      s2 += __expf(lrelu(a.z + adv.z) - em2);
      s3 += __expf(lrelu(a.w + adv.w) - em3);
    }
#pragma unroll
    for (int m = 1; m < 16; m <<= 1) {
      s0 += __shfl_xor(s0, m); s1 += __shfl_xor(s1, m);
      s2 += __shfl_xor(s2, m); s3 += __shfl_xor(s3, m);
    }
    rdh = sel_h(hd, 1.f / (s0 + 1e-16f), 1.f / (s1 + 1e-16f),
                    1.f / (s2 + 1e-16f), 1.f / (s3 + 1e-16f));
    float adh = sel_h(hd, adv.x, adv.y, adv.z, adv.w);
    float emh = sel_h(hd, em0, em1, em2, em3);
    for (int e = 0; e < nt; ++e) {
      int s = csr[beg + e];
      float4 a = as_v[s];
      float ah = sel_h(hd, a.x, a.y, a.z, a.w);
      float al = __expf(lrelu(ah + adh) - emh) * rdh;
      f16x8 v0 = *(const f16x8*)&Hh[(size_t)s * DHID + g * 16];
      f16x8 v1 = *(const f16x8*)&Hh[(size_t)s * DHID + g * 16 + 8];
#pragma unroll
      for (int qq = 0; qq < 8; ++qq) acc[qq] += al * (float)v0[qq];
#pragma unroll
      for (int qq = 0; qq < 8; ++qq) acc[8 + qq] += al * (float)v1[qq];
    }
  }

  const float* bv = &bias[g * 16];
  float* ob = &OUT[(size_t)n * DHID + g * 16];
#pragma unroll
  for (int k = 0; k < 4; ++k) {
    float4 b4 = *(const float4*)&bv[k * 4];
    *(float4*)&ob[k * 4] = make_float4(acc[k * 4] + b4.x, acc[k * 4 + 1] + b4.y,
                                       acc[k * 4 + 2] + b4.z, acc[k * 4 + 3] + b4.w);
  }
}

// ---------------- GAT aggregation, layer 2: one node per 16-lane group ----------------
__global__ __launch_bounds__(256) void k_agg2(const int* __restrict__ off, const int* __restrict__ csr,
                                              const float4* __restrict__ as_v, const float4* __restrict__ ad_v,
                                              const ushort_t* __restrict__ Hh, const float* __restrict__ bias,
                                              float* __restrict__ OUT) {
  __shared__ int s_tab[16][65];
  __shared__ __align__(16) float al_tab[16][260];
  const int tid = threadIdx.x;
  const int nd = tid >> 4;
  const int g = tid & 15;
  const int hd = g >> 2;
  const int n = blockIdx.x * 16 + nd;
  if (n >= NN) return;
  const int beg = off[n];
  const int nt = off[n + 1] - beg;
  const float4 adv = ad_v[n];

  float acc[8] = {};
  float rdh;

  if (nt <= 64) {
    float mx0 = -INFINITY, mx1 = -INFINITY, mx2 = -INFINITY, mx3 = -INFINITY;
    for (int le = g; le < nt; le += 16) {
      int s = csr[beg + le];
      float4 a = as_v[s];
      s_tab[nd][le] = s;
      *(float4*)&al_tab[nd][le << 2] = a;
      mx0 = fmaxf(mx0, a.x); mx1 = fmaxf(mx1, a.y);
      mx2 = fmaxf(mx2, a.z); mx3 = fmaxf(mx3, a.w);
    }
#pragma unroll
    for (int m = 1; m < 16; m <<= 1) {
      mx0 = fmaxf(mx0, __shfl_xor(mx0, m)); mx1 = fmaxf(mx1, __shfl_xor(mx1, m));
      mx2 = fmaxf(mx2, __shfl_xor(mx2, m)); mx3 = fmaxf(mx3, __shfl_xor(mx3, m));
    }
    float em0 = lrelu(mx0 + adv.x), em1 = lrelu(mx1 + adv.y);
    float em2 = lrelu(mx2 + adv.z), em3 = lrelu(mx3 + adv.w);
    float s0 = 0.f, s1 = 0.f, s2 = 0.f, s3 = 0.f;
    for (int le = g; le < nt; le += 16) {
      float4 a = *(const float4*)&al_tab[nd][le << 2];
      float p0 = __expf(lrelu(a.x + adv.x) - em0);
      float p1 = __expf(lrelu(a.y + adv.y) - em1);
      float p2 = __expf(lrelu(a.z + adv.z) - em2);
      float p3 = __expf(lrelu(a.w + adv.w) - em3);
      *(float4*)&al_tab[nd][le << 2] = make_float4(p0, p1, p2, p3);
      s0 += p0; s1 += p1; s2 += p2; s3 += p3;
    }
#pragma unroll
    for (int m = 1; m < 16; m <<= 1) {
      s0 += __shfl_xor(s0, m); s1 += __shfl_xor(s1, m);
      s2 += __shfl_xor(s2, m); s3 += __shfl_xor(s3, m);
    }
    rdh = sel_h(hd, 1.f / (s0 + 1e-16f), 1.f / (s1 + 1e-16f),
                    1.f / (s2 + 1e-16f), 1.f / (s3 + 1e-16f));

    int sP = s_tab[nd][0];
    float pP = al_tab[nd][hd];
    f16x8 v0 = *(const f16x8*)&Hh[(size_t)sP * DOUT + g * 8];
    for (int e = 0; e < nt; ++e) {
      int en = (e + 1 < nt) ? e + 1 : e;
      int sN = s_tab[nd][en];
      float pN = al_tab[nd][(en << 2) | hd];
      f16x8 n0 = *(const f16x8*)&Hh[(size_t)sN * DOUT + g * 8];
      float al = pP * rdh;
#pragma unroll
      for (int qq = 0; qq < 8; ++qq) acc[qq] += al * (float)v0[qq];
      pP = pN; v0 = n0;
    }
  } else {
    float mx0 = -INFINITY, mx1 = -INFINITY, mx2 = -INFINITY, mx3 = -INFINITY;
    for (int le = g; le < nt; le += 16) {
      float4 a = as_v[csr[beg + le]];
      mx0 = fmaxf(mx0, a.x); mx1 = fmaxf(mx1, a.y);
      mx2 = fmaxf(mx2, a.z); mx3 = fmaxf(mx3, a.w);
    }
#pragma unroll
    for (int m = 1; m < 16; m <<= 1) {
      mx0 = fmaxf(mx0, __shfl_xor(mx0, m)); mx1 = fmaxf(mx1, __shfl_xor(mx1, m));
      mx2 = fmaxf(mx2, __shfl_xor(mx2, m)); mx3 = fmaxf(mx3, __shfl_xor(mx3, m));
    }
    float em0 = lrelu(mx0 + adv.x), em1 = lrelu(mx1 + adv.y);
    float em2 = lrelu(mx2 + adv.z), em3 = lrelu(mx3 + adv.w);
    float s0 = 0.f, s1 = 0.f, s2 = 0.f, s3 = 0.f;
    for (int le = g; le < nt; le += 16) {
      float4 a = as_v[csr[beg + le]];
      s0 += __expf(lrelu(a.x + adv.x) - em0);
      s1 += __expf(lrelu(a.y + adv.y) - em1);
      s2 += __expf(lrelu(a.z + adv.z) - em2);
      s3 += __expf(lrelu(a.w + adv.w) - em3);
    }
#pragma unroll
    for (int m = 1; m < 16; m <<= 1) {
      s0 += __shfl_xor(s0, m); s1 += __shfl_xor(s1, m);
      s2 += __shfl_xor(s2, m); s3 += __shfl_xor(s3, m);
    }
    rdh = sel_h(hd, 1.f / (s0 + 1e-16f), 1.f / (s1 + 1e-16f),
                    1.f / (s2 + 1e-16f), 1.f / (s3 + 1e-16f));
    float adh = sel_h(hd, adv.x, adv.y, adv.z, adv.w);
    float emh = sel_h(hd, em0, em1, em2, em3);
    for (int e = 0; e < nt; ++e) {
      int s = csr[beg + e];
      float4 a = as_v[s];
      float ah = sel_h(hd, a.x, a.y, a.z, a.w);
      float al = __expf(lrelu(ah + adh) - emh) * rdh;
      f16x8 v0 = *(const f16x8*)&Hh[(size_t)s * DOUT + g * 8];
#pragma unroll
      for (int qq = 0; qq < 8; ++qq) acc[qq] += al * (float)v0[qq];
    }
  }

  const float* bv = &bias[g * 8];
  float* ob = &OUT[(size_t)n * DOUT + g * 8];
#pragma unroll
  for (int k = 0; k < 2; ++k) {
    float4 b4 = *(const float4*)&bv[k * 4];
    *(float4*)&ob[k * 4] = make_float4(acc[k * 4] + b4.x, acc[k * 4 + 1] + b4.y,
                                       acc[k * 4 + 2] + b4.z, acc[k * 4 + 3] + b4.w);
  }
}

// ---------------- pooling (4-way ILP) ----------------
__global__ __launch_bounds__(256) void k_pool(const int* __restrict__ segstart,
                                              const float* __restrict__ OUT2,
                                              const float* __restrict__ OUT1,
                                              float* __restrict__ out) {
  int b = blockIdx.x;
  int t = threadIdx.x;
  int s = segstart[b], e = segstart[b + 1];
  float* ob = out + (size_t)b * 384;
  if (s >= e) {
    for (int i = t; i < 384; i += 256) ob[i] = 0.f;
    return;
  }
  if (t < 128) {
    float s0 = 0.f, s1 = 0.f, s2 = 0.f, s3 = 0.f;
    int n = s;
    for (; n + 3 < e; n += 4) {
      s0 += fmaxf(OUT2[(size_t)n * DOUT + t], 0.f);
      s1 += fmaxf(OUT2[(size_t)(n + 1) * DOUT + t], 0.f);
      s2 += fmaxf(OUT2[(size_t)(n + 2) * DOUT + t], 0.f);
      s3 += fmaxf(OUT2[(size_t)(n + 3) * DOUT + t], 0.f);
    }
    for (; n < e; ++n) s0 += fmaxf(OUT2[(size_t)n * DOUT + t], 0.f);
    ob[t] = ((s0 + s1) + (s2 + s3)) / (float)(e - s);
  } else {
    int k = t - 128;
    ob[128 + k] = OUT1[(size_t)s * DHID + k];
    ob[256 + k] = OUT1[(size_t)s * DHID + 128 + k];
  }
}

// ---------------- launch ----------------
extern "C" void kernel_launch(void* const* d_in, const int* in_sizes, int n_in,
                              void* d_out, int out_size, void* d_ws, size_t ws_size,
                              hipStream_t stream) {
  const float* x    = (const float*)d_in[0];
  const int*   ei   = (const int*)d_in[1];
  const int*   batch = (const int*)d_in[2];
  const float* W1   = (const float*)d_in[3];
  const float* as1w = (const float*)d_in[4];
  const float* ad1w = (const float*)d_in[5];
  const float* b1   = (const float*)d_in[6];
  const float* W2   = (const float*)d_in[7];
  const float* as2w = (const float*)d_in[8];
  const float* ad2w = (const float*)d_in[9];
  const float* b2   = (const float*)d_in[10];
  float* out = (float*)d_out;
  char* ws = (char*)d_ws;

  const int E = in_sizes[1] / 2;
  const int Etot = E + NN;

  // workspace layout (bytes). Wt2h/R2 live INSIDE the H1h region (0..25.6MB):
  // written only AFTER k_agg1 (H1h dead); H2h (0..12.8MB) stays below them.
  ushort_t* H1h = (ushort_t*)(ws + 0);        // NN*256*2 = 25.6 MB (dead after agg1)
  ushort_t* H2h = (ushort_t*)(ws + 0);        // NN*128*2 = 12.8 MB (aliases H1h)
  ushort_t* Wt2h = (ushort_t*)(ws + 13000000);// 262144 B (written AFTER agg1)
  float*  R2   = (float*)(ws + 14000000);     // 512*128*4 (written after agg1)
  float*  OUT2 = (float*)(ws + 25600000);
  float*  OUT1 = (float*)(ws + 51200000);
  float4* as1  = (float4*)(ws + 102400000);
  float4* ad1  = (float4*)(ws + 103200000);
  float4* as2  = (float4*)(ws + 104000000);
  float4* ad2  = (float4*)(ws + 104800000);
  int* deg     = (int*)(ws + 105600000);
  int* cur     = (int*)(ws + 105800000);
  int* off     = (int*)(ws + 106000000);
  int* csr     = (int*)(ws + 106200016);
  int* segstart = (int*)(ws + 109600016);
  int* bsum    = (int*)(ws + 109802080);
  ushort_t* Wt1h = (ushort_t*)(ws + 105600000); // over deg+cur (dead after scatter)

  const int TB = 256;
  const int NB_SCAN = (NN + 1023) / 1024;

  hipMemsetAsync(deg, 0, NN * sizeof(int), stream);
  hipMemsetAsync(cur, 0, NN * sizeof(int), stream);
  k_hist<<<(Etot + TB - 1) / TB, TB, 0, stream>>>(ei, deg, E, Etot);
  k_scan1<<<NB_SCAN, 1024, 0, stream>>>(deg, off, bsum, NN);
  k_scan2<<<1, 64, 0, stream>>>(bsum, off, NB_SCAN, NN);
  k_scan3<<<NB_SCAN, 1024, 0, stream>>>(off, bsum, NN);
  k_scatter<<<(Etot + TB - 1) / TB, TB, 0, stream>>>(ei, off, cur, csr, E, Etot);
  k_segstart<<<(NBGRAPH + 1 + TB - 1) / TB, TB, 0, stream>>>(batch, segstart, NN, NBGRAPH);

  // layer 1 (scores1 fused into gemm1m epilogue)
  k_prepW<<<(DIN * DHID + TB - 1) / TB, TB, 0, stream>>>(W1, Wt1h, DIN, DHID);
  dim3 g1((NN + 63) / 64, DHID / 128);
  k_gemm1m<<<g1, TB, 0, stream>>>(x, Wt1h, as1w, ad1w, H1h, as1, ad1);
  k_agg1<<<(NN + 15) / 16, TB, 0, stream>>>(off, csr, as1, ad1, H1h, b1, OUT1);

  // layer 2 (H1h dead now; Wt2h/R2/H2h live in its region; scores2 fused into gemm2m)
  k_prepW<<<((DHID + DIN) * DOUT + TB - 1) / TB, TB, 0, stream>>>(W2, Wt2h, DHID + DIN, DOUT);
  k_gemmR<<<NBGRAPH, TB, 0, stream>>>(x, segstart, Wt2h, R2);
  dim3 g2((NN + 63) / 64, 1);
  k_gemm2m<<<g2, TB, 0, stream>>>(OUT1, batch, Wt2h, R2, as2w, ad2w, H2h, as2, ad2);
  k_agg2<<<(NN + 15) / 16, TB, 0, stream>>>(off, csr, as2, ad2, H2h, b2, OUT2);

  k_pool<<<NBGRAPH, TB, 0, stream>>>(segstart, OUT2, OUT1, out);
}

// Round 20
// 331.412 us; speedup vs baseline: 1.0457x; 1.0096x over previous
//
#include <hip/hip_runtime.h>

#define NN 50000
#define NBGRAPH 512
#define DIN 768
#define DHID 256
#define DOUT 128

typedef unsigned short ushort_t;
typedef __attribute__((ext_vector_type(4))) float f32x4;
typedef _Float16 f16_t;
typedef __attribute__((ext_vector_type(8))) _Float16 f16x8;

__device__ __forceinline__ float lrelu(float v) { return v > 0.f ? v : 0.2f * v; }

__device__ __forceinline__ float h2f_u(ushort_t u) { return (float)__builtin_bit_cast(f16_t, u); }
__device__ __forceinline__ ushort_t f2h_u(float f) { return __builtin_bit_cast(ushort_t, (f16_t)f); }

__device__ __forceinline__ float sel_h(int h, float q0, float q1, float q2, float q3) {
  float lo = (h & 1) ? q1 : q0;
  float hi = (h & 1) ? q3 : q2;
  return (h & 2) ? hi : lo;
}

__device__ __forceinline__ f16x8 cvt8(float4 u, float4 v) {
  unsigned int a = __builtin_bit_cast(unsigned int, __builtin_amdgcn_cvt_pkrtz(u.x, u.y));
  unsigned int b = __builtin_bit_cast(unsigned int, __builtin_amdgcn_cvt_pkrtz(u.z, u.w));
  unsigned int c = __builtin_bit_cast(unsigned int, __builtin_amdgcn_cvt_pkrtz(v.x, v.y));
  unsigned int d = __builtin_bit_cast(unsigned int, __builtin_amdgcn_cvt_pkrtz(v.z, v.w));
  uint4 q = {a, b, c, d};
  return __builtin_bit_cast(f16x8, q);
}
__device__ __forceinline__ f16x8 cvt8_relu(float4 u, float4 v) {
  u.x = fmaxf(u.x, 0.f); u.y = fmaxf(u.y, 0.f); u.z = fmaxf(u.z, 0.f); u.w = fmaxf(u.w, 0.f);
  v.x = fmaxf(v.x, 0.f); v.y = fmaxf(v.y, 0.f); v.z = fmaxf(v.z, 0.f); v.w = fmaxf(v.w, 0.f);
  return cvt8(u, v);
}

// ---------------- CSR build ----------------
__global__ void k_hist(const int* __restrict__ ei, int* __restrict__ deg, int E, int Etot) {
  int e = blockIdx.x * blockDim.x + threadIdx.x;
  if (e >= Etot) return;
  int dst = (e < E) ? ei[e] : (e - E);
  atomicAdd(&deg[dst], 1);
}

__global__ __launch_bounds__(1024) void k_scan1(const int* __restrict__ deg, int* __restrict__ off,
                                                int* __restrict__ bsum, int n) {
  __shared__ int wsum[16];
  int tid = threadIdx.x, lane = tid & 63, w = tid >> 6;
  int i = blockIdx.x * 1024 + tid;
  int v = (i < n) ? deg[i] : 0;
  int x = v;
#pragma unroll
  for (int d = 1; d < 64; d <<= 1) { int t = __shfl_up(x, d); if (lane >= d) x += t; }
  if (lane == 63) wsum[w] = x;
  __syncthreads();
  if (tid < 16) {
    int y = wsum[tid];
#pragma unroll
    for (int d = 1; d < 16; d <<= 1) { int t = __shfl_up(y, d); if (tid >= d) y += t; }
    wsum[tid] = y;
  }
  __syncthreads();
  int base = (w > 0) ? wsum[w - 1] : 0;
  if (i < n) off[i] = base + x - v;
  if (tid == 1023) bsum[blockIdx.x] = wsum[15];
}

__global__ void k_scan2(int* __restrict__ bsum, int* __restrict__ off, int nb, int n) {
  int lane = threadIdx.x;
  int v = (lane < nb) ? bsum[lane] : 0;
  int x = v;
#pragma unroll
  for (int d = 1; d < 64; d <<= 1) { int t = __shfl_up(x, d); if (lane >= d) x += t; }
  if (lane < nb) bsum[lane] = x - v;
  if (lane == 63) off[n] = x;
}

__global__ void k_scan3(int* __restrict__ off, const int* __restrict__ bsum, int n) {
  int i = blockIdx.x * blockDim.x + threadIdx.x;
  if (i < n) off[i] += bsum[i >> 10];
}

__global__ void k_scatter(const int* __restrict__ ei, const int* __restrict__ off,
                          int* __restrict__ cur, int* __restrict__ csr, int E, int Etot) {
  int e = blockIdx.x * blockDim.x + threadIdx.x;
  if (e >= Etot) return;
  int dst, src;
  if (e < E) { dst = ei[e]; src = ei[E + e]; }
  else       { dst = src = e - E; }
  int p = atomicAdd(&cur[dst], 1);
  csr[off[dst] + p] = src;
}

// ---------------- roots / segments ----------------
__global__ void k_segstart(const int* __restrict__ batch, int* __restrict__ segstart, int n, int b_cnt) {
  int b = blockIdx.x * blockDim.x + threadIdx.x;
  if (b > b_cnt) return;
  int lo = 0, hi = n;
  while (lo < hi) { int mid = (lo + hi) >> 1; if (batch[mid] < b) lo = mid + 1; else hi = mid; }
  segstart[b] = lo;
}

// ---------------- weight transpose+cast (fp16): Wt[n][k] = f16(W[k][n]) ----------------
__global__ void k_prepW(const float* __restrict__ W, ushort_t* __restrict__ Wt, int K, int N) {
  int id = blockIdx.x * blockDim.x + threadIdx.x;
  if (id >= K * N) return;
  int n = id / K, k = id - n * K;
  Wt[(size_t)n * K + k] = f2h_u(W[(size_t)k * N + n]);
}

// ---------------- GEMM1: BM=64, BN=128, BK=64; epilogue fuses scores1 ----------------
#define LDT2 72
__global__ __launch_bounds__(256) void k_gemm1m(const float* __restrict__ A,
                                                const ushort_t* __restrict__ Bt,
                                                const float* __restrict__ att_s,
                                                const float* __restrict__ att_d,
                                                ushort_t* __restrict__ C,
                                                float4* __restrict__ as_out,
                                                float4* __restrict__ ad_out) {
  const int K = DIN, NC = DHID;
  __shared__ __align__(16) ushort_t As[64 * LDT2];
  __shared__ __align__(16) ushort_t Bs[128 * LDT2];
  const int tid = threadIdx.x;
  const int bm = blockIdx.x * 64;
  const int bn = blockIdx.y * 128;
  const int row = tid >> 2, q = tid & 3;
  const int arow = bm + row;
  const int r_c = arow < NN ? arow : NN - 1;
  const int wid = tid >> 6, lane = tid & 63;
  const int wr = (wid >> 1) * 32, wc = (wid & 1) * 64;
  const int fr = lane & 15, fg = lane >> 4;
  const float* aptr = &A[(size_t)r_c * K + q * 16];
  const int bc0 = tid >> 3, bk0 = tid & 7;
  const int bc1 = (tid + 256) >> 3, bk1 = (tid + 256) & 7;
  const int bc2 = (tid + 512) >> 3, bk2 = (tid + 512) & 7;
  const int bc3 = (tid + 768) >> 3, bk3 = (tid + 768) & 7;
  const ushort_t* bp0 = &Bt[(size_t)(bn + bc0) * K + bk0 * 8];
  const ushort_t* bp1 = &Bt[(size_t)(bn + bc1) * K + bk1 * 8];
  const ushort_t* bp2 = &Bt[(size_t)(bn + bc2) * K + bk2 * 8];
  const ushort_t* bp3 = &Bt[(size_t)(bn + bc3) * K + bk3 * 8];
  f32x4 acc[2][4] = {};

  float4 Pa0, Pa1, Pa2, Pa3; uint4 Pb0, Pb1, Pb2, Pb3;
  float4 Qa0, Qa1, Qa2, Qa3; uint4 Qb0, Qb1, Qb2, Qb3;

  auto loadP = [&](int kk) {
    const float4* s = (const float4*)(aptr + kk);
    Pa0 = s[0]; Pa1 = s[1]; Pa2 = s[2]; Pa3 = s[3];
    Pb0 = *(const uint4*)(bp0 + kk); Pb1 = *(const uint4*)(bp1 + kk);
    Pb2 = *(const uint4*)(bp2 + kk); Pb3 = *(const uint4*)(bp3 + kk);
  };
  auto loadQ = [&](int kk) {
    const float4* s = (const float4*)(aptr + kk);
    Qa0 = s[0]; Qa1 = s[1]; Qa2 = s[2]; Qa3 = s[3];
    Qb0 = *(const uint4*)(bp0 + kk); Qb1 = *(const uint4*)(bp1 + kk);
    Qb2 = *(const uint4*)(bp2 + kk); Qb3 = *(const uint4*)(bp3 + kk);
  };
  auto stage = [&](float4 a0, float4 a1, float4 a2, float4 a3,
                   uint4 b0, uint4 b1, uint4 b2, uint4 b3) {
    const int p = row * LDT2 + q * 16;
    *(f16x8*)&As[p + 0] = cvt8(a0, a1);
    *(f16x8*)&As[p + 8] = cvt8(a2, a3);
    *(uint4*)&Bs[bc0 * LDT2 + bk0 * 8] = b0;
    *(uint4*)&Bs[bc1 * LDT2 + bk1 * 8] = b1;
    *(uint4*)&Bs[bc2 * LDT2 + bk2 * 8] = b2;
    *(uint4*)&Bs[bc3 * LDT2 + bk3 * 8] = b3;
  };
  auto compute = [&]() {
#pragma unroll
    for (int kk = 0; kk < 64; kk += 32) {
      f16x8 af0 = *(const f16x8*)&As[(wr + fr) * LDT2 + kk + fg * 8];
      f16x8 af1 = *(const f16x8*)&As[(wr + 16 + fr) * LDT2 + kk + fg * 8];
      f16x8 bf0 = *(const f16x8*)&Bs[(wc + fr) * LDT2 + kk + fg * 8];
      f16x8 bf1 = *(const f16x8*)&Bs[(wc + 16 + fr) * LDT2 + kk + fg * 8];
      f16x8 bf2 = *(const f16x8*)&Bs[(wc + 32 + fr) * LDT2 + kk + fg * 8];
      f16x8 bf3 = *(const f16x8*)&Bs[(wc + 48 + fr) * LDT2 + kk + fg * 8];
      acc[0][0] = __builtin_amdgcn_mfma_f32_16x16x32_f16(af0, bf0, acc[0][0], 0, 0, 0);
      acc[0][1] = __builtin_amdgcn_mfma_f32_16x16x32_f16(af0, bf1, acc[0][1], 0, 0, 0);
      acc[0][2] = __builtin_amdgcn_mfma_f32_16x16x32_f16(af0, bf2, acc[0][2], 0, 0, 0);
      acc[0][3] = __builtin_amdgcn_mfma_f32_16x16x32_f16(af0, bf3, acc[0][3], 0, 0, 0);
      acc[1][0] = __builtin_amdgcn_mfma_f32_16x16x32_f16(af1, bf0, acc[1][0], 0, 0, 0);
      acc[1][1] = __builtin_amdgcn_mfma_f32_16x16x32_f16(af1, bf1, acc[1][1], 0, 0, 0);
      acc[1][2] = __builtin_amdgcn_mfma_f32_16x16x32_f16(af1, bf2, acc[1][2], 0, 0, 0);
      acc[1][3] = __builtin_amdgcn_mfma_f32_16x16x32_f16(af1, bf3, acc[1][3], 0, 0, 0);
    }
  };

  loadP(0);
  loadQ(64);
  for (int k0 = 0; k0 < K; k0 += 128) {
    stage(Pa0, Pa1, Pa2, Pa3, Pb0, Pb1, Pb2, Pb3);
    __syncthreads();
    if (k0 + 128 < K) loadP(k0 + 128);
    compute();
    __syncthreads();
    stage(Qa0, Qa1, Qa2, Qa3, Qb0, Qb1, Qb2, Qb3);
    __syncthreads();
    if (k0 + 192 < K) loadQ(k0 + 192);
    compute();
    __syncthreads();
  }

  // epilogue: store f16 H1 + fused scores1 (wave's cols all in head h = (bn+wc)>>6)
  const int h = (bn + wc) >> 6;
  float as_c[4], ad_c[4];
#pragma unroll
  for (int n = 0; n < 4; ++n) {
    int col = bn + wc + n * 16 + fr;
    as_c[n] = att_s[col];
    ad_c[n] = att_d[col];
  }
#pragma unroll
  for (int m = 0; m < 2; ++m)
#pragma unroll
    for (int j = 0; j < 4; ++j) {
      int r = bm + wr + m * 16 + fg * 4 + j;
      float v0 = acc[m][0][j], v1 = acc[m][1][j], v2 = acc[m][2][j], v3 = acc[m][3][j];
      if (r < NN) {
        C[(size_t)r * NC + bn + wc + fr] = f2h_u(v0);
        C[(size_t)r * NC + bn + wc + 16 + fr] = f2h_u(v1);
        C[(size_t)r * NC + bn + wc + 32 + fr] = f2h_u(v2);
        C[(size_t)r * NC + bn + wc + 48 + fr] = f2h_u(v3);
      }
      float ps = v0 * as_c[0] + v1 * as_c[1] + v2 * as_c[2] + v3 * as_c[3];
      float pd = v0 * ad_c[0] + v1 * ad_c[1] + v2 * ad_c[2] + v3 * ad_c[3];
#pragma unroll
      for (int msk = 1; msk < 16; msk <<= 1) {
        ps += __shfl_xor(ps, msk);
        pd += __shfl_xor(pd, msk);
      }
      if (fr == m * 4 + j && r < NN) {
        ((float*)&as_out[r])[h] = ps;
        ((float*)&ad_out[r])[h] = pd;
      }
    }
}

// ---------------- gemmR: R2[b][c] = relu(x[segstart[b]]) . W2[256:, c]  (512 graphs) ----------------
__global__ __launch_bounds__(256) void k_gemmR(const float* __restrict__ X,
                                               const int* __restrict__ segstart,
                                               const ushort_t* __restrict__ Wt2,
                                               float* __restrict__ R2) {
  __shared__ float part[2][128];
  const int b = blockIdx.x;
  const int t = threadIdx.x;
  const int c = t & 127, seg = t >> 7;
  int root = segstart[b];
  if (root >= NN) root = NN - 1;
  const float* xr = &X[(size_t)root * DIN + seg * 384];
  const ushort_t* wp = &Wt2[(size_t)c * (DHID + DIN) + DHID + seg * 384];
  float s = 0.f;
#pragma unroll 4
  for (int k = 0; k < 384; k += 4) {
    float4 xv = *(const float4*)&xr[k];
    ushort4 wv = *(const ushort4*)&wp[k];
    s += fmaxf(xv.x, 0.f) * h2f_u(wv.x);
    s += fmaxf(xv.y, 0.f) * h2f_u(wv.y);
    s += fmaxf(xv.z, 0.f) * h2f_u(wv.z);
    s += fmaxf(xv.w, 0.f) * h2f_u(wv.w);
  }
  part[seg][c] = s;
  __syncthreads();
  if (t < 128) R2[(size_t)b * DOUT + t] = part[0][t] + part[1][t];
}

// ---------------- GEMM2: K=256, 2-deep prefetch; epilogue adds R2 AND fuses scores2 ----------------
__global__ __launch_bounds__(256) void k_gemm2m(const float* __restrict__ OUT1,
                                                const int* __restrict__ batch,
                                                const ushort_t* __restrict__ Bt,
                                                const float* __restrict__ R2,
                                                const float* __restrict__ att_s,
                                                const float* __restrict__ att_d,
                                                ushort_t* __restrict__ C,
                                                float4* __restrict__ as_out,
                                                float4* __restrict__ ad_out) {
  const int K = DHID;           // 256
  const int KS = DHID + DIN;    // B row stride = 1024
  __shared__ __align__(16) ushort_t As[64 * LDT2];
  __shared__ __align__(16) ushort_t Bs[128 * LDT2];
  const int tid = threadIdx.x;
  const int bm = blockIdx.x * 64;
  const int row = tid >> 2, q = tid & 3;
  const int arow = bm + row;
  const int r_c = arow < NN ? arow : NN - 1;
  const int wid = tid >> 6, lane = tid & 63;
  const int wr = (wid >> 1) * 32, wc = (wid & 1) * 64;
  const int fr = lane & 15, fg = lane >> 4;
  const float* aptr = &OUT1[(size_t)r_c * DHID + q * 16];
  const int bc0 = tid >> 3, bk0 = tid & 7;
  const int bc1 = (tid + 256) >> 3, bk1 = (tid + 256) & 7;
  const int bc2 = (tid + 512) >> 3, bk2 = (tid + 512) & 7;
  const int bc3 = (tid + 768) >> 3, bk3 = (tid + 768) & 7;
  const ushort_t* bp0 = &Bt[(size_t)bc0 * KS + bk0 * 8];
  const ushort_t* bp1 = &Bt[(size_t)bc1 * KS + bk1 * 8];
  const ushort_t* bp2 = &Bt[(size_t)bc2 * KS + bk2 * 8];
  const ushort_t* bp3 = &Bt[(size_t)bc3 * KS + bk3 * 8];
  f32x4 acc[2][4] = {};

  float4 Pa0, Pa1, Pa2, Pa3; uint4 Pb0, Pb1, Pb2, Pb3;
  float4 Qa0, Qa1, Qa2, Qa3; uint4 Qb0, Qb1, Qb2, Qb3;

  auto loadP = [&](int kk) {
    const float4* s = (const float4*)(aptr + kk);
    Pa0 = s[0]; Pa1 = s[1]; Pa2 = s[2]; Pa3 = s[3];
    Pb0 = *(const uint4*)(bp0 + kk); Pb1 = *(const uint4*)(bp1 + kk);
    Pb2 = *(const uint4*)(bp2 + kk); Pb3 = *(const uint4*)(bp3 + kk);
  };
  auto loadQ = [&](int kk) {
    const float4* s = (const float4*)(aptr + kk);
    Qa0 = s[0]; Qa1 = s[1]; Qa2 = s[2]; Qa3 = s[3];
    Qb0 = *(const uint4*)(bp0 + kk); Qb1 = *(const uint4*)(bp1 + kk);
    Qb2 = *(const uint4*)(bp2 + kk); Qb3 = *(const uint4*)(bp3 + kk);
  };
  auto stage = [&](float4 a0, float4 a1, float4 a2, float4 a3,
                   uint4 b0, uint4 b1, uint4 b2, uint4 b3) {
    const int p = row * LDT2 + q * 16;
    *(f16x8*)&As[p + 0] = cvt8_relu(a0, a1);
    *(f16x8*)&As[p + 8] = cvt8_relu(a2, a3);
    *(uint4*)&Bs[bc0 * LDT2 + bk0 * 8] = b0;
    *(uint4*)&Bs[bc1 * LDT2 + bk1 * 8] = b1;
    *(uint4*)&Bs[bc2 * LDT2 + bk2 * 8] = b2;
    *(uint4*)&Bs[bc3 * LDT2 + bk3 * 8] = b3;
  };
  auto compute = [&]() {
#pragma unroll
    for (int kk = 0; kk < 64; kk += 32) {
      f16x8 af0 = *(const f16x8*)&As[(wr + fr) * LDT2 + kk + fg * 8];
      f16x8 af1 = *(const f16x8*)&As[(wr + 16 + fr) * LDT2 + kk + fg * 8];
      f16x8 bf0 = *(const f16x8*)&Bs[(wc + fr) * LDT2 + kk + fg * 8];
      f16x8 bf1 = *(const f16x8*)&Bs[(wc + 16 + fr) * LDT2 + kk + fg * 8];
      f16x8 bf2 = *(const f16x8*)&Bs[(wc + 32 + fr) * LDT2 + kk + fg * 8];
      f16x8 bf3 = *(const f16x8*)&Bs[(wc + 48 + fr) * LDT2 + kk + fg * 8];
      acc[0][0] = __builtin_amdgcn_mfma_f32_16x16x32_f16(af0, bf0, acc[0][0], 0, 0, 0);
      acc[0][1] = __builtin_amdgcn_mfma_f32_16x16x32_f16(af0, bf1, acc[0][1], 0, 0, 0);
      acc[0][2] = __builtin_amdgcn_mfma_f32_16x16x32_f16(af0, bf2, acc[0][2], 0, 0, 0);
      acc[0][3] = __builtin_amdgcn_mfma_f32_16x16x32_f16(af0, bf3, acc[0][3], 0, 0, 0);
      acc[1][0] = __builtin_amdgcn_mfma_f32_16x16x32_f16(af1, bf0, acc[1][0], 0, 0, 0);
      acc[1][1] = __builtin_amdgcn_mfma_f32_16x16x32_f16(af1, bf1, acc[1][1], 0, 0, 0);
      acc[1][2] = __builtin_amdgcn_mfma_f32_16x16x32_f16(af1, bf2, acc[1][2], 0, 0, 0);
      acc[1][3] = __builtin_amdgcn_mfma_f32_16x16x32_f16(af1, bf3, acc[1][3], 0, 0, 0);
    }
  };

  loadP(0);
  loadQ(64);
  for (int k0 = 0; k0 < K; k0 += 128) {
    stage(Pa0, Pa1, Pa2, Pa3, Pb0, Pb1, Pb2, Pb3);
    __syncthreads();
    if (k0 + 128 < K) loadP(k0 + 128);
    compute();
    __syncthreads();
    stage(Qa0, Qa1, Qa2, Qa3, Qb0, Qb1, Qb2, Qb3);
    __syncthreads();
    if (k0 + 192 < K) loadQ(k0 + 192);
    compute();
    __syncthreads();
  }

  // epilogue: v = acc + R2[batch[r]]; store f16 H2; fused per-head score dots.
  float as_c[4], ad_c[4];
#pragma unroll
  for (int n = 0; n < 4; ++n) {
    int col = wc + n * 16 + fr;
    as_c[n] = att_s[col];
    ad_c[n] = att_d[col];
  }
#pragma unroll
  for (int m = 0; m < 2; ++m)
#pragma unroll
    for (int j = 0; j < 4; ++j) {
      int r = bm + wr + m * 16 + fg * 4 + j;
      int rc = r < NN ? r : NN - 1;
      int gb = batch[rc];
      const float* r2 = &R2[(size_t)gb * DOUT];
      float v0 = acc[m][0][j] + r2[wc + fr];
      float v1 = acc[m][1][j] + r2[wc + 16 + fr];
      float v2 = acc[m][2][j] + r2[wc + 32 + fr];
      float v3 = acc[m][3][j] + r2[wc + 48 + fr];
      if (r < NN) {
        C[(size_t)r * DOUT + wc + fr] = f2h_u(v0);
        C[(size_t)r * DOUT + wc + 16 + fr] = f2h_u(v1);
        C[(size_t)r * DOUT + wc + 32 + fr] = f2h_u(v2);
        C[(size_t)r * DOUT + wc + 48 + fr] = f2h_u(v3);
      }
      float psl = v0 * as_c[0] + v1 * as_c[1];
      float psh = v2 * as_c[2] + v3 * as_c[3];
      float pdl = v0 * ad_c[0] + v1 * ad_c[1];
      float pdh = v2 * ad_c[2] + v3 * ad_c[3];
#pragma unroll
      for (int msk = 1; msk < 16; msk <<= 1) {
        psl += __shfl_xor(psl, msk);
        psh += __shfl_xor(psh, msk);
        pdl += __shfl_xor(pdl, msk);
        pdh += __shfl_xor(pdh, msk);
      }
      if (fr == m * 4 + j && r < NN) {
        float* sp = (float*)&as_out[r] + (wid & 1) * 2;
        float* dp = (float*)&ad_out[r] + (wid & 1) * 2;
        sp[0] = psl; sp[1] = psh;
        dp[0] = pdl; dp[1] = pdh;
      }
    }
}

// ---------------- GAT aggregation, layer 1: one node per 16-lane group ----------------
__global__ __launch_bounds__(256) void k_agg1(const int* __restrict__ off, const int* __restrict__ csr,
                                              const float4* __restrict__ as_v, const float4* __restrict__ ad_v,
                                              const ushort_t* __restrict__ Hh, const float* __restrict__ bias,
                                              float* __restrict__ OUT) {
  __shared__ int s_tab[16][65];
  __shared__ __align__(16) float al_tab[16][260];
  const int tid = threadIdx.x;
  const int nd = tid >> 4;
  const int g = tid & 15;
  const int hd = g >> 2;
  const int n = blockIdx.x * 16 + nd;
  if (n >= NN) return;
  const int beg = off[n];
  const int nt = off[n + 1] - beg;
  const float4 adv = ad_v[n];

  float acc[16] = {};
  float rdh;

  if (nt <= 64) {
    float mx0 = -INFINITY, mx1 = -INFINITY, mx2 = -INFINITY, mx3 = -INFINITY;
    for (int le = g; le < nt; le += 16) {
      int s = csr[beg + le];
      float4 a = as_v[s];
      s_tab[nd][le] = s;
      *(float4*)&al_tab[nd][le << 2] = a;
      mx0 = fmaxf(mx0, a.x); mx1 = fmaxf(mx1, a.y);
      mx2 = fmaxf(mx2, a.z); mx3 = fmaxf(mx3, a.w);
    }
#pragma unroll
    for (int m = 1; m < 16; m <<= 1) {
      mx0 = fmaxf(mx0, __shfl_xor(mx0, m)); mx1 = fmaxf(mx1, __shfl_xor(mx1, m));
      mx2 = fmaxf(mx2, __shfl_xor(mx2, m)); mx3 = fmaxf(mx3, __shfl_xor(mx3, m));
    }
    float em0 = lrelu(mx0 + adv.x), em1 = lrelu(mx1 + adv.y);
    float em2 = lrelu(mx2 + adv.z), em3 = lrelu(mx3 + adv.w);
    float s0 = 0.f, s1 = 0.f, s2 = 0.f, s3 = 0.f;
    for (int le = g; le < nt; le += 16) {
      float4 a = *(const float4*)&al_tab[nd][le << 2];
      float p0 = __expf(lrelu(a.x + adv.x) - em0);
      float p1 = __expf(lrelu(a.y + adv.y) - em1);
      float p2 = __expf(lrelu(a.z + adv.z) - em2);
      float p3 = __expf(lrelu(a.w + adv.w) - em3);
      *(float4*)&al_tab[nd][le << 2] = make_float4(p0, p1, p2, p3);
      s0 += p0; s1 += p1; s2 += p2; s3 += p3;
    }
#pragma unroll
    for (int m = 1; m < 16; m <<= 1) {
      s0 += __shfl_xor(s0, m); s1 += __shfl_xor(s1, m);
      s2 += __shfl_xor(s2, m); s3 += __shfl_xor(s3, m);
    }
    rdh = sel_h(hd, 1.f / (s0 + 1e-16f), 1.f / (s1 + 1e-16f),
                    1.f / (s2 + 1e-16f), 1.f / (s3 + 1e-16f));

    // pass C: 2-edge unroll (4 independent 16B loads in flight per lane)
    int e = 0;
    for (; e + 1 < nt; e += 2) {
      int sA = s_tab[nd][e];
      int sB = s_tab[nd][e + 1];
      float pA = al_tab[nd][(e << 2) | hd] * rdh;
      float pB = al_tab[nd][((e + 1) << 2) | hd] * rdh;
      f16x8 a0 = *(const f16x8*)&Hh[(size_t)sA * DHID + g * 16];
      f16x8 a1 = *(const f16x8*)&Hh[(size_t)sA * DHID + g * 16 + 8];
      f16x8 b0 = *(const f16x8*)&Hh[(size_t)sB * DHID + g * 16];
      f16x8 b1 = *(const f16x8*)&Hh[(size_t)sB * DHID + g * 16 + 8];
#pragma unroll
      for (int qq = 0; qq < 8; ++qq) acc[qq] += pA * (float)a0[qq] + pB * (float)b0[qq];
#pragma unroll
      for (int qq = 0; qq < 8; ++qq) acc[8 + qq] += pA * (float)a1[qq] + pB * (float)b1[qq];
    }
    if (e < nt) {
      int sA = s_tab[nd][e];
      float pA = al_tab[nd][(e << 2) | hd] * rdh;
      f16x8 a0 = *(const f16x8*)&Hh[(size_t)sA * DHID + g * 16];
      f16x8 a1 = *(const f16x8*)&Hh[(size_t)sA * DHID + g * 16 + 8];
#pragma unroll
      for (int qq = 0; qq < 8; ++qq) acc[qq] += pA * (float)a0[qq];
#pragma unroll
      for (int qq = 0; qq < 8; ++qq) acc[8 + qq] += pA * (float)a1[qq];
    }
  } else {
    float mx0 = -INFINITY, mx1 = -INFINITY, mx2 = -INFINITY, mx3 = -INFINITY;
    for (int le = g; le < nt; le += 16) {
      float4 a = as_v[csr[beg + le]];
      mx0 = fmaxf(mx0, a.x); mx1 = fmaxf(mx1, a.y);
      mx2 = fmaxf(mx2, a.z); mx3 = fmaxf(mx3, a.w);
    }
#pragma unroll
    for (int m = 1; m < 16; m <<= 1) {
      mx0 = fmaxf(mx0, __shfl_xor(mx0, m)); mx1 = fmaxf(mx1, __shfl_xor(mx1, m));
      mx2 = fmaxf(mx2, __shfl_xor(mx2, m)); mx3 = fmaxf(mx3, __shfl_xor(mx3, m));
    }
    float em0 = lrelu(mx0 + adv.x), em1 = lrelu(mx1 + adv.y);
    float em2 = lrelu(mx2 + adv.z), em3 = lrelu(mx3 + adv.w);
    float s0 = 0.f, s1 = 0.f, s2 = 0.f, s3 = 0.f;
    for (int le = g; le < nt; le += 16) {
      float4 a = as_v[csr[beg + le]];
      s0 += __expf(lrelu(a.x + adv.x) - em0);
      s1 += __expf(lrelu(a.y + adv.y) - em1);
      s2 += __expf(lrelu(a.z + adv.z) - em2);
      s3 += __expf(lrelu(a.w + adv.w) - em3);
    }
#pragma unroll
    for (int m = 1; m < 16; m <<= 1) {
      s0 += __shfl_xor(s0, m); s1 += __shfl_xor(s1, m);
      s2 += __shfl_xor(s2, m); s3 += __shfl_xor(s3, m);
    }
    rdh = sel_h(hd, 1.f / (s0 + 1e-16f), 1.f / (s1 + 1e-16f),
                    1.f / (s2 + 1e-16f), 1.f / (s3 + 1e-16f));
    float adh = sel_h(hd, adv.x, adv.y, adv.z, adv.w);
    float emh = sel_h(hd, em0, em1, em2, em3);
    for (int e = 0; e < nt; ++e) {
      int s = csr[beg + e];
      float4 a = as_v[s];
      float ah = sel_h(hd, a.x, a.y, a.z, a.w);
      float al = __expf(lrelu(ah + adh) - emh) * rdh;
      f16x8 v0 = *(const f16x8*)&Hh[(size_t)s * DHID + g * 16];
      f16x8 v1 = *(const f16x8*)&Hh[(size_t)s * DHID + g * 16 + 8];
#pragma unroll
      for (int qq = 0; qq < 8; ++qq) acc[qq] += al * (float)v0[qq];
#pragma unroll
      for (int qq = 0; qq < 8; ++qq) acc[8 + qq] += al * (float)v1[qq];
    }
  }

  const float* bv = &bias[g * 16];
  float* ob = &OUT[(size_t)n * DHID + g * 16];
#pragma unroll
  for (int k = 0; k < 4; ++k) {
    float4 b4 = *(const float4*)&bv[k * 4];
    *(float4*)&ob[k * 4] = make_float4(acc[k * 4] + b4.x, acc[k * 4 + 1] + b4.y,
                                       acc[k * 4 + 2] + b4.z, acc[k * 4 + 3] + b4.w);
  }
}

// ---------------- GAT aggregation, layer 2: one node per 16-lane group ----------------
__global__ __launch_bounds__(256) void k_agg2(const int* __restrict__ off, const int* __restrict__ csr,
                                              const float4* __restrict__ as_v, const float4* __restrict__ ad_v,
                                              const ushort_t* __restrict__ Hh, const float* __restrict__ bias,
                                              float* __restrict__ OUT) {
  __shared__ int s_tab[16][65];
  __shared__ __align__(16) float al_tab[16][260];
  const int tid = threadIdx.x;
  const int nd = tid >> 4;
  const int g = tid & 15;
  const int hd = g >> 2;
  const int n = blockIdx.x * 16 + nd;
  if (n >= NN) return;
  const int beg = off[n];
  const int nt = off[n + 1] - beg;
  const float4 adv = ad_v[n];

  float acc[8] = {};
  float rdh;

  if (nt <= 64) {
    float mx0 = -INFINITY, mx1 = -INFINITY, mx2 = -INFINITY, mx3 = -INFINITY;
    for (int le = g; le < nt; le += 16) {
      int s = csr[beg + le];
      float4 a = as_v[s];
      s_tab[nd][le] = s;
      *(float4*)&al_tab[nd][le << 2] = a;
      mx0 = fmaxf(mx0, a.x); mx1 = fmaxf(mx1, a.y);
      mx2 = fmaxf(mx2, a.z); mx3 = fmaxf(mx3, a.w);
    }
#pragma unroll
    for (int m = 1; m < 16; m <<= 1) {
      mx0 = fmaxf(mx0, __shfl_xor(mx0, m)); mx1 = fmaxf(mx1, __shfl_xor(mx1, m));
      mx2 = fmaxf(mx2, __shfl_xor(mx2, m)); mx3 = fmaxf(mx3, __shfl_xor(mx3, m));
    }
    float em0 = lrelu(mx0 + adv.x), em1 = lrelu(mx1 + adv.y);
    float em2 = lrelu(mx2 + adv.z), em3 = lrelu(mx3 + adv.w);
    float s0 = 0.f, s1 = 0.f, s2 = 0.f, s3 = 0.f;
    for (int le = g; le < nt; le += 16) {
      float4 a = *(const float4*)&al_tab[nd][le << 2];
      float p0 = __expf(lrelu(a.x + adv.x) - em0);
      float p1 = __expf(lrelu(a.y + adv.y) - em1);
      float p2 = __expf(lrelu(a.z + adv.z) - em2);
      float p3 = __expf(lrelu(a.w + adv.w) - em3);
      *(float4*)&al_tab[nd][le << 2] = make_float4(p0, p1, p2, p3);
      s0 += p0; s1 += p1; s2 += p2; s3 += p3;
    }
#pragma unroll
    for (int m = 1; m < 16; m <<= 1) {
      s0 += __shfl_xor(s0, m); s1 += __shfl_xor(s1, m);
      s2 += __shfl_xor(s2, m); s3 += __shfl_xor(s3, m);
    }
    rdh = sel_h(hd, 1.f / (s0 + 1e-16f), 1.f / (s1 + 1e-16f),
                    1.f / (s2 + 1e-16f), 1.f / (s3 + 1e-16f));

    // pass C: 2-edge unroll
    int e = 0;
    for (; e + 1 < nt; e += 2) {
      int sA = s_tab[nd][e];
      int sB = s_tab[nd][e + 1];
      float pA = al_tab[nd][(e << 2) | hd] * rdh;
      float pB = al_tab[nd][((e + 1) << 2) | hd] * rdh;
      f16x8 a0 = *(const f16x8*)&Hh[(size_t)sA * DOUT + g * 8];
      f16x8 b0 = *(const f16x8*)&Hh[(size_t)sB * DOUT + g * 8];
#pragma unroll
      for (int qq = 0; qq < 8; ++qq) acc[qq] += pA * (float)a0[qq] + pB * (float)b0[qq];
    }
    if (e < nt) {
      int sA = s_tab[nd][e];
      float pA = al_tab[nd][(e << 2) | hd] * rdh;
      f16x8 a0 = *(const f16x8*)&Hh[(size_t)sA * DOUT + g * 8];
#pragma unroll
      for (int qq = 0; qq < 8; ++qq) acc[qq] += pA * (float)a0[qq];
    }
  } else {
    float mx0 = -INFINITY, mx1 = -INFINITY, mx2 = -INFINITY, mx3 = -INFINITY;
    for (int le = g; le < nt; le += 16) {
      float4 a = as_v[csr[beg + le]];
      mx0 = fmaxf(mx0, a.x); mx1 = fmaxf(mx1, a.y);
      mx2 = fmaxf(mx2, a.z); mx3 = fmaxf(mx3, a.w);
    }
#pragma unroll
    for (int m = 1; m < 16; m <<= 1) {
      mx0 = fmaxf(mx0, __shfl_xor(mx0, m)); mx1 = fmaxf(mx1, __shfl_xor(mx1, m));
      mx2 = fmaxf(mx2, __shfl_xor(mx2, m)); mx3 = fmaxf(mx3, __shfl_xor(mx3, m));
    }
    float em0 = lrelu(mx0 + adv.x), em1 = lrelu(mx1 + adv.y);
    float em2 = lrelu(mx2 + adv.z), em3 = lrelu(mx3 + adv.w);
    float s0 = 0.f, s1 = 0.f, s2 = 0.f, s3 = 0.f;
    for (int le = g; le < nt; le += 16) {
      float4 a = as_v[csr[beg + le]];
      s0 += __expf(lrelu(a.x + adv.x) - em0);
      s1 += __expf(lrelu(a.y + adv.y) - em1);
      s2 += __expf(lrelu(a.z + adv.z) - em2);
      s3 += __expf(lrelu(a.w + adv.w) - em3);
    }
#pragma unroll
    for (int m = 1; m < 16; m <<= 1) {
      s0 += __shfl_xor(s0, m); s1 += __shfl_xor(s1, m);
      s2 += __shfl_xor(s2, m); s3 += __shfl_xor(s3, m);
    }
    rdh = sel_h(hd, 1.f / (s0 + 1e-16f), 1.f / (s1 + 1e-16f),
                    1.f / (s2 + 1e-16f), 1.f / (s3 + 1e-16f));
    float adh = sel_h(hd, adv.x, adv.y, adv.z, adv.w);
    float emh = sel_h(hd, em0, em1, em2, em3);
    for (int e = 0; e < nt; ++e) {
      int s = csr[beg + e];
      float4 a = as_v[s];
      float ah = sel_h(hd, a.x, a.y, a.z, a.w);
      float al = __expf(lrelu(ah + adh) - emh) * rdh;
      f16x8 v0 = *(const f16x8*)&Hh[(size_t)s * DOUT + g * 8];
#pragma unroll
      for (int qq = 0; qq < 8; ++qq) acc[qq] += al * (float)v0[qq];
    }
  }

  const float* bv = &bias[g * 8];
  float* ob = &OUT[(size_t)n * DOUT + g * 8];
#pragma unroll
  for (int k = 0; k < 2; ++k) {
    float4 b4 = *(const float4*)&bv[k * 4];
    *(float4*)&ob[k * 4] = make_float4(acc[k * 4] + b4.x, acc[k * 4 + 1] + b4.y,
                                       acc[k * 4 + 2] + b4.z, acc[k * 4 + 3] + b4.w);
  }
}

// ---------------- pooling (4-way ILP) ----------------
__global__ __launch_bounds__(256) void k_pool(const int* __restrict__ segstart,
                                              const float* __restrict__ OUT2,
                                              const float* __restrict__ OUT1,
                                              float* __restrict__ out) {
  int b = blockIdx.x;
  int t = threadIdx.x;
  int s = segstart[b], e = segstart[b + 1];
  float* ob = out + (size_t)b * 384;
  if (s >= e) {
    for (int i = t; i < 384; i += 256) ob[i] = 0.f;
    return;
  }
  if (t < 128) {
    float s0 = 0.f, s1 = 0.f, s2 = 0.f, s3 = 0.f;
    int n = s;
    for (; n + 3 < e; n += 4) {
      s0 += fmaxf(OUT2[(size_t)n * DOUT + t], 0.f);
      s1 += fmaxf(OUT2[(size_t)(n + 1) * DOUT + t], 0.f);
      s2 += fmaxf(OUT2[(size_t)(n + 2) * DOUT + t], 0.f);
      s3 += fmaxf(OUT2[(size_t)(n + 3) * DOUT + t], 0.f);
    }
    for (; n < e; ++n) s0 += fmaxf(OUT2[(size_t)n * DOUT + t], 0.f);
    ob[t] = ((s0 + s1) + (s2 + s3)) / (float)(e - s);
  } else {
    int k = t - 128;
    ob[128 + k] = OUT1[(size_t)s * DHID + k];
    ob[256 + k] = OUT1[(size_t)s * DHID + 128 + k];
  }
}

// ---------------- launch ----------------
extern "C" void kernel_launch(void* const* d_in, const int* in_sizes, int n_in,
                              void* d_out, int out_size, void* d_ws, size_t ws_size,
                              hipStream_t stream) {
  const float* x    = (const float*)d_in[0];
  const int*   ei   = (const int*)d_in[1];
  const int*   batch = (const int*)d_in[2];
  const float* W1   = (const float*)d_in[3];
  const float* as1w = (const float*)d_in[4];
  const float* ad1w = (const float*)d_in[5];
  const float* b1   = (const float*)d_in[6];
  const float* W2   = (const float*)d_in[7];
  const float* as2w = (const float*)d_in[8];
  const float* ad2w = (const float*)d_in[9];
  const float* b2   = (const float*)d_in[10];
  float* out = (float*)d_out;
  char* ws = (char*)d_ws;

  const int E = in_sizes[1] / 2;
  const int Etot = E + NN;

  // workspace layout (bytes). Wt2h/R2 live INSIDE the H1h region (0..25.6MB):
  // written only AFTER k_agg1 (H1h dead); H2h (0..12.8MB) stays below them.
  ushort_t* H1h = (ushort_t*)(ws + 0);        // NN*256*2 = 25.6 MB (dead after agg1)
  ushort_t* H2h = (ushort_t*)(ws + 0);        // NN*128*2 = 12.8 MB (aliases H1h)
  ushort_t* Wt2h = (ushort_t*)(ws + 13000000);// 262144 B (written AFTER agg1)
  float*  R2   = (float*)(ws + 14000000);     // 512*128*4 (written after agg1)
  float*  OUT2 = (float*)(ws + 25600000);
  float*  OUT1 = (float*)(ws + 51200000);
  float4* as1  = (float4*)(ws + 102400000);
  float4* ad1  = (float4*)(ws + 103200000);
  float4* as2  = (float4*)(ws + 104000000);
  float4* ad2  = (float4*)(ws + 104800000);
  int* deg     = (int*)(ws + 105600000);
  int* cur     = (int*)(ws + 105800000);
  int* off     = (int*)(ws + 106000000);
  int* csr     = (int*)(ws + 106200016);
  int* segstart = (int*)(ws + 109600016);
  int* bsum    = (int*)(ws + 109802080);
  ushort_t* Wt1h = (ushort_t*)(ws + 105600000); // over deg+cur (dead after scatter)

  const int TB = 256;
  const int NB_SCAN = (NN + 1023) / 1024;

  hipMemsetAsync(deg, 0, NN * sizeof(int), stream);
  hipMemsetAsync(cur, 0, NN * sizeof(int), stream);
  k_hist<<<(Etot + TB - 1) / TB, TB, 0, stream>>>(ei, deg, E, Etot);
  k_scan1<<<NB_SCAN, 1024, 0, stream>>>(deg, off, bsum, NN);
  k_scan2<<<1, 64, 0, stream>>>(bsum, off, NB_SCAN, NN);
  k_scan3<<<NB_SCAN, 1024, 0, stream>>>(off, bsum, NN);
  k_scatter<<<(Etot + TB - 1) / TB, TB, 0, stream>>>(ei, off, cur, csr, E, Etot);
  k_segstart<<<(NBGRAPH + 1 + TB - 1) / TB, TB, 0, stream>>>(batch, segstart, NN, NBGRAPH);

  // layer 1 (scores1 fused into gemm1m epilogue)
  k_prepW<<<(DIN * DHID + TB - 1) / TB, TB, 0, stream>>>(W1, Wt1h, DIN, DHID);
  dim3 g1((NN + 63) / 64, DHID / 128);
  k_gemm1m<<<g1, TB, 0, stream>>>(x, Wt1h, as1w, ad1w, H1h, as1, ad1);
  k_agg1<<<(NN + 15) / 16, TB, 0, stream>>>(off, csr, as1, ad1, H1h, b1, OUT1);

  // layer 2 (H1h dead now; Wt2h/R2/H2h live in its region; scores2 fused into gemm2m)
  k_prepW<<<((DHID + DIN) * DOUT + TB - 1) / TB, TB, 0, stream>>>(W2, Wt2h, DHID + DIN, DOUT);
  k_gemmR<<<NBGRAPH, TB, 0, stream>>>(x, segstart, Wt2h, R2);
  dim3 g2((NN + 63) / 64, 1);
  k_gemm2m<<<g2, TB, 0, stream>>>(OUT1, batch, Wt2h, R2, as2w, ad2w, H2h, as2, ad2);
  k_agg2<<<(NN + 15) / 16, TB, 0, stream>>>(off, csr, as2, ad2, H2h, b2, OUT2);

  k_pool<<<NBGRAPH, TB, 0, stream>>>(segstart, OUT2, OUT1, out);
}

// Round 21
// 331.062 us; speedup vs baseline: 1.0468x; 1.0011x over previous
//
#include <hip/hip_runtime.h>

#define NN 50000
#define NBGRAPH 512
#define DIN 768
#define DHID 256
#define DOUT 128

typedef unsigned short ushort_t;
typedef __attribute__((ext_vector_type(4))) float f32x4;
typedef _Float16 f16_t;
typedef __attribute__((ext_vector_type(8))) _Float16 f16x8;

__device__ __forceinline__ float lrelu(float v) { return v > 0.f ? v : 0.2f * v; }

__device__ __forceinline__ float h2f_u(ushort_t u) { return (float)__builtin_bit_cast(f16_t, u); }
__device__ __forceinline__ ushort_t f2h_u(float f) { return __builtin_bit_cast(ushort_t, (f16_t)f); }

__device__ __forceinline__ float sel_h(int h, float q0, float q1, float q2, float q3) {
  float lo = (h & 1) ? q1 : q0;
  float hi = (h & 1) ? q3 : q2;
  return (h & 2) ? hi : lo;
}

__device__ __forceinline__ f16x8 cvt8(float4 u, float4 v) {
  unsigned int a = __builtin_bit_cast(unsigned int, __builtin_amdgcn_cvt_pkrtz(u.x, u.y));
  unsigned int b = __builtin_bit_cast(unsigned int, __builtin_amdgcn_cvt_pkrtz(u.z, u.w));
  unsigned int c = __builtin_bit_cast(unsigned int, __builtin_amdgcn_cvt_pkrtz(v.x, v.y));
  unsigned int d = __builtin_bit_cast(unsigned int, __builtin_amdgcn_cvt_pkrtz(v.z, v.w));
  uint4 q = {a, b, c, d};
  return __builtin_bit_cast(f16x8, q);
}
__device__ __forceinline__ f16x8 cvt8_relu(float4 u, float4 v) {
  u.x = fmaxf(u.x, 0.f); u.y = fmaxf(u.y, 0.f); u.z = fmaxf(u.z, 0.f); u.w = fmaxf(u.w, 0.f);
  v.x = fmaxf(v.x, 0.f); v.y = fmaxf(v.y, 0.f); v.z = fmaxf(v.z, 0.f); v.w = fmaxf(v.w, 0.f);
  return cvt8(u, v);
}

// ---------------- CSR build ----------------
__global__ void k_hist(const int* __restrict__ ei, int* __restrict__ deg, int E, int Etot) {
  int e = blockIdx.x * blockDim.x + threadIdx.x;
  if (e >= Etot) return;
  int dst = (e < E) ? ei[e] : (e - E);
  atomicAdd(&deg[dst], 1);
}

__global__ __launch_bounds__(1024) void k_scan1(const int* __restrict__ deg, int* __restrict__ off,
                                                int* __restrict__ bsum, int n) {
  __shared__ int wsum[16];
  int tid = threadIdx.x, lane = tid & 63, w = tid >> 6;
  int i = blockIdx.x * 1024 + tid;
  int v = (i < n) ? deg[i] : 0;
  int x = v;
#pragma unroll
  for (int d = 1; d < 64; d <<= 1) { int t = __shfl_up(x, d); if (lane >= d) x += t; }
  if (lane == 63) wsum[w] = x;
  __syncthreads();
  if (tid < 16) {
    int y = wsum[tid];
#pragma unroll
    for (int d = 1; d < 16; d <<= 1) { int t = __shfl_up(y, d); if (tid >= d) y += t; }
    wsum[tid] = y;
  }
  __syncthreads();
  int base = (w > 0) ? wsum[w - 1] : 0;
  if (i < n) off[i] = base + x - v;
  if (tid == 1023) bsum[blockIdx.x] = wsum[15];
}

__global__ void k_scan2(int* __restrict__ bsum, int* __restrict__ off, int nb, int n) {
  int lane = threadIdx.x;
  int v = (lane < nb) ? bsum[lane] : 0;
  int x = v;
#pragma unroll
  for (int d = 1; d < 64; d <<= 1) { int t = __shfl_up(x, d); if (lane >= d) x += t; }
  if (lane < nb) bsum[lane] = x - v;
  if (lane == 63) off[n] = x;
}

__global__ void k_scan3(int* __restrict__ off, const int* __restrict__ bsum, int n) {
  int i = blockIdx.x * blockDim.x + threadIdx.x;
  if (i < n) off[i] += bsum[i >> 10];
}

__global__ void k_scatter(const int* __restrict__ ei, const int* __restrict__ off,
                          int* __restrict__ cur, int* __restrict__ csr, int E, int Etot) {
  int e = blockIdx.x * blockDim.x + threadIdx.x;
  if (e >= Etot) return;
  int dst, src;
  if (e < E) { dst = ei[e]; src = ei[E + e]; }
  else       { dst = src = e - E; }
  int p = atomicAdd(&cur[dst], 1);
  csr[off[dst] + p] = src;
}

// ---------------- roots / segments ----------------
__global__ void k_segstart(const int* __restrict__ batch, int* __restrict__ segstart, int n, int b_cnt) {
  int b = blockIdx.x * blockDim.x + threadIdx.x;
  if (b > b_cnt) return;
  int lo = 0, hi = n;
  while (lo < hi) { int mid = (lo + hi) >> 1; if (batch[mid] < b) lo = mid + 1; else hi = mid; }
  segstart[b] = lo;
}

// ---------------- weight transpose+cast (fp16): Wt[n][k] = f16(W[k][n]) ----------------
__global__ void k_prepW(const float* __restrict__ W, ushort_t* __restrict__ Wt, int K, int N) {
  int id = blockIdx.x * blockDim.x + threadIdx.x;
  if (id >= K * N) return;
  int n = id / K, k = id - n * K;
  Wt[(size_t)n * K + k] = f2h_u(W[(size_t)k * N + n]);
}

// ---------------- GEMM1: BM=64, BN=128, BK=64; epilogue fuses scores1 ----------------
#define LDT2 72
__global__ __launch_bounds__(256) void k_gemm1m(const float* __restrict__ A,
                                                const ushort_t* __restrict__ Bt,
                                                const float* __restrict__ att_s,
                                                const float* __restrict__ att_d,
                                                ushort_t* __restrict__ C,
                                                float4* __restrict__ as_out,
                                                float4* __restrict__ ad_out) {
  const int K = DIN, NC = DHID;
  __shared__ __align__(16) ushort_t As[64 * LDT2];
  __shared__ __align__(16) ushort_t Bs[128 * LDT2];
  const int tid = threadIdx.x;
  const int bm = blockIdx.x * 64;
  const int bn = blockIdx.y * 128;
  const int row = tid >> 2, q = tid & 3;
  const int arow = bm + row;
  const int r_c = arow < NN ? arow : NN - 1;
  const int wid = tid >> 6, lane = tid & 63;
  const int wr = (wid >> 1) * 32, wc = (wid & 1) * 64;
  const int fr = lane & 15, fg = lane >> 4;
  const float* aptr = &A[(size_t)r_c * K + q * 16];
  const int bc0 = tid >> 3, bk0 = tid & 7;
  const int bc1 = (tid + 256) >> 3, bk1 = (tid + 256) & 7;
  const int bc2 = (tid + 512) >> 3, bk2 = (tid + 512) & 7;
  const int bc3 = (tid + 768) >> 3, bk3 = (tid + 768) & 7;
  const ushort_t* bp0 = &Bt[(size_t)(bn + bc0) * K + bk0 * 8];
  const ushort_t* bp1 = &Bt[(size_t)(bn + bc1) * K + bk1 * 8];
  const ushort_t* bp2 = &Bt[(size_t)(bn + bc2) * K + bk2 * 8];
  const ushort_t* bp3 = &Bt[(size_t)(bn + bc3) * K + bk3 * 8];
  f32x4 acc[2][4] = {};

  float4 Pa0, Pa1, Pa2, Pa3; uint4 Pb0, Pb1, Pb2, Pb3;
  float4 Qa0, Qa1, Qa2, Qa3; uint4 Qb0, Qb1, Qb2, Qb3;

  auto loadP = [&](int kk) {
    const float4* s = (const float4*)(aptr + kk);
    Pa0 = s[0]; Pa1 = s[1]; Pa2 = s[2]; Pa3 = s[3];
    Pb0 = *(const uint4*)(bp0 + kk); Pb1 = *(const uint4*)(bp1 + kk);
    Pb2 = *(const uint4*)(bp2 + kk); Pb3 = *(const uint4*)(bp3 + kk);
  };
  auto loadQ = [&](int kk) {
    const float4* s = (const float4*)(aptr + kk);
    Qa0 = s[0]; Qa1 = s[1]; Qa2 = s[2]; Qa3 = s[3];
    Qb0 = *(const uint4*)(bp0 + kk); Qb1 = *(const uint4*)(bp1 + kk);
    Qb2 = *(const uint4*)(bp2 + kk); Qb3 = *(const uint4*)(bp3 + kk);
  };
  auto stage = [&](float4 a0, float4 a1, float4 a2, float4 a3,
                   uint4 b0, uint4 b1, uint4 b2, uint4 b3) {
    const int p = row * LDT2 + q * 16;
    *(f16x8*)&As[p + 0] = cvt8(a0, a1);
    *(f16x8*)&As[p + 8] = cvt8(a2, a3);
    *(uint4*)&Bs[bc0 * LDT2 + bk0 * 8] = b0;
    *(uint4*)&Bs[bc1 * LDT2 + bk1 * 8] = b1;
    *(uint4*)&Bs[bc2 * LDT2 + bk2 * 8] = b2;
    *(uint4*)&Bs[bc3 * LDT2 + bk3 * 8] = b3;
  };
  auto compute = [&]() {
#pragma unroll
    for (int kk = 0; kk < 64; kk += 32) {
      f16x8 af0 = *(const f16x8*)&As[(wr + fr) * LDT2 + kk + fg * 8];
      f16x8 af1 = *(const f16x8*)&As[(wr + 16 + fr) * LDT2 + kk + fg * 8];
      f16x8 bf0 = *(const f16x8*)&Bs[(wc + fr) * LDT2 + kk + fg * 8];
      f16x8 bf1 = *(const f16x8*)&Bs[(wc + 16 + fr) * LDT2 + kk + fg * 8];
      f16x8 bf2 = *(const f16x8*)&Bs[(wc + 32 + fr) * LDT2 + kk + fg * 8];
      f16x8 bf3 = *(const f16x8*)&Bs[(wc + 48 + fr) * LDT2 + kk + fg * 8];
      acc[0][0] = __builtin_amdgcn_mfma_f32_16x16x32_f16(af0, bf0, acc[0][0], 0, 0, 0);
      acc[0][1] = __builtin_amdgcn_mfma_f32_16x16x32_f16(af0, bf1, acc[0][1], 0, 0, 0);
      acc[0][2] = __builtin_amdgcn_mfma_f32_16x16x32_f16(af0, bf2, acc[0][2], 0, 0, 0);
      acc[0][3] = __builtin_amdgcn_mfma_f32_16x16x32_f16(af0, bf3, acc[0][3], 0, 0, 0);
      acc[1][0] = __builtin_amdgcn_mfma_f32_16x16x32_f16(af1, bf0, acc[1][0], 0, 0, 0);
      acc[1][1] = __builtin_amdgcn_mfma_f32_16x16x32_f16(af1, bf1, acc[1][1], 0, 0, 0);
      acc[1][2] = __builtin_amdgcn_mfma_f32_16x16x32_f16(af1, bf2, acc[1][2], 0, 0, 0);
      acc[1][3] = __builtin_amdgcn_mfma_f32_16x16x32_f16(af1, bf3, acc[1][3], 0, 0, 0);
    }
  };

  loadP(0);
  loadQ(64);
  for (int k0 = 0; k0 < K; k0 += 128) {
    stage(Pa0, Pa1, Pa2, Pa3, Pb0, Pb1, Pb2, Pb3);
    __syncthreads();
    if (k0 + 128 < K) loadP(k0 + 128);
    compute();
    __syncthreads();
    stage(Qa0, Qa1, Qa2, Qa3, Qb0, Qb1, Qb2, Qb3);
    __syncthreads();
    if (k0 + 192 < K) loadQ(k0 + 192);
    compute();
    __syncthreads();
  }

  // epilogue: store f16 H1 + fused scores1 (wave's cols all in head h = (bn+wc)>>6)
  const int h = (bn + wc) >> 6;
  float as_c[4], ad_c[4];
#pragma unroll
  for (int n = 0; n < 4; ++n) {
    int col = bn + wc + n * 16 + fr;
    as_c[n] = att_s[col];
    ad_c[n] = att_d[col];
  }
#pragma unroll
  for (int m = 0; m < 2; ++m)
#pragma unroll
    for (int j = 0; j < 4; ++j) {
      int r = bm + wr + m * 16 + fg * 4 + j;
      float v0 = acc[m][0][j], v1 = acc[m][1][j], v2 = acc[m][2][j], v3 = acc[m][3][j];
      if (r < NN) {
        C[(size_t)r * NC + bn + wc + fr] = f2h_u(v0);
        C[(size_t)r * NC + bn + wc + 16 + fr] = f2h_u(v1);
        C[(size_t)r * NC + bn + wc + 32 + fr] = f2h_u(v2);
        C[(size_t)r * NC + bn + wc + 48 + fr] = f2h_u(v3);
      }
      float ps = v0 * as_c[0] + v1 * as_c[1] + v2 * as_c[2] + v3 * as_c[3];
      float pd = v0 * ad_c[0] + v1 * ad_c[1] + v2 * ad_c[2] + v3 * ad_c[3];
#pragma unroll
      for (int msk = 1; msk < 16; msk <<= 1) {
        ps += __shfl_xor(ps, msk);
        pd += __shfl_xor(pd, msk);
      }
      if (fr == m * 4 + j && r < NN) {
        ((float*)&as_out[r])[h] = ps;
        ((float*)&ad_out[r])[h] = pd;
      }
    }
}

// ---------------- gemmR: R2[b][c] = relu(x[segstart[b]]) . W2[256:, c]  (512 graphs) ----------------
__global__ __launch_bounds__(256) void k_gemmR(const float* __restrict__ X,
                                               const int* __restrict__ segstart,
                                               const ushort_t* __restrict__ Wt2,
                                               float* __restrict__ R2) {
  __shared__ float part[2][128];
  const int b = blockIdx.x;
  const int t = threadIdx.x;
  const int c = t & 127, seg = t >> 7;
  int root = segstart[b];
  if (root >= NN) root = NN - 1;
  const float* xr = &X[(size_t)root * DIN + seg * 384];
  const ushort_t* wp = &Wt2[(size_t)c * (DHID + DIN) + DHID + seg * 384];
  float s = 0.f;
#pragma unroll 4
  for (int k = 0; k < 384; k += 4) {
    float4 xv = *(const float4*)&xr[k];
    ushort4 wv = *(const ushort4*)&wp[k];
    s += fmaxf(xv.x, 0.f) * h2f_u(wv.x);
    s += fmaxf(xv.y, 0.f) * h2f_u(wv.y);
    s += fmaxf(xv.z, 0.f) * h2f_u(wv.z);
    s += fmaxf(xv.w, 0.f) * h2f_u(wv.w);
  }
  part[seg][c] = s;
  __syncthreads();
  if (t < 128) R2[(size_t)b * DOUT + t] = part[0][t] + part[1][t];
}

// ---------------- GEMM2: K=256, 2-deep prefetch; epilogue adds R2 AND fuses scores2 ----------------
__global__ __launch_bounds__(256) void k_gemm2m(const float* __restrict__ OUT1,
                                                const int* __restrict__ batch,
                                                const ushort_t* __restrict__ Bt,
                                                const float* __restrict__ R2,
                                                const float* __restrict__ att_s,
                                                const float* __restrict__ att_d,
                                                ushort_t* __restrict__ C,
                                                float4* __restrict__ as_out,
                                                float4* __restrict__ ad_out) {
  const int K = DHID;           // 256
  const int KS = DHID + DIN;    // B row stride = 1024
  __shared__ __align__(16) ushort_t As[64 * LDT2];
  __shared__ __align__(16) ushort_t Bs[128 * LDT2];
  const int tid = threadIdx.x;
  const int bm = blockIdx.x * 64;
  const int row = tid >> 2, q = tid & 3;
  const int arow = bm + row;
  const int r_c = arow < NN ? arow : NN - 1;
  const int wid = tid >> 6, lane = tid & 63;
  const int wr = (wid >> 1) * 32, wc = (wid & 1) * 64;
  const int fr = lane & 15, fg = lane >> 4;
  const float* aptr = &OUT1[(size_t)r_c * DHID + q * 16];
  const int bc0 = tid >> 3, bk0 = tid & 7;
  const int bc1 = (tid + 256) >> 3, bk1 = (tid + 256) & 7;
  const int bc2 = (tid + 512) >> 3, bk2 = (tid + 512) & 7;
  const int bc3 = (tid + 768) >> 3, bk3 = (tid + 768) & 7;
  const ushort_t* bp0 = &Bt[(size_t)bc0 * KS + bk0 * 8];
  const ushort_t* bp1 = &Bt[(size_t)bc1 * KS + bk1 * 8];
  const ushort_t* bp2 = &Bt[(size_t)bc2 * KS + bk2 * 8];
  const ushort_t* bp3 = &Bt[(size_t)bc3 * KS + bk3 * 8];
  f32x4 acc[2][4] = {};

  float4 Pa0, Pa1, Pa2, Pa3; uint4 Pb0, Pb1, Pb2, Pb3;
  float4 Qa0, Qa1, Qa2, Qa3; uint4 Qb0, Qb1, Qb2, Qb3;

  auto loadP = [&](int kk) {
    const float4* s = (const float4*)(aptr + kk);
    Pa0 = s[0]; Pa1 = s[1]; Pa2 = s[2]; Pa3 = s[3];
    Pb0 = *(const uint4*)(bp0 + kk); Pb1 = *(const uint4*)(bp1 + kk);
    Pb2 = *(const uint4*)(bp2 + kk); Pb3 = *(const uint4*)(bp3 + kk);
  };
  auto loadQ = [&](int kk) {
    const float4* s = (const float4*)(aptr + kk);
    Qa0 = s[0]; Qa1 = s[1]; Qa2 = s[2]; Qa3 = s[3];
    Qb0 = *(const uint4*)(bp0 + kk); Qb1 = *(const uint4*)(bp1 + kk);
    Qb2 = *(const uint4*)(bp2 + kk); Qb3 = *(const uint4*)(bp3 + kk);
  };
  auto stage = [&](float4 a0, float4 a1, float4 a2, float4 a3,
                   uint4 b0, uint4 b1, uint4 b2, uint4 b3) {
    const int p = row * LDT2 + q * 16;
    *(f16x8*)&As[p + 0] = cvt8_relu(a0, a1);
    *(f16x8*)&As[p + 8] = cvt8_relu(a2, a3);
    *(uint4*)&Bs[bc0 * LDT2 + bk0 * 8] = b0;
    *(uint4*)&Bs[bc1 * LDT2 + bk1 * 8] = b1;
    *(uint4*)&Bs[bc2 * LDT2 + bk2 * 8] = b2;
    *(uint4*)&Bs[bc3 * LDT2 + bk3 * 8] = b3;
  };
  auto compute = [&]() {
#pragma unroll
    for (int kk = 0; kk < 64; kk += 32) {
      f16x8 af0 = *(const f16x8*)&As[(wr + fr) * LDT2 + kk + fg * 8];
      f16x8 af1 = *(const f16x8*)&As[(wr + 16 + fr) * LDT2 + kk + fg * 8];
      f16x8 bf0 = *(const f16x8*)&Bs[(wc + fr) * LDT2 + kk + fg * 8];
      f16x8 bf1 = *(const f16x8*)&Bs[(wc + 16 + fr) * LDT2 + kk + fg * 8];
      f16x8 bf2 = *(const f16x8*)&Bs[(wc + 32 + fr) * LDT2 + kk + fg * 8];
      f16x8 bf3 = *(const f16x8*)&Bs[(wc + 48 + fr) * LDT2 + kk + fg * 8];
      acc[0][0] = __builtin_amdgcn_mfma_f32_16x16x32_f16(af0, bf0, acc[0][0], 0, 0, 0);
      acc[0][1] = __builtin_amdgcn_mfma_f32_16x16x32_f16(af0, bf1, acc[0][1], 0, 0, 0);
      acc[0][2] = __builtin_amdgcn_mfma_f32_16x16x32_f16(af0, bf2, acc[0][2], 0, 0, 0);
      acc[0][3] = __builtin_amdgcn_mfma_f32_16x16x32_f16(af0, bf3, acc[0][3], 0, 0, 0);
      acc[1][0] = __builtin_amdgcn_mfma_f32_16x16x32_f16(af1, bf0, acc[1][0], 0, 0, 0);
      acc[1][1] = __builtin_amdgcn_mfma_f32_16x16x32_f16(af1, bf1, acc[1][1], 0, 0, 0);
      acc[1][2] = __builtin_amdgcn_mfma_f32_16x16x32_f16(af1, bf2, acc[1][2], 0, 0, 0);
      acc[1][3] = __builtin_amdgcn_mfma_f32_16x16x32_f16(af1, bf3, acc[1][3], 0, 0, 0);
    }
  };

  loadP(0);
  loadQ(64);
  for (int k0 = 0; k0 < K; k0 += 128) {
    stage(Pa0, Pa1, Pa2, Pa3, Pb0, Pb1, Pb2, Pb3);
    __syncthreads();
    if (k0 + 128 < K) loadP(k0 + 128);
    compute();
    __syncthreads();
    stage(Qa0, Qa1, Qa2, Qa3, Qb0, Qb1, Qb2, Qb3);
    __syncthreads();
    if (k0 + 192 < K) loadQ(k0 + 192);
    compute();
    __syncthreads();
  }

  // epilogue: v = acc + R2[batch[r]]; store f16 H2; fused per-head score dots.
  float as_c[4], ad_c[4];
#pragma unroll
  for (int n = 0; n < 4; ++n) {
    int col = wc + n * 16 + fr;
    as_c[n] = att_s[col];
    ad_c[n] = att_d[col];
  }
#pragma unroll
  for (int m = 0; m < 2; ++m)
#pragma unroll
    for (int j = 0; j < 4; ++j) {
      int r = bm + wr + m * 16 + fg * 4 + j;
      int rc = r < NN ? r : NN - 1;
      int gb = batch[rc];
      const float* r2 = &R2[(size_t)gb * DOUT];
      float v0 = acc[m][0][j] + r2[wc + fr];
      float v1 = acc[m][1][j] + r2[wc + 16 + fr];
      float v2 = acc[m][2][j] + r2[wc + 32 + fr];
      float v3 = acc[m][3][j] + r2[wc + 48 + fr];
      if (r < NN) {
        C[(size_t)r * DOUT + wc + fr] = f2h_u(v0);
        C[(size_t)r * DOUT + wc + 16 + fr] = f2h_u(v1);
        C[(size_t)r * DOUT + wc + 32 + fr] = f2h_u(v2);
        C[(size_t)r * DOUT + wc + 48 + fr] = f2h_u(v3);
      }
      float psl = v0 * as_c[0] + v1 * as_c[1];
      float psh = v2 * as_c[2] + v3 * as_c[3];
      float pdl = v0 * ad_c[0] + v1 * ad_c[1];
      float pdh = v2 * ad_c[2] + v3 * ad_c[3];
#pragma unroll
      for (int msk = 1; msk < 16; msk <<= 1) {
        psl += __shfl_xor(psl, msk);
        psh += __shfl_xor(psh, msk);
        pdl += __shfl_xor(pdl, msk);
        pdh += __shfl_xor(pdh, msk);
      }
      if (fr == m * 4 + j && r < NN) {
        float* sp = (float*)&as_out[r] + (wid & 1) * 2;
        float* dp = (float*)&ad_out[r] + (wid & 1) * 2;
        sp[0] = psl; sp[1] = psh;
        dp[0] = pdl; dp[1] = pdh;
      }
    }
}

// ---------------- GAT aggregation, layer 1: one node per 16-lane group ----------------
__global__ __launch_bounds__(256) void k_agg1(const int* __restrict__ off, const int* __restrict__ csr,
                                              const float4* __restrict__ as_v, const float4* __restrict__ ad_v,
                                              const ushort_t* __restrict__ Hh, const float* __restrict__ bias,
                                              float* __restrict__ OUT) {
  __shared__ int s_tab[16][65];
  __shared__ __align__(16) float al_tab[16][260];
  const int tid = threadIdx.x;
  const int nd = tid >> 4;
  const int g = tid & 15;
  const int hd = g >> 2;
  const int n = blockIdx.x * 16 + nd;
  if (n >= NN) return;
  const int beg = off[n];
  const int nt = off[n + 1] - beg;
  const float4 adv = ad_v[n];

  float acc[16] = {};
  float rdh;

  if (nt <= 64) {
    float mx0 = -INFINITY, mx1 = -INFINITY, mx2 = -INFINITY, mx3 = -INFINITY;
    for (int le = g; le < nt; le += 16) {
      int s = csr[beg + le];
      float4 a = as_v[s];
      s_tab[nd][le] = s;
      *(float4*)&al_tab[nd][le << 2] = a;
      mx0 = fmaxf(mx0, a.x); mx1 = fmaxf(mx1, a.y);
      mx2 = fmaxf(mx2, a.z); mx3 = fmaxf(mx3, a.w);
    }
#pragma unroll
    for (int m = 1; m < 16; m <<= 1) {
      mx0 = fmaxf(mx0, __shfl_xor(mx0, m)); mx1 = fmaxf(mx1, __shfl_xor(mx1, m));
      mx2 = fmaxf(mx2, __shfl_xor(mx2, m)); mx3 = fmaxf(mx3, __shfl_xor(mx3, m));
    }
    float em0 = lrelu(mx0 + adv.x), em1 = lrelu(mx1 + adv.y);
    float em2 = lrelu(mx2 + adv.z), em3 = lrelu(mx3 + adv.w);
    float s0 = 0.f, s1 = 0.f, s2 = 0.f, s3 = 0.f;
    for (int le = g; le < nt; le += 16) {
      float4 a = *(const float4*)&al_tab[nd][le << 2];
      float p0 = __expf(lrelu(a.x + adv.x) - em0);
      float p1 = __expf(lrelu(a.y + adv.y) - em1);
      float p2 = __expf(lrelu(a.z + adv.z) - em2);
      float p3 = __expf(lrelu(a.w + adv.w) - em3);
      *(float4*)&al_tab[nd][le << 2] = make_float4(p0, p1, p2, p3);
      s0 += p0; s1 += p1; s2 += p2; s3 += p3;
    }
#pragma unroll
    for (int m = 1; m < 16; m <<= 1) {
      s0 += __shfl_xor(s0, m); s1 += __shfl_xor(s1, m);
      s2 += __shfl_xor(s2, m); s3 += __shfl_xor(s3, m);
    }
    rdh = sel_h(hd, 1.f / (s0 + 1e-16f), 1.f / (s1 + 1e-16f),
                    1.f / (s2 + 1e-16f), 1.f / (s3 + 1e-16f));

    // pass C: 4-edge unroll (8 independent 16B loads in flight per lane)
    int e = 0;
    for (; e + 3 < nt; e += 4) {
      int sA = s_tab[nd][e], sB = s_tab[nd][e + 1];
      int sC = s_tab[nd][e + 2], sD = s_tab[nd][e + 3];
      float pA = al_tab[nd][(e << 2) | hd] * rdh;
      float pB = al_tab[nd][((e + 1) << 2) | hd] * rdh;
      float pC = al_tab[nd][((e + 2) << 2) | hd] * rdh;
      float pD = al_tab[nd][((e + 3) << 2) | hd] * rdh;
      f16x8 a0 = *(const f16x8*)&Hh[(size_t)sA * DHID + g * 16];
      f16x8 a1 = *(const f16x8*)&Hh[(size_t)sA * DHID + g * 16 + 8];
      f16x8 b0 = *(const f16x8*)&Hh[(size_t)sB * DHID + g * 16];
      f16x8 b1 = *(const f16x8*)&Hh[(size_t)sB * DHID + g * 16 + 8];
      f16x8 c0 = *(const f16x8*)&Hh[(size_t)sC * DHID + g * 16];
      f16x8 c1 = *(const f16x8*)&Hh[(size_t)sC * DHID + g * 16 + 8];
      f16x8 d0 = *(const f16x8*)&Hh[(size_t)sD * DHID + g * 16];
      f16x8 d1 = *(const f16x8*)&Hh[(size_t)sD * DHID + g * 16 + 8];
#pragma unroll
      for (int qq = 0; qq < 8; ++qq)
        acc[qq] += (pA * (float)a0[qq] + pB * (float)b0[qq]) +
                   (pC * (float)c0[qq] + pD * (float)d0[qq]);
#pragma unroll
      for (int qq = 0; qq < 8; ++qq)
        acc[8 + qq] += (pA * (float)a1[qq] + pB * (float)b1[qq]) +
                       (pC * (float)c1[qq] + pD * (float)d1[qq]);
    }
    for (; e < nt; ++e) {
      int sA = s_tab[nd][e];
      float pA = al_tab[nd][(e << 2) | hd] * rdh;
      f16x8 a0 = *(const f16x8*)&Hh[(size_t)sA * DHID + g * 16];
      f16x8 a1 = *(const f16x8*)&Hh[(size_t)sA * DHID + g * 16 + 8];
#pragma unroll
      for (int qq = 0; qq < 8; ++qq) acc[qq] += pA * (float)a0[qq];
#pragma unroll
      for (int qq = 0; qq < 8; ++qq) acc[8 + qq] += pA * (float)a1[qq];
    }
  } else {
    float mx0 = -INFINITY, mx1 = -INFINITY, mx2 = -INFINITY, mx3 = -INFINITY;
    for (int le = g; le < nt; le += 16) {
      float4 a = as_v[csr[beg + le]];
      mx0 = fmaxf(mx0, a.x); mx1 = fmaxf(mx1, a.y);
      mx2 = fmaxf(mx2, a.z); mx3 = fmaxf(mx3, a.w);
    }
#pragma unroll
    for (int m = 1; m < 16; m <<= 1) {
      mx0 = fmaxf(mx0, __shfl_xor(mx0, m)); mx1 = fmaxf(mx1, __shfl_xor(mx1, m));
      mx2 = fmaxf(mx2, __shfl_xor(mx2, m)); mx3 = fmaxf(mx3, __shfl_xor(mx3, m));
    }
    float em0 = lrelu(mx0 + adv.x), em1 = lrelu(mx1 + adv.y);
    float em2 = lrelu(mx2 + adv.z), em3 = lrelu(mx3 + adv.w);
    float s0 = 0.f, s1 = 0.f, s2 = 0.f, s3 = 0.f;
    for (int le = g; le < nt; le += 16) {
      float4 a = as_v[csr[beg + le]];
      s0 += __expf(lrelu(a.x + adv.x) - em0);
      s1 += __expf(lrelu(a.y + adv.y) - em1);
      s2 += __expf(lrelu(a.z + adv.z) - em2);
      s3 += __expf(lrelu(a.w + adv.w) - em3);
    }
#pragma unroll
    for (int m = 1; m < 16; m <<= 1) {
      s0 += __shfl_xor(s0, m); s1 += __shfl_xor(s1, m);
      s2 += __shfl_xor(s2, m); s3 += __shfl_xor(s3, m);
    }
    rdh = sel_h(hd, 1.f / (s0 + 1e-16f), 1.f / (s1 + 1e-16f),
                    1.f / (s2 + 1e-16f), 1.f / (s3 + 1e-16f));
    float adh = sel_h(hd, adv.x, adv.y, adv.z, adv.w);
    float emh = sel_h(hd, em0, em1, em2, em3);
    for (int e = 0; e < nt; ++e) {
      int s = csr[beg + e];
      float4 a = as_v[s];
      float ah = sel_h(hd, a.x, a.y, a.z, a.w);
      float al = __expf(lrelu(ah + adh) - emh) * rdh;
      f16x8 v0 = *(const f16x8*)&Hh[(size_t)s * DHID + g * 16];
      f16x8 v1 = *(const f16x8*)&Hh[(size_t)s * DHID + g * 16 + 8];
#pragma unroll
      for (int qq = 0; qq < 8; ++qq) acc[qq] += al * (float)v0[qq];
#pragma unroll
      for (int qq = 0; qq < 8; ++qq) acc[8 + qq] += al * (float)v1[qq];
    }
  }

  const float* bv = &bias[g * 16];
  float* ob = &OUT[(size_t)n * DHID + g * 16];
#pragma unroll
  for (int k = 0; k < 4; ++k) {
    float4 b4 = *(const float4*)&bv[k * 4];
    *(float4*)&ob[k * 4] = make_float4(acc[k * 4] + b4.x, acc[k * 4 + 1] + b4.y,
                                       acc[k * 4 + 2] + b4.z, acc[k * 4 + 3] + b4.w);
  }
}

// ---------------- GAT aggregation, layer 2: one node per 16-lane group ----------------
__global__ __launch_bounds__(256) void k_agg2(const int* __restrict__ off, const int* __restrict__ csr,
                                              const float4* __restrict__ as_v, const float4* __restrict__ ad_v,
                                              const ushort_t* __restrict__ Hh, const float* __restrict__ bias,
                                              float* __restrict__ OUT) {
  __shared__ int s_tab[16][65];
  __shared__ __align__(16) float al_tab[16][260];
  const int tid = threadIdx.x;
  const int nd = tid >> 4;
  const int g = tid & 15;
  const int hd = g >> 2;
  const int n = blockIdx.x * 16 + nd;
  if (n >= NN) return;
  const int beg = off[n];
  const int nt = off[n + 1] - beg;
  const float4 adv = ad_v[n];

  float acc[8] = {};
  float rdh;

  if (nt <= 64) {
    float mx0 = -INFINITY, mx1 = -INFINITY, mx2 = -INFINITY, mx3 = -INFINITY;
    for (int le = g; le < nt; le += 16) {
      int s = csr[beg + le];
      float4 a = as_v[s];
      s_tab[nd][le] = s;
      *(float4*)&al_tab[nd][le << 2] = a;
      mx0 = fmaxf(mx0, a.x); mx1 = fmaxf(mx1, a.y);
      mx2 = fmaxf(mx2, a.z); mx3 = fmaxf(mx3, a.w);
    }
#pragma unroll
    for (int m = 1; m < 16; m <<= 1) {
      mx0 = fmaxf(mx0, __shfl_xor(mx0, m)); mx1 = fmaxf(mx1, __shfl_xor(mx1, m));
      mx2 = fmaxf(mx2, __shfl_xor(mx2, m)); mx3 = fmaxf(mx3, __shfl_xor(mx3, m));
    }
    float em0 = lrelu(mx0 + adv.x), em1 = lrelu(mx1 + adv.y);
    float em2 = lrelu(mx2 + adv.z), em3 = lrelu(mx3 + adv.w);
    float s0 = 0.f, s1 = 0.f, s2 = 0.f, s3 = 0.f;
    for (int le = g; le < nt; le += 16) {
      float4 a = *(const float4*)&al_tab[nd][le << 2];
      float p0 = __expf(lrelu(a.x + adv.x) - em0);
      float p1 = __expf(lrelu(a.y + adv.y) - em1);
      float p2 = __expf(lrelu(a.z + adv.z) - em2);
      float p3 = __expf(lrelu(a.w + adv.w) - em3);
      *(float4*)&al_tab[nd][le << 2] = make_float4(p0, p1, p2, p3);
      s0 += p0; s1 += p1; s2 += p2; s3 += p3;
    }
#pragma unroll
    for (int m = 1; m < 16; m <<= 1) {
      s0 += __shfl_xor(s0, m); s1 += __shfl_xor(s1, m);
      s2 += __shfl_xor(s2, m); s3 += __shfl_xor(s3, m);
    }
    rdh = sel_h(hd, 1.f / (s0 + 1e-16f), 1.f / (s1 + 1e-16f),
                    1.f / (s2 + 1e-16f), 1.f / (s3 + 1e-16f));

    // pass C: 4-edge unroll
    int e = 0;
    for (; e + 3 < nt; e += 4) {
      int sA = s_tab[nd][e], sB = s_tab[nd][e + 1];
      int sC = s_tab[nd][e + 2], sD = s_tab[nd][e + 3];
      float pA = al_tab[nd][(e << 2) | hd] * rdh;
      float pB = al_tab[nd][((e + 1) << 2) | hd] * rdh;
      float pC = al_tab[nd][((e + 2) << 2) | hd] * rdh;
      float pD = al_tab[nd][((e + 3) << 2) | hd] * rdh;
      f16x8 a0 = *(const f16x8*)&Hh[(size_t)sA * DOUT + g * 8];
      f16x8 b0 = *(const f16x8*)&Hh[(size_t)sB * DOUT + g * 8];
      f16x8 c0 = *(const f16x8*)&Hh[(size_t)sC * DOUT + g * 8];
      f16x8 d0 = *(const f16x8*)&Hh[(size_t)sD * DOUT + g * 8];
#pragma unroll
      for (int qq = 0; qq < 8; ++qq)
        acc[qq] += (pA * (float)a0[qq] + pB * (float)b0[qq]) +
                   (pC * (float)c0[qq] + pD * (float)d0[qq]);
    }
    for (; e < nt; ++e) {
      int sA = s_tab[nd][e];
      float pA = al_tab[nd][(e << 2) | hd] * rdh;
      f16x8 a0 = *(const f16x8*)&Hh[(size_t)sA * DOUT + g * 8];
#pragma unroll
      for (int qq = 0; qq < 8; ++qq) acc[qq] += pA * (float)a0[qq];
    }
  } else {
    float mx0 = -INFINITY, mx1 = -INFINITY, mx2 = -INFINITY, mx3 = -INFINITY;
    for (int le = g; le < nt; le += 16) {
      float4 a = as_v[csr[beg + le]];
      mx0 = fmaxf(mx0, a.x); mx1 = fmaxf(mx1, a.y);
      mx2 = fmaxf(mx2, a.z); mx3 = fmaxf(mx3, a.w);
    }
#pragma unroll
    for (int m = 1; m < 16; m <<= 1) {
      mx0 = fmaxf(mx0, __shfl_xor(mx0, m)); mx1 = fmaxf(mx1, __shfl_xor(mx1, m));
      mx2 = fmaxf(mx2, __shfl_xor(mx2, m)); mx3 = fmaxf(mx3, __shfl_xor(mx3, m));
    }
    float em0 = lrelu(mx0 + adv.x), em1 = lrelu(mx1 + adv.y);
    float em2 = lrelu(mx2 + adv.z), em3 = lrelu(mx3 + adv.w);
    float s0 = 0.f, s1 = 0.f, s2 = 0.f, s3 = 0.f;
    for (int le = g; le < nt; le += 16) {
      float4 a = as_v[csr[beg + le]];
      s0 += __expf(lrelu(a.x + adv.x) - em0);
      s1 += __expf(lrelu(a.y + adv.y) - em1);
      s2 += __expf(lrelu(a.z + adv.z) - em2);
      s3 += __expf(lrelu(a.w + adv.w) - em3);
    }
#pragma unroll
    for (int m = 1; m < 16; m <<= 1) {
      s0 += __shfl_xor(s0, m); s1 += __shfl_xor(s1, m);
      s2 += __shfl_xor(s2, m); s3 += __shfl_xor(s3, m);
    }
    rdh = sel_h(hd, 1.f / (s0 + 1e-16f), 1.f / (s1 + 1e-16f),
                    1.f / (s2 + 1e-16f), 1.f / (s3 + 1e-16f));
    float adh = sel_h(hd, adv.x, adv.y, adv.z, adv.w);
    float emh = sel_h(hd, em0, em1, em2, em3);
    for (int e = 0; e < nt; ++e) {
      int s = csr[beg + e];
      float4 a = as_v[s];
      float ah = sel_h(hd, a.x, a.y, a.z, a.w);
      float al = __expf(lrelu(ah + adh) - emh) * rdh;
      f16x8 v0 = *(const f16x8*)&Hh[(size_t)s * DOUT + g * 8];
#pragma unroll
      for (int qq = 0; qq < 8; ++qq) acc[qq] += al * (float)v0[qq];
    }
  }

  const float* bv = &bias[g * 8];
  float* ob = &OUT[(size_t)n * DOUT + g * 8];
#pragma unroll
  for (int k = 0; k < 2; ++k) {
    float4 b4 = *(const float4*)&bv[k * 4];
    *(float4*)&ob[k * 4] = make_float4(acc[k * 4] + b4.x, acc[k * 4 + 1] + b4.y,
                                       acc[k * 4 + 2] + b4.z, acc[k * 4 + 3] + b4.w);
  }
}

// ---------------- pooling (4-way ILP) ----------------
__global__ __launch_bounds__(256) void k_pool(const int* __restrict__ segstart,
                                              const float* __restrict__ OUT2,
                                              const float* __restrict__ OUT1,
                                              float* __restrict__ out) {
  int b = blockIdx.x;
  int t = threadIdx.x;
  int s = segstart[b], e = segstart[b + 1];
  float* ob = out + (size_t)b * 384;
  if (s >= e) {
    for (int i = t; i < 384; i += 256) ob[i] = 0.f;
    return;
  }
  if (t < 128) {
    float s0 = 0.f, s1 = 0.f, s2 = 0.f, s3 = 0.f;
    int n = s;
    for (; n + 3 < e; n += 4) {
      s0 += fmaxf(OUT2[(size_t)n * DOUT + t], 0.f);
      s1 += fmaxf(OUT2[(size_t)(n + 1) * DOUT + t], 0.f);
      s2 += fmaxf(OUT2[(size_t)(n + 2) * DOUT + t], 0.f);
      s3 += fmaxf(OUT2[(size_t)(n + 3) * DOUT + t], 0.f);
    }
    for (; n < e; ++n) s0 += fmaxf(OUT2[(size_t)n * DOUT + t], 0.f);
    ob[t] = ((s0 + s1) + (s2 + s3)) / (float)(e - s);
  } else {
    int k = t - 128;
    ob[128 + k] = OUT1[(size_t)s * DHID + k];
    ob[256 + k] = OUT1[(size_t)s * DHID + 128 + k];
  }
}

// ---------------- launch ----------------
extern "C" void kernel_launch(void* const* d_in, const int* in_sizes, int n_in,
                              void* d_out, int out_size, void* d_ws, size_t ws_size,
                              hipStream_t stream) {
  const float* x    = (const float*)d_in[0];
  const int*   ei   = (const int*)d_in[1];
  const int*   batch = (const int*)d_in[2];
  const float* W1   = (const float*)d_in[3];
  const float* as1w = (const float*)d_in[4];
  const float* ad1w = (const float*)d_in[5];
  const float* b1   = (const float*)d_in[6];
  const float* W2   = (const float*)d_in[7];
  const float* as2w = (const float*)d_in[8];
  const float* ad2w = (const float*)d_in[9];
  const float* b2   = (const float*)d_in[10];
  float* out = (float*)d_out;
  char* ws = (char*)d_ws;

  const int E = in_sizes[1] / 2;
  const int Etot = E + NN;

  // workspace layout (bytes). Wt2h/R2 live INSIDE the H1h region (0..25.6MB):
  // written only AFTER k_agg1 (H1h dead); H2h (0..12.8MB) stays below them.
  ushort_t* H1h = (ushort_t*)(ws + 0);        // NN*256*2 = 25.6 MB (dead after agg1)
  ushort_t* H2h = (ushort_t*)(ws + 0);        // NN*128*2 = 12.8 MB (aliases H1h)
  ushort_t* Wt2h = (ushort_t*)(ws + 13000000);// 262144 B (written AFTER agg1)
  float*  R2   = (float*)(ws + 14000000);     // 512*128*4 (written after agg1)
  float*  OUT2 = (float*)(ws + 25600000);
  float*  OUT1 = (float*)(ws + 51200000);
  float4* as1  = (float4*)(ws + 102400000);
  float4* ad1  = (float4*)(ws + 103200000);
  float4* as2  = (float4*)(ws + 104000000);
  float4* ad2  = (float4*)(ws + 104800000);
  int* deg     = (int*)(ws + 105600000);
  int* cur     = (int*)(ws + 105800000);
  int* off     = (int*)(ws + 106000000);
  int* csr     = (int*)(ws + 106200016);
  int* segstart = (int*)(ws + 109600016);
  int* bsum    = (int*)(ws + 109802080);
  ushort_t* Wt1h = (ushort_t*)(ws + 105600000); // over deg+cur (dead after scatter)

  const int TB = 256;
  const int NB_SCAN = (NN + 1023) / 1024;

  hipMemsetAsync(deg, 0, 2 * NN * sizeof(int), stream);  // deg+cur contiguous (200KB each)
  k_hist<<<(Etot + TB - 1) / TB, TB, 0, stream>>>(ei, deg, E, Etot);
  k_scan1<<<NB_SCAN, 1024, 0, stream>>>(deg, off, bsum, NN);
  k_scan2<<<1, 64, 0, stream>>>(bsum, off, NB_SCAN, NN);
  k_scan3<<<NB_SCAN, 1024, 0, stream>>>(off, bsum, NN);
  k_scatter<<<(Etot + TB - 1) / TB, TB, 0, stream>>>(ei, off, cur, csr, E, Etot);
  k_segstart<<<(NBGRAPH + 1 + TB - 1) / TB, TB, 0, stream>>>(batch, segstart, NN, NBGRAPH);

  // layer 1 (scores1 fused into gemm1m epilogue)
  k_prepW<<<(DIN * DHID + TB - 1) / TB, TB, 0, stream>>>(W1, Wt1h, DIN, DHID);
  dim3 g1((NN + 63) / 64, DHID / 128);
  k_gemm1m<<<g1, TB, 0, stream>>>(x, Wt1h, as1w, ad1w, H1h, as1, ad1);
  k_agg1<<<(NN + 15) / 16, TB, 0, stream>>>(off, csr, as1, ad1, H1h, b1, OUT1);

  // layer 2 (H1h dead now; Wt2h/R2/H2h live in its region; scores2 fused into gemm2m)
  k_prepW<<<((DHID + DIN) * DOUT + TB - 1) / TB, TB, 0, stream>>>(W2, Wt2h, DHID + DIN, DOUT);
  k_gemmR<<<NBGRAPH, TB, 0, stream>>>(x, segstart, Wt2h, R2);
  dim3 g2((NN + 63) / 64, 1);
  k_gemm2m<<<g2, TB, 0, stream>>>(OUT1, batch, Wt2h, R2, as2w, ad2w, H2h, as2, ad2);
  k_agg2<<<(NN + 15) / 16, TB, 0, stream>>>(off, csr, as2, ad2, H2h, b2, OUT2);

  k_pool<<<NBGRAPH, TB, 0, stream>>>(segstart, OUT2, OUT1, out);
}